// Round 7
// baseline (463.363 us; speedup 1.0000x reference)
//
#include <hip/hip_runtime.h>
#include <hip/hip_bf16.h>

#define N_NODES 131072
#define N_EDGES 2097152
#define BATCHES 256
#define LPATH   32
// two-level counting sort params
#define NB   256          // coarse buckets (512 nodes each)
#define NPB  512          // nodes per bucket
#define GB   256          // cntA/passA2 blocks
#define EPB  8192         // edges per block

typedef __hip_bfloat16 bf16;
using short8  = __attribute__((ext_vector_type(8))) short;
using floatx4 = __attribute__((ext_vector_type(4))) float;
using floatx2 = __attribute__((ext_vector_type(2))) float;

__device__ __forceinline__ float bl(unsigned u){ union {unsigned x; float f;} c; c.x = u << 16; return c.f; }
__device__ __forceinline__ float bh(unsigned u){ union {unsigned x; float f;} c; c.x = u & 0xffff0000u; return c.f; }
__device__ __forceinline__ unsigned packbf(float lo, float hi){
  bf16 l = __float2bfloat16(lo), h = __float2bfloat16(hi);
  unsigned short lu, hu;
  __builtin_memcpy(&lu, &l, 2); __builtin_memcpy(&hu, &h, 2);
  return (unsigned)lu | ((unsigned)hu << 16);
}
__device__ __forceinline__ float frcp(float x){ return __builtin_amdgcn_rcpf(x); }
__device__ __forceinline__ float sigf(float x){ return frcp(1.f + __expf(-x)); }
__device__ __forceinline__ float tanh_fast(float x){ return fmaf(2.f, frcp(1.f + __expf(-2.f * x)), -1.f); }

// ---------------- prep: f32 weights -> bf16 (concat along K for SAGE layers) ----------------
__global__ void prep_k(const float* __restrict__ Wl1, const float* __restrict__ Wr1,
                       const float* __restrict__ Wl2, const float* __restrict__ Wr2,
                       const float* __restrict__ Wih, const float* __restrict__ Whh,
                       const float* __restrict__ bih, const float* __restrict__ bhh,
                       bf16* __restrict__ Wcat1, bf16* __restrict__ Wcat2,
                       bf16* __restrict__ WihB, bf16* __restrict__ WhhB, float* __restrict__ bsumF){
  int g = blockIdx.x * 256 + threadIdx.x;
  if (g < 16384) {                    // Wcat1: 128 x 128 (Wl1 | Wr1), K split at 64
    int h = g >> 7, k = g & 127;
    float v = (k < 64) ? Wl1[h * 64 + k] : Wr1[h * 64 + (k - 64)];
    Wcat1[g] = __float2bfloat16(v);
  } else if (g < 49152) {             // Wcat2: 128 x 256 (Wl2 | Wr2), K split at 128
    int q = g - 16384;
    int h = q >> 8, k = q & 255;
    float v = (k < 128) ? Wl2[h * 128 + k] : Wr2[h * 128 + (k - 128)];
    Wcat2[q] = __float2bfloat16(v);
  } else if (g < 114688) {            // WihB: 512 x 128
    int q = g - 49152;
    WihB[q] = __float2bfloat16(Wih[q]);
  } else if (g < 180224) {            // WhhB: 512 x 128
    int q = g - 114688;
    WhhB[q] = __float2bfloat16(Whh[q]);
  } else if (g < 180736) {            // bsumF = bih + bhh (f32)
    int k = g - 180224;
    bsumF[k] = bih[k] + bhh[k];
  }
}

// ---------------- x (f32) -> xb (bf16) + self-half of Acat1 ----------------
__global__ void xb16_k(const float* __restrict__ x, bf16* __restrict__ xb, bf16* __restrict__ Acat1){
  int g = blockIdx.x * 256 + threadIdx.x;     // one thread per 2 features
  int n = g >> 5, p = g & 31;
  float2 v = *(const float2*)(x + (size_t)n * 64 + p * 2);
  unsigned u = packbf(v.x, v.y);
  *(unsigned*)(xb + (size_t)n * 64 + p * 2) = u;
  *(unsigned*)(Acat1 + (size_t)n * 128 + 64 + p * 2) = u;
}

// ---------------- graph segment bounds (batch is sorted) ----------------
__global__ void bounds_k(const int* __restrict__ batch, int* __restrict__ starts){
  int b = threadIdx.x;
  int lo = 0, hi = N_NODES;
  while (lo < hi){ int mid = (lo + hi) >> 1; if (batch[mid] < b) lo = mid + 1; else hi = mid; }
  starts[b] = lo;
  if (b == 0) starts[BATCHES] = N_NODES;
}

// ---------------- CSR build: two-level counting sort (no global atomics) ----------------
__global__ void cntA_k(const int* __restrict__ dst, int* __restrict__ cntA){
  __shared__ int h[NB];
  int tid = threadIdx.x;
  h[tid] = 0;
  __syncthreads();
  int base = blockIdx.x * EPB;
  #pragma unroll
  for (int i = 0; i < EPB / 256; ++i){
    int d = dst[base + i * 256 + tid];
    atomicAdd(&h[d >> 9], 1);
  }
  __syncthreads();
  cntA[tid * GB + blockIdx.x] = h[tid];
}

__global__ void scan1_k(const int* __restrict__ cnt, int* __restrict__ ofsA, int* __restrict__ bsum){
  __shared__ int sh[256];
  int t = threadIdx.x, i = blockIdx.x * 256 + t;
  int v = cnt[i];
  sh[t] = v; __syncthreads();
  int inc = v;
  for (int d = 1; d < 256; d <<= 1){
    int add = (t >= d) ? sh[t - d] : 0;
    __syncthreads();
    inc += add; sh[t] = inc;
    __syncthreads();
  }
  ofsA[i] = inc - v;
  if (t == 255) bsum[blockIdx.x] = inc;
}

__global__ void scan2_k(const int* __restrict__ bsum, int* __restrict__ bsumEx){
  __shared__ int sh[NB];
  int t = threadIdx.x;
  int v = bsum[t];
  sh[t] = v; __syncthreads();
  int inc = v;
  for (int d = 1; d < NB; d <<= 1){
    int add = (t >= d) ? sh[t - d] : 0;
    __syncthreads();
    inc += add; sh[t] = inc;
    __syncthreads();
  }
  bsumEx[t] = inc - v;
}

__global__ void passA2_k(const int* __restrict__ src, const int* __restrict__ dst,
                         const int* __restrict__ ofsA, const int* __restrict__ bsumEx,
                         unsigned* __restrict__ ebuf){
  __shared__ int cur[NB];
  int tid = threadIdx.x;
  cur[tid] = ofsA[tid * GB + blockIdx.x] + bsumEx[tid];
  __syncthreads();
  int base = blockIdx.x * EPB;
  #pragma unroll
  for (int i = 0; i < EPB / 256; ++i){
    int e = base + i * 256 + tid;
    int s = src[e], d = dst[e];
    int p = atomicAdd(&cur[d >> 9], 1);
    ebuf[p] = (unsigned)s | ((unsigned)(d & (NPB - 1)) << 17);
  }
}

__global__ void passB_k(const unsigned* __restrict__ ebuf, const int* __restrict__ bsumEx,
                        int* __restrict__ offs, int* __restrict__ srcS){
  __shared__ int ncnt[NPB];
  __shared__ int pairs[256];
  __shared__ int nofs[NPB];
  int k = blockIdx.x, tid = threadIdx.x;
  int bs = bsumEx[k];
  int be = (k < NB - 1) ? bsumEx[k + 1] : N_EDGES;
  ncnt[tid] = 0; ncnt[tid + 256] = 0;
  __syncthreads();
  for (int i = bs + tid; i < be; i += 256)
    atomicAdd(&ncnt[ebuf[i] >> 17], 1);
  __syncthreads();
  int p = ncnt[2 * tid] + ncnt[2 * tid + 1];
  pairs[tid] = p;
  __syncthreads();
  int inc = p;
  for (int d = 1; d < 256; d <<= 1){
    int add = (tid >= d) ? pairs[tid - d] : 0;
    __syncthreads();
    inc += add; pairs[tid] = inc;
    __syncthreads();
  }
  int ex = inc - p;
  nofs[2 * tid]     = ex;
  nofs[2 * tid + 1] = ex + ncnt[2 * tid];
  __syncthreads();
  offs[k * NPB + tid]       = bs + nofs[tid];
  offs[k * NPB + tid + 256] = bs + nofs[tid + 256];
  if (k == NB - 1 && tid == 0) offs[N_NODES] = N_EDGES;
  ncnt[tid] = nofs[tid]; ncnt[tid + 256] = nofs[tid + 256];
  __syncthreads();
  for (int i = bs + tid; i < be; i += 256){
    unsigned w = ebuf[i];
    int loc = w >> 17, sv = w & 0x1FFFF;
    int pp = atomicAdd(&ncnt[loc], 1);
    srcS[bs + pp] = sv;
  }
}

// ---------------- SAGE layer-1 aggregation: mean of xb[src], 8 edge-slots x 8 lanes x uint4 ----------------
__global__ void agg1_k(const bf16* __restrict__ xb, const int* __restrict__ offs,
                       const int* __restrict__ srcS, bf16* __restrict__ Acat1){
  int wid = threadIdx.x >> 6, lane = threadIdx.x & 63;
  int n = blockIdx.x * 4 + wid;
  int s = offs[n], e = offs[n + 1];
  int slot = lane >> 3, fl = lane & 7;
  float a0=0,a1=0,a2=0,a3=0,a4=0,a5=0,a6=0,a7=0;
  float c0=0,c1=0,c2=0,c3=0,c4=0,c5=0,c6=0,c7=0;
  int i = s + slot;
  for (; i + 8 < e; i += 16){
    int sv0 = srcS[i], sv1 = srcS[i + 8];
    uint4 u = *(const uint4*)(xb + (size_t)sv0 * 64 + fl * 8);
    uint4 v = *(const uint4*)(xb + (size_t)sv1 * 64 + fl * 8);
    a0 += bl(u.x); a1 += bh(u.x); a2 += bl(u.y); a3 += bh(u.y);
    a4 += bl(u.z); a5 += bh(u.z); a6 += bl(u.w); a7 += bh(u.w);
    c0 += bl(v.x); c1 += bh(v.x); c2 += bl(v.y); c3 += bh(v.y);
    c4 += bl(v.z); c5 += bh(v.z); c6 += bl(v.w); c7 += bh(v.w);
  }
  if (i < e){
    int sv0 = srcS[i];
    uint4 u = *(const uint4*)(xb + (size_t)sv0 * 64 + fl * 8);
    a0 += bl(u.x); a1 += bh(u.x); a2 += bl(u.y); a3 += bh(u.y);
    a4 += bl(u.z); a5 += bh(u.z); a6 += bl(u.w); a7 += bh(u.w);
  }
  a0 += c0; a1 += c1; a2 += c2; a3 += c3;
  a4 += c4; a5 += c5; a6 += c6; a7 += c7;
  a0 += __shfl_xor(a0, 8); a0 += __shfl_xor(a0, 16); a0 += __shfl_xor(a0, 32);
  a1 += __shfl_xor(a1, 8); a1 += __shfl_xor(a1, 16); a1 += __shfl_xor(a1, 32);
  a2 += __shfl_xor(a2, 8); a2 += __shfl_xor(a2, 16); a2 += __shfl_xor(a2, 32);
  a3 += __shfl_xor(a3, 8); a3 += __shfl_xor(a3, 16); a3 += __shfl_xor(a3, 32);
  a4 += __shfl_xor(a4, 8); a4 += __shfl_xor(a4, 16); a4 += __shfl_xor(a4, 32);
  a5 += __shfl_xor(a5, 8); a5 += __shfl_xor(a5, 16); a5 += __shfl_xor(a5, 32);
  a6 += __shfl_xor(a6, 8); a6 += __shfl_xor(a6, 16); a6 += __shfl_xor(a6, 32);
  a7 += __shfl_xor(a7, 8); a7 += __shfl_xor(a7, 16); a7 += __shfl_xor(a7, 32);
  if (slot == 0){
    int d = e - s; if (d < 1) d = 1;
    float inv = 1.f / (float)d;
    uint4 w;
    w.x = packbf(a0 * inv, a1 * inv); w.y = packbf(a2 * inv, a3 * inv);
    w.z = packbf(a4 * inv, a5 * inv); w.w = packbf(a6 * inv, a7 * inv);
    *(uint4*)(Acat1 + (size_t)n * 128 + fl * 8) = w;
  }
}

// ---------------- h1 (bf16, Acat2 cols 128:256) -> fp8 e4m3 (HW cvt) ----------------
__global__ void cvt8_k(const bf16* __restrict__ Acat2, unsigned* __restrict__ h1f8){
  int g = blockIdx.x * 256 + threadIdx.x;      // one thread per 4 features
  int n = g >> 5, p = g & 31;
  uint2 u = *(const uint2*)(Acat2 + (size_t)n * 256 + 128 + p * 4);
  int w = 0;
  w = __builtin_amdgcn_cvt_pk_fp8_f32(bl(u.x), bh(u.x), w, false);
  w = __builtin_amdgcn_cvt_pk_fp8_f32(bl(u.y), bh(u.y), w, true);
  h1f8[(size_t)n * 32 + p] = (unsigned)w;
}

// ---------------- SAGE layer-2 aggregation: mean of h1f8[src], 8 edge-slots x 8 lanes x uint4 (16 fp8) ----------------
__global__ void agg2_k(const int* __restrict__ offs, const int* __restrict__ srcS,
                       const unsigned* __restrict__ h1f8, bf16* __restrict__ Acat2){
  int wid = threadIdx.x >> 6, lane = threadIdx.x & 63;
  int n = blockIdx.x * 4 + wid;
  int s = offs[n], e = offs[n + 1];
  int slot = lane >> 3, fl = lane & 7;         // fl covers features fl*16 .. fl*16+15
  float a[16] = {}, c[16] = {};
  int i = s + slot;
  for (; i + 8 < e; i += 16){
    int sv0 = srcS[i], sv1 = srcS[i + 8];
    uint4 u = *(const uint4*)(h1f8 + (size_t)sv0 * 32 + fl * 4);
    uint4 v = *(const uint4*)(h1f8 + (size_t)sv1 * 32 + fl * 4);
    floatx2 p;
    p = __builtin_amdgcn_cvt_pk_f32_fp8(u.x, false); a[0]+=p.x;  a[1]+=p.y;
    p = __builtin_amdgcn_cvt_pk_f32_fp8(u.x, true);  a[2]+=p.x;  a[3]+=p.y;
    p = __builtin_amdgcn_cvt_pk_f32_fp8(u.y, false); a[4]+=p.x;  a[5]+=p.y;
    p = __builtin_amdgcn_cvt_pk_f32_fp8(u.y, true);  a[6]+=p.x;  a[7]+=p.y;
    p = __builtin_amdgcn_cvt_pk_f32_fp8(u.z, false); a[8]+=p.x;  a[9]+=p.y;
    p = __builtin_amdgcn_cvt_pk_f32_fp8(u.z, true);  a[10]+=p.x; a[11]+=p.y;
    p = __builtin_amdgcn_cvt_pk_f32_fp8(u.w, false); a[12]+=p.x; a[13]+=p.y;
    p = __builtin_amdgcn_cvt_pk_f32_fp8(u.w, true);  a[14]+=p.x; a[15]+=p.y;
    p = __builtin_amdgcn_cvt_pk_f32_fp8(v.x, false); c[0]+=p.x;  c[1]+=p.y;
    p = __builtin_amdgcn_cvt_pk_f32_fp8(v.x, true);  c[2]+=p.x;  c[3]+=p.y;
    p = __builtin_amdgcn_cvt_pk_f32_fp8(v.y, false); c[4]+=p.x;  c[5]+=p.y;
    p = __builtin_amdgcn_cvt_pk_f32_fp8(v.y, true);  c[6]+=p.x;  c[7]+=p.y;
    p = __builtin_amdgcn_cvt_pk_f32_fp8(v.z, false); c[8]+=p.x;  c[9]+=p.y;
    p = __builtin_amdgcn_cvt_pk_f32_fp8(v.z, true);  c[10]+=p.x; c[11]+=p.y;
    p = __builtin_amdgcn_cvt_pk_f32_fp8(v.w, false); c[12]+=p.x; c[13]+=p.y;
    p = __builtin_amdgcn_cvt_pk_f32_fp8(v.w, true);  c[14]+=p.x; c[15]+=p.y;
  }
  if (i < e){
    int sv0 = srcS[i];
    uint4 u = *(const uint4*)(h1f8 + (size_t)sv0 * 32 + fl * 4);
    floatx2 p;
    p = __builtin_amdgcn_cvt_pk_f32_fp8(u.x, false); a[0]+=p.x;  a[1]+=p.y;
    p = __builtin_amdgcn_cvt_pk_f32_fp8(u.x, true);  a[2]+=p.x;  a[3]+=p.y;
    p = __builtin_amdgcn_cvt_pk_f32_fp8(u.y, false); a[4]+=p.x;  a[5]+=p.y;
    p = __builtin_amdgcn_cvt_pk_f32_fp8(u.y, true);  a[6]+=p.x;  a[7]+=p.y;
    p = __builtin_amdgcn_cvt_pk_f32_fp8(u.z, false); a[8]+=p.x;  a[9]+=p.y;
    p = __builtin_amdgcn_cvt_pk_f32_fp8(u.z, true);  a[10]+=p.x; a[11]+=p.y;
    p = __builtin_amdgcn_cvt_pk_f32_fp8(u.w, false); a[12]+=p.x; a[13]+=p.y;
    p = __builtin_amdgcn_cvt_pk_f32_fp8(u.w, true);  a[14]+=p.x; a[15]+=p.y;
  }
  #pragma unroll
  for (int j = 0; j < 16; ++j){
    a[j] += c[j];
    a[j] += __shfl_xor(a[j], 8); a[j] += __shfl_xor(a[j], 16); a[j] += __shfl_xor(a[j], 32);
  }
  if (slot == 0){
    int d = e - s; if (d < 1) d = 1;
    float inv = 1.f / (float)d;
    uint4 w0, w1;
    w0.x = packbf(a[0] * inv,  a[1] * inv);  w0.y = packbf(a[2] * inv,  a[3] * inv);
    w0.z = packbf(a[4] * inv,  a[5] * inv);  w0.w = packbf(a[6] * inv,  a[7] * inv);
    w1.x = packbf(a[8] * inv,  a[9] * inv);  w1.y = packbf(a[10] * inv, a[11] * inv);
    w1.z = packbf(a[12] * inv, a[13] * inv); w1.w = packbf(a[14] * inv, a[15] * inv);
    *(uint4*)(Acat2 + (size_t)n * 256 + fl * 16)     = w0;
    *(uint4*)(Acat2 + (size_t)n * 256 + fl * 16 + 8) = w1;
  }
}

// ---------------- generic MFMA GEMM: out[M x Ncols] = act(A[arow(M) x K] @ W[Ncols x K]^T + bias) ----------------
// ridx (optional): row gather indices for A (fuses path gather into the GEMM)
__global__ __launch_bounds__(256) void gemm_k(const bf16* __restrict__ A, int lda,
                                              const bf16* __restrict__ W, int K,
                                              const float* __restrict__ bias,
                                              void* __restrict__ out, int ldo, int outF32, int relu,
                                              const int* __restrict__ ridx){
  __shared__ bf16 Wl[128][136];   // +8 pad: 2-way bank aliasing only
  int tid = threadIdx.x;
  int wid = tid >> 6, lane = tid & 63;
  int l16 = lane & 15, quad = lane >> 4;
  int rowBase  = blockIdx.x * 64 + wid * 16;
  int colGroup = blockIdx.y * 128;
  int arow = rowBase + l16;
  if (ridx) arow = ridx[arow];
  floatx4 acc[8] = {};
  int nStage = K >> 7;
  for (int ks = 0; ks < nStage; ++ks){
    __syncthreads();
    for (int c = tid; c < 2048; c += 256){
      int r = c >> 4, kc = (c & 15) << 3;
      *(uint4*)(&Wl[r][kc]) = *(const uint4*)(W + (size_t)(colGroup + r) * K + ks * 128 + kc);
    }
    __syncthreads();
    for (int kk = 0; kk < 4; ++kk){
      short8 af = *(const short8*)(A + (size_t)arow * lda + ks * 128 + kk * 32 + quad * 8);
      #pragma unroll
      for (int c = 0; c < 8; ++c){
        short8 bq = *(const short8*)(&Wl[c * 16 + l16][kk * 32 + quad * 8]);
        acc[c] = __builtin_amdgcn_mfma_f32_16x16x32_bf16(af, bq, acc[c], 0, 0, 0);
      }
    }
  }
  #pragma unroll
  for (int c = 0; c < 8; ++c){
    int col = colGroup + c * 16 + l16;
    float bv = bias ? bias[col] : 0.f;
    #pragma unroll
    for (int r = 0; r < 4; ++r){
      int row = rowBase + quad * 4 + r;
      float v = acc[c][r] + bv;
      if (relu) v = fmaxf(v, 0.f);
      if (outF32) ((float*)out)[(size_t)row * ldo + col] = v;
      else        ((bf16*)out)[(size_t)row * ldo + col]  = __float2bfloat16(v);
    }
  }
}

// ---------------- graph mean pooling: 512 thr, 8-way row split + LDS reduce ----------------
__global__ void pool_k(const bf16* __restrict__ ne, const int* __restrict__ starts, float* __restrict__ comb){
  __shared__ float sh[8][128];
  int b = blockIdx.x;
  int q = threadIdx.x >> 6, lane = threadIdx.x & 63;   // 512 threads: 8 slots x 64 lanes
  int s = starts[b], e = starts[b + 1];
  float a0 = 0.f, a1 = 0.f;
  for (int i = s + q; i < e; i += 8){
    unsigned u = *(const unsigned*)(ne + (size_t)i * 128 + lane * 2);
    a0 += bl(u); a1 += bh(u);
  }
  sh[q][lane * 2] = a0; sh[q][lane * 2 + 1] = a1;
  __syncthreads();
  if (threadIdx.x < 128){
    int f = threadIdx.x;
    float tot = 0.f;
    #pragma unroll
    for (int k = 0; k < 8; ++k) tot += sh[k][f];
    int d = e - s; if (d < 1) d = 1;
    comb[b * 320 + f] = tot / (float)d;
  }
}

// ---------------- flow MLP: relu(flow @ Wf^T + bf), all f32 ----------------
__global__ void flow_k(const float* __restrict__ flow, const float* __restrict__ Wf,
                       const float* __restrict__ bfv, float* __restrict__ comb){
  int g = blockIdx.x * 256 + threadIdx.x;
  int b = g >> 6, j = g & 63;
  float acc = bfv[j];
  for (int k = 0; k < 16; ++k)
    acc += flow[b * 16 + k] * Wf[j * 16 + k];
  comb[b * 320 + 256 + j] = fmaxf(acc, 0.f);
}

// ---------------- LSTM recurrence via MFMA: 16 batches/block, 16 blocks ----------------
__global__ __launch_bounds__(256, 1) void lstm_k(const bf16* __restrict__ Whh, const float* __restrict__ pre,
                                                 const int* __restrict__ path_len, float* __restrict__ comb){
  __shared__ bf16 hbuf[2][16][136];   // [buf][batch][dim], +8 pad
  int tid = threadIdx.x;
  int w = tid >> 6, lane = tid & 63;
  int l16 = lane & 15, quad = lane >> 4;
  int b0 = blockIdx.x * 16;

  short8 wb[4][2][4];
  #pragma unroll
  for (int q = 0; q < 4; ++q)
    #pragma unroll
    for (int hf = 0; hf < 2; ++hf){
      const bf16* rp = Whh + (size_t)(q * 128 + w * 32 + hf * 16 + l16) * 128 + quad * 8;
      #pragma unroll
      for (int ks = 0; ks < 4; ++ks) wb[q][hf][ks] = *(const short8*)(rp + ks * 32);
    }

  int lenr[4];
  #pragma unroll
  for (int r = 0; r < 4; ++r){
    int L = path_len[b0 + quad * 4 + r];
    if (L < 1) L = 1; if (L > LPATH) L = LPATH;
    lenr[r] = L;
  }
  int maxlen = 1;
  for (int i = 0; i < 16; ++i){
    int L = path_len[b0 + i];
    if (L > LPATH) L = LPATH;
    if (L > maxlen) maxlen = L;
  }

  for (int i = tid; i < 1088; i += 256) ((unsigned*)&hbuf[0][0][0])[i] = 0;

  const float* pb[4];
  #pragma unroll
  for (int r = 0; r < 4; ++r)
    pb[r] = pre + (size_t)(b0 + quad * 4 + r) * LPATH * 512 + w * 32 + l16;

  float pv[4][2][4];
  #pragma unroll
  for (int q = 0; q < 4; ++q)
    #pragma unroll
    for (int hf = 0; hf < 2; ++hf)
      #pragma unroll
      for (int r = 0; r < 4; ++r)
        pv[q][hf][r] = pb[r][q * 128 + hf * 16];

  float cst[2][4] = {}, hst[2][4] = {};

  for (int t = 0; t < maxlen; ++t){
    int cur = t & 1, nxt = cur ^ 1;
    __syncthreads();
    short8 af[4];
    #pragma unroll
    for (int ks = 0; ks < 4; ++ks)
      af[ks] = *(const short8*)(&hbuf[cur][l16][ks * 32 + quad * 8]);
    int tn = (t + 1 < maxlen) ? t + 1 : t;
    float pnext[4][2][4];
    #pragma unroll
    for (int q = 0; q < 4; ++q)
      #pragma unroll
      for (int hf = 0; hf < 2; ++hf)
        #pragma unroll
        for (int r = 0; r < 4; ++r)
          pnext[q][hf][r] = pb[r][tn * 512 + q * 128 + hf * 16];
    floatx4 acc[4][2];
    #pragma unroll
    for (int q = 0; q < 4; ++q)
      #pragma unroll
      for (int hf = 0; hf < 2; ++hf){
        acc[q][hf][0] = pv[q][hf][0]; acc[q][hf][1] = pv[q][hf][1];
        acc[q][hf][2] = pv[q][hf][2]; acc[q][hf][3] = pv[q][hf][3];
      }
    #pragma unroll
    for (int ks = 0; ks < 4; ++ks)
      #pragma unroll
      for (int q = 0; q < 4; ++q)
        #pragma unroll
        for (int hf = 0; hf < 2; ++hf)
          acc[q][hf] = __builtin_amdgcn_mfma_f32_16x16x32_bf16(af[ks], wb[q][hf][ks], acc[q][hf], 0, 0, 0);
    #pragma unroll
    for (int hf = 0; hf < 2; ++hf)
      #pragma unroll
      for (int r = 0; r < 4; ++r){
        float ig = sigf(acc[0][hf][r]);
        float fg = sigf(acc[1][hf][r]);
        float gg = tanh_fast(acc[2][hf][r]);
        float og = sigf(acc[3][hf][r]);
        float cn = fmaf(fg, cst[hf][r], ig * gg);
        float hn = og * tanh_fast(cn);
        bool vld = t < lenr[r];
        cst[hf][r] = vld ? cn : cst[hf][r];
        hst[hf][r] = vld ? hn : hst[hf][r];
        hbuf[nxt][quad * 4 + r][w * 32 + hf * 16 + l16] = __float2bfloat16(hst[hf][r]);
      }
    #pragma unroll
    for (int q = 0; q < 4; ++q)
      #pragma unroll
      for (int hf = 0; hf < 2; ++hf)
        #pragma unroll
        for (int r = 0; r < 4; ++r)
          pv[q][hf][r] = pnext[q][hf][r];
  }

  #pragma unroll
  for (int hf = 0; hf < 2; ++hf)
    #pragma unroll
    for (int r = 0; r < 4; ++r)
      comb[(b0 + quad * 4 + r) * 320 + 128 + w * 32 + hf * 16 + l16] = hst[hf][r];
}

// ---------------- scoring head (f32 weights) ----------------
__global__ void head_k(const float* __restrict__ comb, const float* __restrict__ Ws1, const float* __restrict__ bs1,
                       const float* __restrict__ Ws2, const float* __restrict__ bs2, float* __restrict__ out){
  __shared__ float cl[320];
  __shared__ float red[128];
  int b = blockIdx.x, j = threadIdx.x;   // 128 threads
  for (int k = j; k < 320; k += 128) cl[k] = comb[b * 320 + k];
  __syncthreads();
  float acc = bs1[j];
  const float4* wr = (const float4*)(Ws1 + (size_t)j * 320);
  #pragma unroll 4
  for (int kc = 0; kc < 80; ++kc){
    float4 u = wr[kc];
    int k = kc * 4;
    acc += u.x * cl[k] + u.y * cl[k + 1] + u.z * cl[k + 2] + u.w * cl[k + 3];
  }
  float hv = fmaxf(acc, 0.f);
  red[j] = hv * Ws2[j];
  __syncthreads();
  for (int s = 64; s > 0; s >>= 1){ if (j < s) red[j] += red[j + s]; __syncthreads(); }
  if (j == 0) out[b] = red[0] + bs2[0];
}

// ---------------- workspace layout (16B-aligned) ----------------
constexpr size_t OFF_OFFS   = 0;                       // (N+1) ints
constexpr size_t OFF_CNTA   = 524544;                  // NB*GB ints = 256 KB
constexpr size_t OFF_OFSA   = OFF_CNTA   + 262144;     // NB*GB ints = 256 KB
constexpr size_t OFF_BSUM   = OFF_OFSA   + 262144;     // NB ints
constexpr size_t OFF_BSUMEX = OFF_BSUM   + 1024;       // NB ints
constexpr size_t OFF_STARTS = OFF_BSUMEX + 1024;       // 257 ints
constexpr size_t OFF_SRCS   = OFF_STARTS + 2048;       // E ints = 8.4 MB
constexpr size_t OFF_WCAT1  = OFF_SRCS   + 8388608;
constexpr size_t OFF_WCAT2  = OFF_WCAT1  + 32768;
constexpr size_t OFF_WIHB   = OFF_WCAT2  + 65536;
constexpr size_t OFF_WHHB   = OFF_WIHB   + 131072;
constexpr size_t OFF_BSUMF  = OFF_WHHB   + 131072;
constexpr size_t OFF_COMB   = OFF_BSUMF  + 2048;
constexpr size_t OFF_ACAT1  = OFF_COMB   + 327680;     // N x 128 bf16 (33.5 MB); node_emb aliases after GEMM1
constexpr size_t OFF_ACAT2  = OFF_ACAT1  + 33554432;   // N x 256 bf16 (67 MB)
// aliases (lifetimes disjoint in stream order):
constexpr size_t OFF_H1F8   = OFF_ACAT1;               // N x 128 B fp8 (16.8 MB): cvt8 (after gemm1 reads Acat1) -> agg2; clobbered by gemm2's node_emb
constexpr size_t OFF_EBUF   = OFF_ACAT2;               // E unsigned (8.4 MB), dead before gemm1
constexpr size_t OFF_PRE    = OFF_ACAT2  + 2097152;    // 8192 x 512 f32, after gemm2
constexpr size_t OFF_XB     = OFF_ACAT2  + 50331648;   // N x 64 bf16, dead before gemm1 writes Acat2

extern "C" void kernel_launch(void* const* d_in, const int* in_sizes, int n_in,
                              void* d_out, int out_size, void* d_ws, size_t ws_size,
                              hipStream_t stream){
  const float* x      = (const float*)d_in[0];
  const int* edge     = (const int*)d_in[1];
  const int* batch    = (const int*)d_in[2];
  const int* path_idx = (const int*)d_in[3];
  const int* path_len = (const int*)d_in[4];
  const float* flow   = (const float*)d_in[5];
  const float* Wl1 = (const float*)d_in[6];
  const float* Wr1 = (const float*)d_in[7];
  const float* b1  = (const float*)d_in[8];
  const float* Wl2 = (const float*)d_in[9];
  const float* Wr2 = (const float*)d_in[10];
  const float* b2  = (const float*)d_in[11];
  const float* Wih = (const float*)d_in[12];
  const float* Whh = (const float*)d_in[13];
  const float* bih = (const float*)d_in[14];
  const float* bhh = (const float*)d_in[15];
  const float* Wf  = (const float*)d_in[16];
  const float* bfv = (const float*)d_in[17];
  const float* Ws1 = (const float*)d_in[18];
  const float* bs1 = (const float*)d_in[19];
  const float* Ws2 = (const float*)d_in[20];
  const float* bs2 = (const float*)d_in[21];

  char* ws = (char*)d_ws;
  int* offs    = (int*)(ws + OFF_OFFS);
  int* cntA    = (int*)(ws + OFF_CNTA);
  int* ofsA    = (int*)(ws + OFF_OFSA);
  int* bsum    = (int*)(ws + OFF_BSUM);
  int* bsumEx  = (int*)(ws + OFF_BSUMEX);
  int* starts  = (int*)(ws + OFF_STARTS);
  int* srcS    = (int*)(ws + OFF_SRCS);
  bf16* Wcat1  = (bf16*)(ws + OFF_WCAT1);
  bf16* Wcat2  = (bf16*)(ws + OFF_WCAT2);
  bf16* WihB   = (bf16*)(ws + OFF_WIHB);
  bf16* WhhB   = (bf16*)(ws + OFF_WHHB);
  float* bsumF = (float*)(ws + OFF_BSUMF);
  float* comb  = (float*)(ws + OFF_COMB);
  bf16* Acat1  = (bf16*)(ws + OFF_ACAT1);
  bf16* node_emb = Acat1;                       // alias: Acat1 dead after GEMM1
  bf16* Acat2  = (bf16*)(ws + OFF_ACAT2);
  unsigned* h1f8 = (unsigned*)(ws + OFF_H1F8);  // alias over Acat1 (dead between gemm1 and gemm2)
  unsigned* ebuf = (unsigned*)(ws + OFF_EBUF);
  float* pre   = (float*)(ws + OFF_PRE);
  bf16* xb     = (bf16*)(ws + OFF_XB);

  prep_k<<<707, 256, 0, stream>>>(Wl1, Wr1, Wl2, Wr2, Wih, Whh, bih, bhh, Wcat1, Wcat2, WihB, WhhB, bsumF);
  xb16_k<<<N_NODES / 8, 256, 0, stream>>>(x, xb, Acat1);
  bounds_k<<<1, 256, 0, stream>>>(batch, starts);
  cntA_k<<<GB, 256, 0, stream>>>(edge + N_EDGES, cntA);
  scan1_k<<<NB, 256, 0, stream>>>(cntA, ofsA, bsum);
  scan2_k<<<1, NB, 0, stream>>>(bsum, bsumEx);
  passA2_k<<<GB, 256, 0, stream>>>(edge, edge + N_EDGES, ofsA, bsumEx, ebuf);
  passB_k<<<NB, 256, 0, stream>>>(ebuf, bsumEx, offs, srcS);
  agg1_k<<<N_NODES / 4, 256, 0, stream>>>(xb, offs, srcS, Acat1);
  gemm_k<<<dim3(N_NODES / 64, 1), 256, 0, stream>>>(Acat1, 128, Wcat1, 128, b1, Acat2 + 128, 256, 0, 1, nullptr);
  cvt8_k<<<N_NODES / 8, 256, 0, stream>>>(Acat2, h1f8);
  agg2_k<<<N_NODES / 4, 256, 0, stream>>>(offs, srcS, h1f8, Acat2);
  gemm_k<<<dim3(N_NODES / 64, 1), 256, 0, stream>>>(Acat2, 256, Wcat2, 256, b2, node_emb, 128, 0, 1, nullptr);
  pool_k<<<BATCHES, 512, 0, stream>>>(node_emb, starts, comb);
  flow_k<<<64, 256, 0, stream>>>(flow, Wf, bfv, comb);
  gemm_k<<<dim3(BATCHES * LPATH / 64, 4), 256, 0, stream>>>(node_emb, 128, WihB, 128, bsumF, pre, 512, 1, 0, path_idx);
  lstm_k<<<BATCHES / 16, 256, 0, stream>>>(WhhB, pre, path_len, comb);
  head_k<<<BATCHES, 128, 0, stream>>>(comb, Ws1, bs1, Ws2, bs2, (float*)d_out);
}

// Round 8
// 444.602 us; speedup vs baseline: 1.0422x; 1.0422x over previous
//
#include <hip/hip_runtime.h>
#include <hip/hip_bf16.h>

#define N_NODES 131072
#define N_EDGES 2097152
#define BATCHES 256
#define LPATH   32
// two-level counting sort params
#define NB   256          // coarse buckets (512 nodes each)
#define NPB  512          // nodes per bucket
#define GB   256          // cntA/passA2 blocks
#define EPB  8192         // edges per block

typedef __hip_bfloat16 bf16;
using short8  = __attribute__((ext_vector_type(8))) short;
using floatx4 = __attribute__((ext_vector_type(4))) float;
using floatx2 = __attribute__((ext_vector_type(2))) float;

__device__ __forceinline__ float bl(unsigned u){ union {unsigned x; float f;} c; c.x = u << 16; return c.f; }
__device__ __forceinline__ float bh(unsigned u){ union {unsigned x; float f;} c; c.x = u & 0xffff0000u; return c.f; }
__device__ __forceinline__ unsigned packbf(float lo, float hi){
  bf16 l = __float2bfloat16(lo), h = __float2bfloat16(hi);
  unsigned short lu, hu;
  __builtin_memcpy(&lu, &l, 2); __builtin_memcpy(&hu, &h, 2);
  return (unsigned)lu | ((unsigned)hu << 16);
}
__device__ __forceinline__ float frcp(float x){ return __builtin_amdgcn_rcpf(x); }
__device__ __forceinline__ float sigf(float x){ return frcp(1.f + __expf(-x)); }
__device__ __forceinline__ float tanh_fast(float x){ return fmaf(2.f, frcp(1.f + __expf(-2.f * x)), -1.f); }

// ---------------- prep: f32 weights -> bf16 (concat along K for SAGE layers) ----------------
__global__ void prep_k(const float* __restrict__ Wl1, const float* __restrict__ Wr1,
                       const float* __restrict__ Wl2, const float* __restrict__ Wr2,
                       const float* __restrict__ Wih, const float* __restrict__ Whh,
                       const float* __restrict__ bih, const float* __restrict__ bhh,
                       bf16* __restrict__ Wcat1, bf16* __restrict__ Wcat2,
                       bf16* __restrict__ WihB, bf16* __restrict__ WhhB, float* __restrict__ bsumF){
  int g = blockIdx.x * 256 + threadIdx.x;
  if (g < 16384) {                    // Wcat1: 128 x 128 (Wl1 | Wr1), K split at 64
    int h = g >> 7, k = g & 127;
    float v = (k < 64) ? Wl1[h * 64 + k] : Wr1[h * 64 + (k - 64)];
    Wcat1[g] = __float2bfloat16(v);
  } else if (g < 49152) {             // Wcat2: 128 x 256 (Wl2 | Wr2), K split at 128
    int q = g - 16384;
    int h = q >> 8, k = q & 255;
    float v = (k < 128) ? Wl2[h * 128 + k] : Wr2[h * 128 + (k - 128)];
    Wcat2[q] = __float2bfloat16(v);
  } else if (g < 114688) {            // WihB: 512 x 128
    int q = g - 49152;
    WihB[q] = __float2bfloat16(Wih[q]);
  } else if (g < 180224) {            // WhhB: 512 x 128
    int q = g - 114688;
    WhhB[q] = __float2bfloat16(Whh[q]);
  } else if (g < 180736) {            // bsumF = bih + bhh (f32)
    int k = g - 180224;
    bsumF[k] = bih[k] + bhh[k];
  }
}

// ---------------- x (f32) -> fp8 rows (xb8) + bf16 self-half of Acat1 ----------------
__global__ void xb8_k(const float* __restrict__ x, unsigned* __restrict__ xb8, bf16* __restrict__ Acat1){
  int g = blockIdx.x * 256 + threadIdx.x;     // one thread per 4 features
  int n = g >> 4, p = g & 15;
  float4 v = *(const float4*)(x + (size_t)n * 64 + p * 4);
  uint2 wb; wb.x = packbf(v.x, v.y); wb.y = packbf(v.z, v.w);
  *(uint2*)(Acat1 + (size_t)n * 128 + 64 + p * 4) = wb;
  int w = 0;
  w = __builtin_amdgcn_cvt_pk_fp8_f32(v.x, v.y, w, false);
  w = __builtin_amdgcn_cvt_pk_fp8_f32(v.z, v.w, w, true);
  xb8[(size_t)n * 16 + p] = (unsigned)w;
}

// ---------------- graph segment bounds (batch is sorted) ----------------
__global__ void bounds_k(const int* __restrict__ batch, int* __restrict__ starts){
  int b = threadIdx.x;
  int lo = 0, hi = N_NODES;
  while (lo < hi){ int mid = (lo + hi) >> 1; if (batch[mid] < b) lo = mid + 1; else hi = mid; }
  starts[b] = lo;
  if (b == 0) starts[BATCHES] = N_NODES;
}

// ---------------- CSR build: two-level counting sort (no global atomics) ----------------
__global__ void cntA_k(const int* __restrict__ dst, int* __restrict__ cntA){
  __shared__ int h[NB];
  int tid = threadIdx.x;
  h[tid] = 0;
  __syncthreads();
  int base = blockIdx.x * EPB;
  #pragma unroll
  for (int i = 0; i < EPB / 256; ++i){
    int d = dst[base + i * 256 + tid];
    atomicAdd(&h[d >> 9], 1);
  }
  __syncthreads();
  cntA[tid * GB + blockIdx.x] = h[tid];
}

__global__ void scan1_k(const int* __restrict__ cnt, int* __restrict__ ofsA, int* __restrict__ bsum){
  __shared__ int sh[256];
  int t = threadIdx.x, i = blockIdx.x * 256 + t;
  int v = cnt[i];
  sh[t] = v; __syncthreads();
  int inc = v;
  for (int d = 1; d < 256; d <<= 1){
    int add = (t >= d) ? sh[t - d] : 0;
    __syncthreads();
    inc += add; sh[t] = inc;
    __syncthreads();
  }
  ofsA[i] = inc - v;
  if (t == 255) bsum[blockIdx.x] = inc;
}

__global__ void scan2_k(const int* __restrict__ bsum, int* __restrict__ bsumEx){
  __shared__ int sh[NB];
  int t = threadIdx.x;
  int v = bsum[t];
  sh[t] = v; __syncthreads();
  int inc = v;
  for (int d = 1; d < NB; d <<= 1){
    int add = (t >= d) ? sh[t - d] : 0;
    __syncthreads();
    inc += add; sh[t] = inc;
    __syncthreads();
  }
  bsumEx[t] = inc - v;
}

__global__ void passA2_k(const int* __restrict__ src, const int* __restrict__ dst,
                         const int* __restrict__ ofsA, const int* __restrict__ bsumEx,
                         unsigned* __restrict__ ebuf){
  __shared__ int cur[NB];
  int tid = threadIdx.x;
  cur[tid] = ofsA[tid * GB + blockIdx.x] + bsumEx[tid];
  __syncthreads();
  int base = blockIdx.x * EPB;
  #pragma unroll
  for (int i = 0; i < EPB / 256; ++i){
    int e = base + i * 256 + tid;
    int s = src[e], d = dst[e];
    int p = atomicAdd(&cur[d >> 9], 1);
    ebuf[p] = (unsigned)s | ((unsigned)(d & (NPB - 1)) << 17);
  }
}

__global__ void passB_k(const unsigned* __restrict__ ebuf, const int* __restrict__ bsumEx,
                        int* __restrict__ offs, int* __restrict__ srcS){
  __shared__ int ncnt[NPB];
  __shared__ int pairs[256];
  __shared__ int nofs[NPB];
  int k = blockIdx.x, tid = threadIdx.x;
  int bs = bsumEx[k];
  int be = (k < NB - 1) ? bsumEx[k + 1] : N_EDGES;
  ncnt[tid] = 0; ncnt[tid + 256] = 0;
  __syncthreads();
  for (int i = bs + tid; i < be; i += 256)
    atomicAdd(&ncnt[ebuf[i] >> 17], 1);
  __syncthreads();
  int p = ncnt[2 * tid] + ncnt[2 * tid + 1];
  pairs[tid] = p;
  __syncthreads();
  int inc = p;
  for (int d = 1; d < 256; d <<= 1){
    int add = (tid >= d) ? pairs[tid - d] : 0;
    __syncthreads();
    inc += add; pairs[tid] = inc;
    __syncthreads();
  }
  int ex = inc - p;
  nofs[2 * tid]     = ex;
  nofs[2 * tid + 1] = ex + ncnt[2 * tid];
  __syncthreads();
  offs[k * NPB + tid]       = bs + nofs[tid];
  offs[k * NPB + tid + 256] = bs + nofs[tid + 256];
  if (k == NB - 1 && tid == 0) offs[N_NODES] = N_EDGES;
  ncnt[tid] = nofs[tid]; ncnt[tid + 256] = nofs[tid + 256];
  __syncthreads();
  for (int i = bs + tid; i < be; i += 256){
    unsigned w = ebuf[i];
    int loc = w >> 17, sv = w & 0x1FFFF;
    int pp = atomicAdd(&ncnt[loc], 1);
    srcS[bs + pp] = sv;
  }
}

// ---------------- SAGE layer-1 aggregation: mean of xb8[src] (fp8), 8 slots x 8 lanes x uint2 ----------------
__global__ void agg1_k(const unsigned* __restrict__ xb8, const int* __restrict__ offs,
                       const int* __restrict__ srcS, bf16* __restrict__ Acat1){
  int wid = threadIdx.x >> 6, lane = threadIdx.x & 63;
  int n = blockIdx.x * 4 + wid;
  int s = offs[n], e = offs[n + 1];
  int slot = lane >> 3, fl = lane & 7;          // fl covers features fl*8 .. fl*8+7
  floatx2 a0={0,0}, a1={0,0}, a2={0,0}, a3={0,0};
  floatx2 c0={0,0}, c1={0,0}, c2={0,0}, c3={0,0};
  int i = s + slot;
  for (; i + 8 < e; i += 16){
    int sv0 = srcS[i], sv1 = srcS[i + 8];
    uint2 u = *(const uint2*)(xb8 + (size_t)sv0 * 16 + fl * 2);
    uint2 v = *(const uint2*)(xb8 + (size_t)sv1 * 16 + fl * 2);
    a0 += __builtin_amdgcn_cvt_pk_f32_fp8(u.x, false);
    a1 += __builtin_amdgcn_cvt_pk_f32_fp8(u.x, true);
    a2 += __builtin_amdgcn_cvt_pk_f32_fp8(u.y, false);
    a3 += __builtin_amdgcn_cvt_pk_f32_fp8(u.y, true);
    c0 += __builtin_amdgcn_cvt_pk_f32_fp8(v.x, false);
    c1 += __builtin_amdgcn_cvt_pk_f32_fp8(v.x, true);
    c2 += __builtin_amdgcn_cvt_pk_f32_fp8(v.y, false);
    c3 += __builtin_amdgcn_cvt_pk_f32_fp8(v.y, true);
  }
  if (i < e){
    int sv0 = srcS[i];
    uint2 u = *(const uint2*)(xb8 + (size_t)sv0 * 16 + fl * 2);
    a0 += __builtin_amdgcn_cvt_pk_f32_fp8(u.x, false);
    a1 += __builtin_amdgcn_cvt_pk_f32_fp8(u.x, true);
    a2 += __builtin_amdgcn_cvt_pk_f32_fp8(u.y, false);
    a3 += __builtin_amdgcn_cvt_pk_f32_fp8(u.y, true);
  }
  a0 += c0; a1 += c1; a2 += c2; a3 += c3;
  float f[8] = {a0.x, a0.y, a1.x, a1.y, a2.x, a2.y, a3.x, a3.y};
  #pragma unroll
  for (int j = 0; j < 8; ++j){
    f[j] += __shfl_xor(f[j], 8);
    f[j] += __shfl_xor(f[j], 16);
    f[j] += __shfl_xor(f[j], 32);
  }
  if (slot == 0){
    int d = e - s; if (d < 1) d = 1;
    float inv = 1.f / (float)d;
    uint4 w;
    w.x = packbf(f[0] * inv, f[1] * inv);
    w.y = packbf(f[2] * inv, f[3] * inv);
    w.z = packbf(f[4] * inv, f[5] * inv);
    w.w = packbf(f[6] * inv, f[7] * inv);
    *(uint4*)(Acat1 + (size_t)n * 128 + fl * 8) = w;
  }
}

// ---------------- h1 (bf16, Acat2 cols 128:256) -> fp8 e4m3 (HW cvt) ----------------
__global__ void cvt8_k(const bf16* __restrict__ Acat2, unsigned* __restrict__ h1f8){
  int g = blockIdx.x * 256 + threadIdx.x;      // one thread per 4 features
  int n = g >> 5, p = g & 31;
  uint2 u = *(const uint2*)(Acat2 + (size_t)n * 256 + 128 + p * 4);
  int w = 0;
  w = __builtin_amdgcn_cvt_pk_fp8_f32(bl(u.x), bh(u.x), w, false);
  w = __builtin_amdgcn_cvt_pk_fp8_f32(bl(u.y), bh(u.y), w, true);
  h1f8[(size_t)n * 32 + p] = (unsigned)w;
}

// ---------------- SAGE layer-2 aggregation: mean of h1f8[src] (fp8), 4 slots x 16 lanes x uint2 ----------------
__global__ void agg2_k(const int* __restrict__ offs, const int* __restrict__ srcS,
                       const unsigned* __restrict__ h1f8, bf16* __restrict__ Acat2){
  int wid = threadIdx.x >> 6, lane = threadIdx.x & 63;
  int n = blockIdx.x * 4 + wid;
  int s = offs[n], e = offs[n + 1];
  int slot = lane >> 4, fl = lane & 15;         // fl covers features fl*8 .. fl*8+7
  floatx2 a0={0,0}, a1={0,0}, a2={0,0}, a3={0,0};
  floatx2 c0={0,0}, c1={0,0}, c2={0,0}, c3={0,0};
  int i = s + slot;
  for (; i + 4 < e; i += 8){
    int sv0 = srcS[i], sv1 = srcS[i + 4];
    uint2 u = *(const uint2*)(h1f8 + (size_t)sv0 * 32 + fl * 2);
    uint2 v = *(const uint2*)(h1f8 + (size_t)sv1 * 32 + fl * 2);
    a0 += __builtin_amdgcn_cvt_pk_f32_fp8(u.x, false);
    a1 += __builtin_amdgcn_cvt_pk_f32_fp8(u.x, true);
    a2 += __builtin_amdgcn_cvt_pk_f32_fp8(u.y, false);
    a3 += __builtin_amdgcn_cvt_pk_f32_fp8(u.y, true);
    c0 += __builtin_amdgcn_cvt_pk_f32_fp8(v.x, false);
    c1 += __builtin_amdgcn_cvt_pk_f32_fp8(v.x, true);
    c2 += __builtin_amdgcn_cvt_pk_f32_fp8(v.y, false);
    c3 += __builtin_amdgcn_cvt_pk_f32_fp8(v.y, true);
  }
  if (i < e){
    int sv0 = srcS[i];
    uint2 u = *(const uint2*)(h1f8 + (size_t)sv0 * 32 + fl * 2);
    a0 += __builtin_amdgcn_cvt_pk_f32_fp8(u.x, false);
    a1 += __builtin_amdgcn_cvt_pk_f32_fp8(u.x, true);
    a2 += __builtin_amdgcn_cvt_pk_f32_fp8(u.y, false);
    a3 += __builtin_amdgcn_cvt_pk_f32_fp8(u.y, true);
  }
  a0 += c0; a1 += c1; a2 += c2; a3 += c3;
  float f[8] = {a0.x, a0.y, a1.x, a1.y, a2.x, a2.y, a3.x, a3.y};
  #pragma unroll
  for (int j = 0; j < 8; ++j){
    f[j] += __shfl_xor(f[j], 16);
    f[j] += __shfl_xor(f[j], 32);
  }
  if (slot == 0){
    int d = e - s; if (d < 1) d = 1;
    float inv = 1.f / (float)d;
    uint4 w;
    w.x = packbf(f[0] * inv, f[1] * inv);
    w.y = packbf(f[2] * inv, f[3] * inv);
    w.z = packbf(f[4] * inv, f[5] * inv);
    w.w = packbf(f[6] * inv, f[7] * inv);
    *(uint4*)(Acat2 + (size_t)n * 256 + fl * 8) = w;
  }
}

// ---------------- generic MFMA GEMM: out[M x Ncols] = act(A[arow(M) x K] @ W[Ncols x K]^T + bias) ----------------
// ridx (optional): row gather indices for A (fuses path gather into the GEMM)
__global__ __launch_bounds__(256) void gemm_k(const bf16* __restrict__ A, int lda,
                                              const bf16* __restrict__ W, int K,
                                              const float* __restrict__ bias,
                                              void* __restrict__ out, int ldo, int outF32, int relu,
                                              const int* __restrict__ ridx){
  __shared__ bf16 Wl[128][136];   // +8 pad: 2-way bank aliasing only
  int tid = threadIdx.x;
  int wid = tid >> 6, lane = tid & 63;
  int l16 = lane & 15, quad = lane >> 4;
  int rowBase  = blockIdx.x * 64 + wid * 16;
  int colGroup = blockIdx.y * 128;
  int arow = rowBase + l16;
  if (ridx) arow = ridx[arow];
  floatx4 acc[8] = {};
  int nStage = K >> 7;
  for (int ks = 0; ks < nStage; ++ks){
    __syncthreads();
    for (int c = tid; c < 2048; c += 256){
      int r = c >> 4, kc = (c & 15) << 3;
      *(uint4*)(&Wl[r][kc]) = *(const uint4*)(W + (size_t)(colGroup + r) * K + ks * 128 + kc);
    }
    __syncthreads();
    for (int kk = 0; kk < 4; ++kk){
      short8 af = *(const short8*)(A + (size_t)arow * lda + ks * 128 + kk * 32 + quad * 8);
      #pragma unroll
      for (int c = 0; c < 8; ++c){
        short8 bq = *(const short8*)(&Wl[c * 16 + l16][kk * 32 + quad * 8]);
        acc[c] = __builtin_amdgcn_mfma_f32_16x16x32_bf16(af, bq, acc[c], 0, 0, 0);
      }
    }
  }
  #pragma unroll
  for (int c = 0; c < 8; ++c){
    int col = colGroup + c * 16 + l16;
    float bv = bias ? bias[col] : 0.f;
    #pragma unroll
    for (int r = 0; r < 4; ++r){
      int row = rowBase + quad * 4 + r;
      float v = acc[c][r] + bv;
      if (relu) v = fmaxf(v, 0.f);
      if (outF32) ((float*)out)[(size_t)row * ldo + col] = v;
      else        ((bf16*)out)[(size_t)row * ldo + col]  = __float2bfloat16(v);
    }
  }
}

// ---------------- graph mean pooling: 512 thr, 8-way row split + LDS reduce ----------------
__global__ void pool_k(const bf16* __restrict__ ne, const int* __restrict__ starts, float* __restrict__ comb){
  __shared__ float sh[8][128];
  int b = blockIdx.x;
  int q = threadIdx.x >> 6, lane = threadIdx.x & 63;   // 512 threads: 8 slots x 64 lanes
  int s = starts[b], e = starts[b + 1];
  float a0 = 0.f, a1 = 0.f;
  for (int i = s + q; i < e; i += 8){
    unsigned u = *(const unsigned*)(ne + (size_t)i * 128 + lane * 2);
    a0 += bl(u); a1 += bh(u);
  }
  sh[q][lane * 2] = a0; sh[q][lane * 2 + 1] = a1;
  __syncthreads();
  if (threadIdx.x < 128){
    int f = threadIdx.x;
    float tot = 0.f;
    #pragma unroll
    for (int k = 0; k < 8; ++k) tot += sh[k][f];
    int d = e - s; if (d < 1) d = 1;
    comb[b * 320 + f] = tot / (float)d;
  }
}

// ---------------- flow MLP: relu(flow @ Wf^T + bf), all f32 ----------------
__global__ void flow_k(const float* __restrict__ flow, const float* __restrict__ Wf,
                       const float* __restrict__ bfv, float* __restrict__ comb){
  int g = blockIdx.x * 256 + threadIdx.x;
  int b = g >> 6, j = g & 63;
  float acc = bfv[j];
  for (int k = 0; k < 16; ++k)
    acc += flow[b * 16 + k] * Wf[j * 16 + k];
  comb[b * 320 + 256 + j] = fmaxf(acc, 0.f);
}

// ---------------- LSTM recurrence via MFMA: 16 batches/block, 16 blocks ----------------
__global__ __launch_bounds__(256, 1) void lstm_k(const bf16* __restrict__ Whh, const float* __restrict__ pre,
                                                 const int* __restrict__ path_len, float* __restrict__ comb){
  __shared__ bf16 hbuf[2][16][136];   // [buf][batch][dim], +8 pad
  int tid = threadIdx.x;
  int w = tid >> 6, lane = tid & 63;
  int l16 = lane & 15, quad = lane >> 4;
  int b0 = blockIdx.x * 16;

  short8 wb[4][2][4];
  #pragma unroll
  for (int q = 0; q < 4; ++q)
    #pragma unroll
    for (int hf = 0; hf < 2; ++hf){
      const bf16* rp = Whh + (size_t)(q * 128 + w * 32 + hf * 16 + l16) * 128 + quad * 8;
      #pragma unroll
      for (int ks = 0; ks < 4; ++ks) wb[q][hf][ks] = *(const short8*)(rp + ks * 32);
    }

  int lenr[4];
  #pragma unroll
  for (int r = 0; r < 4; ++r){
    int L = path_len[b0 + quad * 4 + r];
    if (L < 1) L = 1; if (L > LPATH) L = LPATH;
    lenr[r] = L;
  }
  int maxlen = 1;
  for (int i = 0; i < 16; ++i){
    int L = path_len[b0 + i];
    if (L > LPATH) L = LPATH;
    if (L > maxlen) maxlen = L;
  }

  for (int i = tid; i < 1088; i += 256) ((unsigned*)&hbuf[0][0][0])[i] = 0;

  const float* pb[4];
  #pragma unroll
  for (int r = 0; r < 4; ++r)
    pb[r] = pre + (size_t)(b0 + quad * 4 + r) * LPATH * 512 + w * 32 + l16;

  float pv[4][2][4];
  #pragma unroll
  for (int q = 0; q < 4; ++q)
    #pragma unroll
    for (int hf = 0; hf < 2; ++hf)
      #pragma unroll
      for (int r = 0; r < 4; ++r)
        pv[q][hf][r] = pb[r][q * 128 + hf * 16];

  float cst[2][4] = {}, hst[2][4] = {};

  for (int t = 0; t < maxlen; ++t){
    int cur = t & 1, nxt = cur ^ 1;
    __syncthreads();
    short8 af[4];
    #pragma unroll
    for (int ks = 0; ks < 4; ++ks)
      af[ks] = *(const short8*)(&hbuf[cur][l16][ks * 32 + quad * 8]);
    int tn = (t + 1 < maxlen) ? t + 1 : t;
    float pnext[4][2][4];
    #pragma unroll
    for (int q = 0; q < 4; ++q)
      #pragma unroll
      for (int hf = 0; hf < 2; ++hf)
        #pragma unroll
        for (int r = 0; r < 4; ++r)
          pnext[q][hf][r] = pb[r][tn * 512 + q * 128 + hf * 16];
    floatx4 acc[4][2];
    #pragma unroll
    for (int q = 0; q < 4; ++q)
      #pragma unroll
      for (int hf = 0; hf < 2; ++hf){
        acc[q][hf][0] = pv[q][hf][0]; acc[q][hf][1] = pv[q][hf][1];
        acc[q][hf][2] = pv[q][hf][2]; acc[q][hf][3] = pv[q][hf][3];
      }
    #pragma unroll
    for (int ks = 0; ks < 4; ++ks)
      #pragma unroll
      for (int q = 0; q < 4; ++q)
        #pragma unroll
        for (int hf = 0; hf < 2; ++hf)
          acc[q][hf] = __builtin_amdgcn_mfma_f32_16x16x32_bf16(af[ks], wb[q][hf][ks], acc[q][hf], 0, 0, 0);
    #pragma unroll
    for (int hf = 0; hf < 2; ++hf)
      #pragma unroll
      for (int r = 0; r < 4; ++r){
        float ig = sigf(acc[0][hf][r]);
        float fg = sigf(acc[1][hf][r]);
        float gg = tanh_fast(acc[2][hf][r]);
        float og = sigf(acc[3][hf][r]);
        float cn = fmaf(fg, cst[hf][r], ig * gg);
        float hn = og * tanh_fast(cn);
        bool vld = t < lenr[r];
        cst[hf][r] = vld ? cn : cst[hf][r];
        hst[hf][r] = vld ? hn : hst[hf][r];
        hbuf[nxt][quad * 4 + r][w * 32 + hf * 16 + l16] = __float2bfloat16(hst[hf][r]);
      }
    #pragma unroll
    for (int q = 0; q < 4; ++q)
      #pragma unroll
      for (int hf = 0; hf < 2; ++hf)
        #pragma unroll
        for (int r = 0; r < 4; ++r)
          pv[q][hf][r] = pnext[q][hf][r];
  }

  #pragma unroll
  for (int hf = 0; hf < 2; ++hf)
    #pragma unroll
    for (int r = 0; r < 4; ++r)
      comb[(b0 + quad * 4 + r) * 320 + 128 + w * 32 + hf * 16 + l16] = hst[hf][r];
}

// ---------------- scoring head (f32 weights) ----------------
__global__ void head_k(const float* __restrict__ comb, const float* __restrict__ Ws1, const float* __restrict__ bs1,
                       const float* __restrict__ Ws2, const float* __restrict__ bs2, float* __restrict__ out){
  __shared__ float cl[320];
  __shared__ float red[128];
  int b = blockIdx.x, j = threadIdx.x;   // 128 threads
  for (int k = j; k < 320; k += 128) cl[k] = comb[b * 320 + k];
  __syncthreads();
  float acc = bs1[j];
  const float4* wr = (const float4*)(Ws1 + (size_t)j * 320);
  #pragma unroll 4
  for (int kc = 0; kc < 80; ++kc){
    float4 u = wr[kc];
    int k = kc * 4;
    acc += u.x * cl[k] + u.y * cl[k + 1] + u.z * cl[k + 2] + u.w * cl[k + 3];
  }
  float hv = fmaxf(acc, 0.f);
  red[j] = hv * Ws2[j];
  __syncthreads();
  for (int s = 64; s > 0; s >>= 1){ if (j < s) red[j] += red[j + s]; __syncthreads(); }
  if (j == 0) out[b] = red[0] + bs2[0];
}

// ---------------- workspace layout (16B-aligned) ----------------
constexpr size_t OFF_OFFS   = 0;                       // (N+1) ints
constexpr size_t OFF_CNTA   = 524544;                  // NB*GB ints = 256 KB
constexpr size_t OFF_OFSA   = OFF_CNTA   + 262144;     // NB*GB ints = 256 KB
constexpr size_t OFF_BSUM   = OFF_OFSA   + 262144;     // NB ints
constexpr size_t OFF_BSUMEX = OFF_BSUM   + 1024;       // NB ints
constexpr size_t OFF_STARTS = OFF_BSUMEX + 1024;       // 257 ints
constexpr size_t OFF_SRCS   = OFF_STARTS + 2048;       // E ints = 8.4 MB
constexpr size_t OFF_WCAT1  = OFF_SRCS   + 8388608;
constexpr size_t OFF_WCAT2  = OFF_WCAT1  + 32768;
constexpr size_t OFF_WIHB   = OFF_WCAT2  + 65536;
constexpr size_t OFF_WHHB   = OFF_WIHB   + 131072;
constexpr size_t OFF_BSUMF  = OFF_WHHB   + 131072;
constexpr size_t OFF_COMB   = OFF_BSUMF  + 2048;
constexpr size_t OFF_ACAT1  = OFF_COMB   + 327680;     // N x 128 bf16 (33.5 MB); node_emb aliases after GEMM1
constexpr size_t OFF_ACAT2  = OFF_ACAT1  + 33554432;   // N x 256 bf16 (67 MB)
// aliases (lifetimes disjoint in stream order):
constexpr size_t OFF_H1F8   = OFF_ACAT1;               // N x 128 B fp8 (16.8 MB): cvt8 (after gemm1 reads Acat1) -> agg2; clobbered by gemm2's node_emb
constexpr size_t OFF_EBUF   = OFF_ACAT2;               // E unsigned (8.4 MB), dead before gemm1
constexpr size_t OFF_PRE    = OFF_ACAT2  + 2097152;    // 8192 x 512 f32, after gemm2
constexpr size_t OFF_XB8    = OFF_ACAT2  + 50331648;   // N x 64 B fp8 (8.4 MB), dead before gemm1 writes Acat2

extern "C" void kernel_launch(void* const* d_in, const int* in_sizes, int n_in,
                              void* d_out, int out_size, void* d_ws, size_t ws_size,
                              hipStream_t stream){
  const float* x      = (const float*)d_in[0];
  const int* edge     = (const int*)d_in[1];
  const int* batch    = (const int*)d_in[2];
  const int* path_idx = (const int*)d_in[3];
  const int* path_len = (const int*)d_in[4];
  const float* flow   = (const float*)d_in[5];
  const float* Wl1 = (const float*)d_in[6];
  const float* Wr1 = (const float*)d_in[7];
  const float* b1  = (const float*)d_in[8];
  const float* Wl2 = (const float*)d_in[9];
  const float* Wr2 = (const float*)d_in[10];
  const float* b2  = (const float*)d_in[11];
  const float* Wih = (const float*)d_in[12];
  const float* Whh = (const float*)d_in[13];
  const float* bih = (const float*)d_in[14];
  const float* bhh = (const float*)d_in[15];
  const float* Wf  = (const float*)d_in[16];
  const float* bfv = (const float*)d_in[17];
  const float* Ws1 = (const float*)d_in[18];
  const float* bs1 = (const float*)d_in[19];
  const float* Ws2 = (const float*)d_in[20];
  const float* bs2 = (const float*)d_in[21];

  char* ws = (char*)d_ws;
  int* offs    = (int*)(ws + OFF_OFFS);
  int* cntA    = (int*)(ws + OFF_CNTA);
  int* ofsA    = (int*)(ws + OFF_OFSA);
  int* bsum    = (int*)(ws + OFF_BSUM);
  int* bsumEx  = (int*)(ws + OFF_BSUMEX);
  int* starts  = (int*)(ws + OFF_STARTS);
  int* srcS    = (int*)(ws + OFF_SRCS);
  bf16* Wcat1  = (bf16*)(ws + OFF_WCAT1);
  bf16* Wcat2  = (bf16*)(ws + OFF_WCAT2);
  bf16* WihB   = (bf16*)(ws + OFF_WIHB);
  bf16* WhhB   = (bf16*)(ws + OFF_WHHB);
  float* bsumF = (float*)(ws + OFF_BSUMF);
  float* comb  = (float*)(ws + OFF_COMB);
  bf16* Acat1  = (bf16*)(ws + OFF_ACAT1);
  bf16* node_emb = Acat1;                       // alias: Acat1 dead after GEMM1
  bf16* Acat2  = (bf16*)(ws + OFF_ACAT2);
  unsigned* h1f8 = (unsigned*)(ws + OFF_H1F8);  // alias over Acat1 (dead between gemm1 and gemm2)
  unsigned* ebuf = (unsigned*)(ws + OFF_EBUF);
  float* pre   = (float*)(ws + OFF_PRE);
  unsigned* xb8 = (unsigned*)(ws + OFF_XB8);

  prep_k<<<707, 256, 0, stream>>>(Wl1, Wr1, Wl2, Wr2, Wih, Whh, bih, bhh, Wcat1, Wcat2, WihB, WhhB, bsumF);
  xb8_k<<<N_NODES / 16, 256, 0, stream>>>(x, xb8, Acat1);
  bounds_k<<<1, 256, 0, stream>>>(batch, starts);
  cntA_k<<<GB, 256, 0, stream>>>(edge + N_EDGES, cntA);
  scan1_k<<<NB, 256, 0, stream>>>(cntA, ofsA, bsum);
  scan2_k<<<1, NB, 0, stream>>>(bsum, bsumEx);
  passA2_k<<<GB, 256, 0, stream>>>(edge, edge + N_EDGES, ofsA, bsumEx, ebuf);
  passB_k<<<NB, 256, 0, stream>>>(ebuf, bsumEx, offs, srcS);
  agg1_k<<<N_NODES / 4, 256, 0, stream>>>(xb8, offs, srcS, Acat1);
  gemm_k<<<dim3(N_NODES / 64, 1), 256, 0, stream>>>(Acat1, 128, Wcat1, 128, b1, Acat2 + 128, 256, 0, 1, nullptr);
  cvt8_k<<<N_NODES / 8, 256, 0, stream>>>(Acat2, h1f8);
  agg2_k<<<N_NODES / 4, 256, 0, stream>>>(offs, srcS, h1f8, Acat2);
  gemm_k<<<dim3(N_NODES / 64, 1), 256, 0, stream>>>(Acat2, 256, Wcat2, 256, b2, node_emb, 128, 0, 1, nullptr);
  pool_k<<<BATCHES, 512, 0, stream>>>(node_emb, starts, comb);
  flow_k<<<64, 256, 0, stream>>>(flow, Wf, bfv, comb);
  gemm_k<<<dim3(BATCHES * LPATH / 64, 4), 256, 0, stream>>>(node_emb, 128, WihB, 128, bsumF, pre, 512, 1, 0, path_idx);
  lstm_k<<<BATCHES / 16, 256, 0, stream>>>(WhhB, pre, path_len, comb);
  head_k<<<BATCHES, 128, 0, stream>>>(comb, Ws1, bs1, Ws2, bs2, (float*)d_out);
}

// Round 9
// 438.678 us; speedup vs baseline: 1.0563x; 1.0135x over previous
//
#include <hip/hip_runtime.h>
#include <hip/hip_bf16.h>

#define N_NODES 131072
#define N_EDGES 2097152
#define BATCHES 256
#define LPATH   32
// two-level counting sort params
#define NB   256          // coarse buckets (512 nodes each)
#define NPB  512          // nodes per bucket
#define GB   256          // cntA/passA2 blocks
#define EPB  8192         // edges per block

typedef __hip_bfloat16 bf16;
using short8  = __attribute__((ext_vector_type(8))) short;
using floatx4 = __attribute__((ext_vector_type(4))) float;
using floatx2 = __attribute__((ext_vector_type(2))) float;

__device__ __forceinline__ float bl(unsigned u){ union {unsigned x; float f;} c; c.x = u << 16; return c.f; }
__device__ __forceinline__ float bh(unsigned u){ union {unsigned x; float f;} c; c.x = u & 0xffff0000u; return c.f; }
__device__ __forceinline__ unsigned packbf(float lo, float hi){
  bf16 l = __float2bfloat16(lo), h = __float2bfloat16(hi);
  unsigned short lu, hu;
  __builtin_memcpy(&lu, &l, 2); __builtin_memcpy(&hu, &h, 2);
  return (unsigned)lu | ((unsigned)hu << 16);
}
__device__ __forceinline__ float frcp(float x){ return __builtin_amdgcn_rcpf(x); }
__device__ __forceinline__ float sigf(float x){ return frcp(1.f + __expf(-x)); }
__device__ __forceinline__ float tanh_fast(float x){ return fmaf(2.f, frcp(1.f + __expf(-2.f * x)), -1.f); }

// ---------------- mega0: xb8 [0,8192) | cntA [8192,8448) | prep [8448,9155) | bounds {9155} ----------------
__global__ void mega0_k(const float* __restrict__ x, unsigned* __restrict__ xb8, bf16* __restrict__ Acat1,
                        const int* __restrict__ dst, int* __restrict__ cntA,
                        const float* __restrict__ Wl1, const float* __restrict__ Wr1,
                        const float* __restrict__ Wl2, const float* __restrict__ Wr2,
                        const float* __restrict__ Wih, const float* __restrict__ Whh,
                        const float* __restrict__ bih, const float* __restrict__ bhh,
                        bf16* __restrict__ Wcat1, bf16* __restrict__ Wcat2,
                        bf16* __restrict__ WihB, bf16* __restrict__ WhhB, float* __restrict__ bsumF,
                        const int* __restrict__ batch, int* __restrict__ starts){
  __shared__ int h[NB];
  int bid = blockIdx.x, tid = threadIdx.x;
  if (bid < 8192){                     // x (f32) -> fp8 rows + bf16 self-half of Acat1
    int g = bid * 256 + tid;           // one thread per 4 features
    int n = g >> 4, p = g & 15;
    float4 v = *(const float4*)(x + (size_t)n * 64 + p * 4);
    uint2 wb; wb.x = packbf(v.x, v.y); wb.y = packbf(v.z, v.w);
    *(uint2*)(Acat1 + (size_t)n * 128 + 64 + p * 4) = wb;
    int w = 0;
    w = __builtin_amdgcn_cvt_pk_fp8_f32(v.x, v.y, w, false);
    w = __builtin_amdgcn_cvt_pk_fp8_f32(v.z, v.w, w, true);
    xb8[(size_t)n * 16 + p] = (unsigned)w;
  } else if (bid < 8448){              // cntA: coarse bucket histogram
    int cb = bid - 8192;
    h[tid] = 0;
    __syncthreads();
    int base = cb * EPB;
    #pragma unroll
    for (int i = 0; i < EPB / 256; ++i){
      int d = dst[base + i * 256 + tid];
      atomicAdd(&h[d >> 9], 1);
    }
    __syncthreads();
    cntA[tid * GB + cb] = h[tid];
  } else if (bid < 9155){              // prep: f32 weights -> bf16
    int g = (bid - 8448) * 256 + tid;
    if (g < 16384) {                   // Wcat1: 128 x 128 (Wl1 | Wr1)
      int hh = g >> 7, k = g & 127;
      float v = (k < 64) ? Wl1[hh * 64 + k] : Wr1[hh * 64 + (k - 64)];
      Wcat1[g] = __float2bfloat16(v);
    } else if (g < 49152) {            // Wcat2: 128 x 256 (Wl2 | Wr2)
      int q = g - 16384;
      int hh = q >> 8, k = q & 255;
      float v = (k < 128) ? Wl2[hh * 128 + k] : Wr2[hh * 128 + (k - 128)];
      Wcat2[q] = __float2bfloat16(v);
    } else if (g < 114688) {           // WihB: 512 x 128
      int q = g - 49152;
      WihB[q] = __float2bfloat16(Wih[q]);
    } else if (g < 180224) {           // WhhB: 512 x 128
      int q = g - 114688;
      WhhB[q] = __float2bfloat16(Whh[q]);
    } else if (g < 180736) {           // bsumF = bih + bhh (f32)
      int k = g - 180224;
      bsumF[k] = bih[k] + bhh[k];
    }
  } else {                             // bounds: segment starts (batch sorted)
    int b = tid;
    int lo = 0, hi = N_NODES;
    while (lo < hi){ int mid = (lo + hi) >> 1; if (batch[mid] < b) lo = mid + 1; else hi = mid; }
    starts[b] = lo;
    if (b == 0) starts[BATCHES] = N_NODES;
  }
}

// ---------------- per-bucket exclusive scan (one block per bucket) + bucket totals ----------------
__global__ void scan1_k(const int* __restrict__ cnt, int* __restrict__ ofsA, int* __restrict__ bsum){
  __shared__ int sh[256];
  int t = threadIdx.x, i = blockIdx.x * 256 + t;
  int v = cnt[i];
  sh[t] = v; __syncthreads();
  int inc = v;
  for (int d = 1; d < 256; d <<= 1){
    int add = (t >= d) ? sh[t - d] : 0;
    __syncthreads();
    inc += add; sh[t] = inc;
    __syncthreads();
  }
  ofsA[i] = inc - v;
  if (t == 255) bsum[blockIdx.x] = inc;
}

// ---------------- passA2: place packed (src | localNode<<17); bucket-total scan computed locally ----------------
__global__ void passA2_k(const int* __restrict__ src, const int* __restrict__ dst,
                         const int* __restrict__ ofsA, const int* __restrict__ bsum,
                         unsigned* __restrict__ ebuf){
  __shared__ int cur[NB];
  __shared__ int sc[NB];
  int tid = threadIdx.x;
  // local exclusive scan of bucket totals
  int v = bsum[tid];
  sc[tid] = v; __syncthreads();
  int inc = v;
  for (int d = 1; d < NB; d <<= 1){
    int add = (tid >= d) ? sc[tid - d] : 0;
    __syncthreads();
    inc += add; sc[tid] = inc;
    __syncthreads();
  }
  cur[tid] = ofsA[tid * GB + blockIdx.x] + (inc - v);
  __syncthreads();
  int base = blockIdx.x * EPB;
  #pragma unroll
  for (int i = 0; i < EPB / 256; ++i){
    int e = base + i * 256 + tid;
    int s = src[e], d = dst[e];
    int p = atomicAdd(&cur[d >> 9], 1);
    ebuf[p] = (unsigned)s | ((unsigned)(d & (NPB - 1)) << 17);
  }
}

// ---------------- passB: per-node CSR within bucket; bucket-total scan computed locally ----------------
__global__ void passB_k(const unsigned* __restrict__ ebuf, const int* __restrict__ bsum,
                        int* __restrict__ offs, int* __restrict__ srcS){
  __shared__ int ncnt[NPB];
  __shared__ int pairs[256];
  __shared__ int nofs[NPB];
  __shared__ int sc[NB];
  int k = blockIdx.x, tid = threadIdx.x;
  // local exclusive scan of bucket totals
  int v = bsum[tid];
  sc[tid] = v; __syncthreads();
  int inc0 = v;
  for (int d = 1; d < NB; d <<= 1){
    int add = (tid >= d) ? sc[tid - d] : 0;
    __syncthreads();
    inc0 += add; sc[tid] = inc0;
    __syncthreads();
  }
  sc[tid] = inc0 - v;                 // exclusive
  __syncthreads();
  int bs = sc[k];
  int be = (k < NB - 1) ? sc[k + 1] : N_EDGES;
  ncnt[tid] = 0; ncnt[tid + 256] = 0;
  __syncthreads();
  for (int i = bs + tid; i < be; i += 256)
    atomicAdd(&ncnt[ebuf[i] >> 17], 1);
  __syncthreads();
  int p = ncnt[2 * tid] + ncnt[2 * tid + 1];
  pairs[tid] = p;
  __syncthreads();
  int inc = p;
  for (int d = 1; d < 256; d <<= 1){
    int add = (tid >= d) ? pairs[tid - d] : 0;
    __syncthreads();
    inc += add; pairs[tid] = inc;
    __syncthreads();
  }
  int ex = inc - p;
  nofs[2 * tid]     = ex;
  nofs[2 * tid + 1] = ex + ncnt[2 * tid];
  __syncthreads();
  offs[k * NPB + tid]       = bs + nofs[tid];
  offs[k * NPB + tid + 256] = bs + nofs[tid + 256];
  if (k == NB - 1 && tid == 0) offs[N_NODES] = N_EDGES;
  ncnt[tid] = nofs[tid]; ncnt[tid + 256] = nofs[tid + 256];
  __syncthreads();
  for (int i = bs + tid; i < be; i += 256){
    unsigned w = ebuf[i];
    int loc = w >> 17, sv = w & 0x1FFFF;
    int pp = atomicAdd(&ncnt[loc], 1);
    srcS[bs + pp] = sv;
  }
}

// ---------------- SAGE layer-1 aggregation: mean of xb8[src] (fp8), 8 slots x 8 lanes x uint2 ----------------
__global__ void agg1_k(const unsigned* __restrict__ xb8, const int* __restrict__ offs,
                       const int* __restrict__ srcS, bf16* __restrict__ Acat1){
  int wid = threadIdx.x >> 6, lane = threadIdx.x & 63;
  int n = blockIdx.x * 4 + wid;
  int s = offs[n], e = offs[n + 1];
  int slot = lane >> 3, fl = lane & 7;          // fl covers features fl*8 .. fl*8+7
  floatx2 a0={0,0}, a1={0,0}, a2={0,0}, a3={0,0};
  floatx2 c0={0,0}, c1={0,0}, c2={0,0}, c3={0,0};
  int i = s + slot;
  for (; i + 8 < e; i += 16){
    int sv0 = srcS[i], sv1 = srcS[i + 8];
    uint2 u = *(const uint2*)(xb8 + (size_t)sv0 * 16 + fl * 2);
    uint2 v = *(const uint2*)(xb8 + (size_t)sv1 * 16 + fl * 2);
    a0 += __builtin_amdgcn_cvt_pk_f32_fp8(u.x, false);
    a1 += __builtin_amdgcn_cvt_pk_f32_fp8(u.x, true);
    a2 += __builtin_amdgcn_cvt_pk_f32_fp8(u.y, false);
    a3 += __builtin_amdgcn_cvt_pk_f32_fp8(u.y, true);
    c0 += __builtin_amdgcn_cvt_pk_f32_fp8(v.x, false);
    c1 += __builtin_amdgcn_cvt_pk_f32_fp8(v.x, true);
    c2 += __builtin_amdgcn_cvt_pk_f32_fp8(v.y, false);
    c3 += __builtin_amdgcn_cvt_pk_f32_fp8(v.y, true);
  }
  if (i < e){
    int sv0 = srcS[i];
    uint2 u = *(const uint2*)(xb8 + (size_t)sv0 * 16 + fl * 2);
    a0 += __builtin_amdgcn_cvt_pk_f32_fp8(u.x, false);
    a1 += __builtin_amdgcn_cvt_pk_f32_fp8(u.x, true);
    a2 += __builtin_amdgcn_cvt_pk_f32_fp8(u.y, false);
    a3 += __builtin_amdgcn_cvt_pk_f32_fp8(u.y, true);
  }
  a0 += c0; a1 += c1; a2 += c2; a3 += c3;
  float f[8] = {a0.x, a0.y, a1.x, a1.y, a2.x, a2.y, a3.x, a3.y};
  #pragma unroll
  for (int j = 0; j < 8; ++j){
    f[j] += __shfl_xor(f[j], 8);
    f[j] += __shfl_xor(f[j], 16);
    f[j] += __shfl_xor(f[j], 32);
  }
  if (slot == 0){
    int d = e - s; if (d < 1) d = 1;
    float inv = 1.f / (float)d;
    uint4 w;
    w.x = packbf(f[0] * inv, f[1] * inv);
    w.y = packbf(f[2] * inv, f[3] * inv);
    w.z = packbf(f[4] * inv, f[5] * inv);
    w.w = packbf(f[6] * inv, f[7] * inv);
    *(uint4*)(Acat1 + (size_t)n * 128 + fl * 8) = w;
  }
}

// ---------------- h1 (bf16, Acat2 cols 128:256) -> fp8 e4m3 (HW cvt) ----------------
__global__ void cvt8_k(const bf16* __restrict__ Acat2, unsigned* __restrict__ h1f8){
  int g = blockIdx.x * 256 + threadIdx.x;      // one thread per 4 features
  int n = g >> 5, p = g & 31;
  uint2 u = *(const uint2*)(Acat2 + (size_t)n * 256 + 128 + p * 4);
  int w = 0;
  w = __builtin_amdgcn_cvt_pk_fp8_f32(bl(u.x), bh(u.x), w, false);
  w = __builtin_amdgcn_cvt_pk_fp8_f32(bl(u.y), bh(u.y), w, true);
  h1f8[(size_t)n * 32 + p] = (unsigned)w;
}

// ---------------- SAGE layer-2 aggregation: mean of h1f8[src] (fp8), 4 slots x 16 lanes, unroll 4 ----------------
__global__ void agg2_k(const int* __restrict__ offs, const int* __restrict__ srcS,
                       const unsigned* __restrict__ h1f8, bf16* __restrict__ Acat2){
  int wid = threadIdx.x >> 6, lane = threadIdx.x & 63;
  int n = blockIdx.x * 4 + wid;
  int s = offs[n], e = offs[n + 1];
  int slot = lane >> 4, fl = lane & 15;         // fl covers features fl*8 .. fl*8+7
  floatx2 a0={0,0}, a1={0,0}, a2={0,0}, a3={0,0};
  floatx2 b0={0,0}, b1={0,0}, b2={0,0}, b3={0,0};
  floatx2 c0={0,0}, c1={0,0}, c2={0,0}, c3={0,0};
  floatx2 d0={0,0}, d1={0,0}, d2={0,0}, d3={0,0};
  int i = s + slot;
  for (; i + 12 < e; i += 16){
    int sv0 = srcS[i], sv1 = srcS[i + 4], sv2 = srcS[i + 8], sv3 = srcS[i + 12];
    uint2 u = *(const uint2*)(h1f8 + (size_t)sv0 * 32 + fl * 2);
    uint2 v = *(const uint2*)(h1f8 + (size_t)sv1 * 32 + fl * 2);
    uint2 w = *(const uint2*)(h1f8 + (size_t)sv2 * 32 + fl * 2);
    uint2 z = *(const uint2*)(h1f8 + (size_t)sv3 * 32 + fl * 2);
    a0 += __builtin_amdgcn_cvt_pk_f32_fp8(u.x, false);
    a1 += __builtin_amdgcn_cvt_pk_f32_fp8(u.x, true);
    a2 += __builtin_amdgcn_cvt_pk_f32_fp8(u.y, false);
    a3 += __builtin_amdgcn_cvt_pk_f32_fp8(u.y, true);
    b0 += __builtin_amdgcn_cvt_pk_f32_fp8(v.x, false);
    b1 += __builtin_amdgcn_cvt_pk_f32_fp8(v.x, true);
    b2 += __builtin_amdgcn_cvt_pk_f32_fp8(v.y, false);
    b3 += __builtin_amdgcn_cvt_pk_f32_fp8(v.y, true);
    c0 += __builtin_amdgcn_cvt_pk_f32_fp8(w.x, false);
    c1 += __builtin_amdgcn_cvt_pk_f32_fp8(w.x, true);
    c2 += __builtin_amdgcn_cvt_pk_f32_fp8(w.y, false);
    c3 += __builtin_amdgcn_cvt_pk_f32_fp8(w.y, true);
    d0 += __builtin_amdgcn_cvt_pk_f32_fp8(z.x, false);
    d1 += __builtin_amdgcn_cvt_pk_f32_fp8(z.x, true);
    d2 += __builtin_amdgcn_cvt_pk_f32_fp8(z.y, false);
    d3 += __builtin_amdgcn_cvt_pk_f32_fp8(z.y, true);
  }
  for (; i < e; i += 4){
    int sv0 = srcS[i];
    uint2 u = *(const uint2*)(h1f8 + (size_t)sv0 * 32 + fl * 2);
    a0 += __builtin_amdgcn_cvt_pk_f32_fp8(u.x, false);
    a1 += __builtin_amdgcn_cvt_pk_f32_fp8(u.x, true);
    a2 += __builtin_amdgcn_cvt_pk_f32_fp8(u.y, false);
    a3 += __builtin_amdgcn_cvt_pk_f32_fp8(u.y, true);
  }
  a0 += b0; a1 += b1; a2 += b2; a3 += b3;
  c0 += d0; c1 += d1; c2 += d2; c3 += d3;
  a0 += c0; a1 += c1; a2 += c2; a3 += c3;
  float f[8] = {a0.x, a0.y, a1.x, a1.y, a2.x, a2.y, a3.x, a3.y};
  #pragma unroll
  for (int j = 0; j < 8; ++j){
    f[j] += __shfl_xor(f[j], 16);
    f[j] += __shfl_xor(f[j], 32);
  }
  if (slot == 0){
    int d = e - s; if (d < 1) d = 1;
    float inv = 1.f / (float)d;
    uint4 w;
    w.x = packbf(f[0] * inv, f[1] * inv);
    w.y = packbf(f[2] * inv, f[3] * inv);
    w.z = packbf(f[4] * inv, f[5] * inv);
    w.w = packbf(f[6] * inv, f[7] * inv);
    *(uint4*)(Acat2 + (size_t)n * 256 + fl * 8) = w;
  }
}

// ---------------- generic MFMA GEMM: out[M x Ncols] = act(A[arow(M) x K] @ W[Ncols x K]^T + bias) ----------------
__global__ __launch_bounds__(256) void gemm_k(const bf16* __restrict__ A, int lda,
                                              const bf16* __restrict__ W, int K,
                                              const float* __restrict__ bias,
                                              void* __restrict__ out, int ldo, int outF32, int relu,
                                              const int* __restrict__ ridx){
  __shared__ bf16 Wl[128][136];   // +8 pad: 2-way bank aliasing only
  int tid = threadIdx.x;
  int wid = tid >> 6, lane = tid & 63;
  int l16 = lane & 15, quad = lane >> 4;
  int rowBase  = blockIdx.x * 64 + wid * 16;
  int colGroup = blockIdx.y * 128;
  int arow = rowBase + l16;
  if (ridx) arow = ridx[arow];
  floatx4 acc[8] = {};
  int nStage = K >> 7;
  for (int ks = 0; ks < nStage; ++ks){
    __syncthreads();
    for (int c = tid; c < 2048; c += 256){
      int r = c >> 4, kc = (c & 15) << 3;
      *(uint4*)(&Wl[r][kc]) = *(const uint4*)(W + (size_t)(colGroup + r) * K + ks * 128 + kc);
    }
    __syncthreads();
    for (int kk = 0; kk < 4; ++kk){
      short8 af = *(const short8*)(A + (size_t)arow * lda + ks * 128 + kk * 32 + quad * 8);
      #pragma unroll
      for (int c = 0; c < 8; ++c){
        short8 bq = *(const short8*)(&Wl[c * 16 + l16][kk * 32 + quad * 8]);
        acc[c] = __builtin_amdgcn_mfma_f32_16x16x32_bf16(af, bq, acc[c], 0, 0, 0);
      }
    }
  }
  #pragma unroll
  for (int c = 0; c < 8; ++c){
    int col = colGroup + c * 16 + l16;
    float bv = bias ? bias[col] : 0.f;
    #pragma unroll
    for (int r = 0; r < 4; ++r){
      int row = rowBase + quad * 4 + r;
      float v = acc[c][r] + bv;
      if (relu) v = fmaxf(v, 0.f);
      if (outF32) ((float*)out)[(size_t)row * ldo + col] = v;
      else        ((bf16*)out)[(size_t)row * ldo + col]  = __float2bfloat16(v);
    }
  }
}

// ---------------- pool [0,256) + flow [256,288), 512 threads ----------------
__global__ void poolflow_k(const bf16* __restrict__ ne, const int* __restrict__ starts,
                           const float* __restrict__ flow, const float* __restrict__ Wf,
                           const float* __restrict__ bfv, float* __restrict__ comb){
  __shared__ float sh[8][128];
  int bid = blockIdx.x;
  if (bid < 256){
    int b = bid;
    int q = threadIdx.x >> 6, lane = threadIdx.x & 63;   // 8 slots x 64 lanes
    int s = starts[b], e = starts[b + 1];
    float a0 = 0.f, a1 = 0.f;
    for (int i = s + q; i < e; i += 8){
      unsigned u = *(const unsigned*)(ne + (size_t)i * 128 + lane * 2);
      a0 += bl(u); a1 += bh(u);
    }
    sh[q][lane * 2] = a0; sh[q][lane * 2 + 1] = a1;
    __syncthreads();
    if (threadIdx.x < 128){
      int f = threadIdx.x;
      float tot = 0.f;
      #pragma unroll
      for (int k = 0; k < 8; ++k) tot += sh[k][f];
      int d = e - s; if (d < 1) d = 1;
      comb[b * 320 + f] = tot / (float)d;
    }
  } else {
    int g = (bid - 256) * 512 + threadIdx.x;   // 16384 = 256 batches x 64 outputs
    int b = g >> 6, j = g & 63;
    float acc = bfv[j];
    for (int k = 0; k < 16; ++k)
      acc += flow[b * 16 + k] * Wf[j * 16 + k];
    comb[b * 320 + 256 + j] = fmaxf(acc, 0.f);
  }
}

// ---------------- LSTM recurrence via MFMA: 16 batches/block, 16 blocks ----------------
__global__ __launch_bounds__(256, 1) void lstm_k(const bf16* __restrict__ Whh, const float* __restrict__ pre,
                                                 const int* __restrict__ path_len, float* __restrict__ comb){
  __shared__ bf16 hbuf[2][16][136];   // [buf][batch][dim], +8 pad
  int tid = threadIdx.x;
  int w = tid >> 6, lane = tid & 63;
  int l16 = lane & 15, quad = lane >> 4;
  int b0 = blockIdx.x * 16;

  short8 wb[4][2][4];
  #pragma unroll
  for (int q = 0; q < 4; ++q)
    #pragma unroll
    for (int hf = 0; hf < 2; ++hf){
      const bf16* rp = Whh + (size_t)(q * 128 + w * 32 + hf * 16 + l16) * 128 + quad * 8;
      #pragma unroll
      for (int ks = 0; ks < 4; ++ks) wb[q][hf][ks] = *(const short8*)(rp + ks * 32);
    }

  int lenr[4];
  #pragma unroll
  for (int r = 0; r < 4; ++r){
    int L = path_len[b0 + quad * 4 + r];
    if (L < 1) L = 1; if (L > LPATH) L = LPATH;
    lenr[r] = L;
  }
  int maxlen = 1;
  for (int i = 0; i < 16; ++i){
    int L = path_len[b0 + i];
    if (L > LPATH) L = LPATH;
    if (L > maxlen) maxlen = L;
  }

  for (int i = tid; i < 1088; i += 256) ((unsigned*)&hbuf[0][0][0])[i] = 0;

  const float* pb[4];
  #pragma unroll
  for (int r = 0; r < 4; ++r)
    pb[r] = pre + (size_t)(b0 + quad * 4 + r) * LPATH * 512 + w * 32 + l16;

  float pv[4][2][4];
  #pragma unroll
  for (int q = 0; q < 4; ++q)
    #pragma unroll
    for (int hf = 0; hf < 2; ++hf)
      #pragma unroll
      for (int r = 0; r < 4; ++r)
        pv[q][hf][r] = pb[r][q * 128 + hf * 16];

  float cst[2][4] = {}, hst[2][4] = {};

  for (int t = 0; t < maxlen; ++t){
    int cur = t & 1, nxt = cur ^ 1;
    __syncthreads();
    short8 af[4];
    #pragma unroll
    for (int ks = 0; ks < 4; ++ks)
      af[ks] = *(const short8*)(&hbuf[cur][l16][ks * 32 + quad * 8]);
    int tn = (t + 1 < maxlen) ? t + 1 : t;
    float pnext[4][2][4];
    #pragma unroll
    for (int q = 0; q < 4; ++q)
      #pragma unroll
      for (int hf = 0; hf < 2; ++hf)
        #pragma unroll
        for (int r = 0; r < 4; ++r)
          pnext[q][hf][r] = pb[r][tn * 512 + q * 128 + hf * 16];
    floatx4 acc[4][2];
    #pragma unroll
    for (int q = 0; q < 4; ++q)
      #pragma unroll
      for (int hf = 0; hf < 2; ++hf){
        acc[q][hf][0] = pv[q][hf][0]; acc[q][hf][1] = pv[q][hf][1];
        acc[q][hf][2] = pv[q][hf][2]; acc[q][hf][3] = pv[q][hf][3];
      }
    #pragma unroll
    for (int ks = 0; ks < 4; ++ks)
      #pragma unroll
      for (int q = 0; q < 4; ++q)
        #pragma unroll
        for (int hf = 0; hf < 2; ++hf)
          acc[q][hf] = __builtin_amdgcn_mfma_f32_16x16x32_bf16(af[ks], wb[q][hf][ks], acc[q][hf], 0, 0, 0);
    #pragma unroll
    for (int hf = 0; hf < 2; ++hf)
      #pragma unroll
      for (int r = 0; r < 4; ++r){
        float ig = sigf(acc[0][hf][r]);
        float fg = sigf(acc[1][hf][r]);
        float gg = tanh_fast(acc[2][hf][r]);
        float og = sigf(acc[3][hf][r]);
        float cn = fmaf(fg, cst[hf][r], ig * gg);
        float hn = og * tanh_fast(cn);
        bool vld = t < lenr[r];
        cst[hf][r] = vld ? cn : cst[hf][r];
        hst[hf][r] = vld ? hn : hst[hf][r];
        hbuf[nxt][quad * 4 + r][w * 32 + hf * 16 + l16] = __float2bfloat16(hst[hf][r]);
      }
    #pragma unroll
    for (int q = 0; q < 4; ++q)
      #pragma unroll
      for (int hf = 0; hf < 2; ++hf)
        #pragma unroll
        for (int r = 0; r < 4; ++r)
          pv[q][hf][r] = pnext[q][hf][r];
  }

  #pragma unroll
  for (int hf = 0; hf < 2; ++hf)
    #pragma unroll
    for (int r = 0; r < 4; ++r)
      comb[(b0 + quad * 4 + r) * 320 + 128 + w * 32 + hf * 16 + l16] = hst[hf][r];
}

// ---------------- scoring head (f32 weights) ----------------
__global__ void head_k(const float* __restrict__ comb, const float* __restrict__ Ws1, const float* __restrict__ bs1,
                       const float* __restrict__ Ws2, const float* __restrict__ bs2, float* __restrict__ out){
  __shared__ float cl[320];
  __shared__ float red[128];
  int b = blockIdx.x, j = threadIdx.x;   // 128 threads
  for (int k = j; k < 320; k += 128) cl[k] = comb[b * 320 + k];
  __syncthreads();
  float acc = bs1[j];
  const float4* wr = (const float4*)(Ws1 + (size_t)j * 320);
  #pragma unroll 4
  for (int kc = 0; kc < 80; ++kc){
    float4 u = wr[kc];
    int k = kc * 4;
    acc += u.x * cl[k] + u.y * cl[k + 1] + u.z * cl[k + 2] + u.w * cl[k + 3];
  }
  float hv = fmaxf(acc, 0.f);
  red[j] = hv * Ws2[j];
  __syncthreads();
  for (int s = 64; s > 0; s >>= 1){ if (j < s) red[j] += red[j + s]; __syncthreads(); }
  if (j == 0) out[b] = red[0] + bs2[0];
}

// ---------------- workspace layout (16B-aligned) ----------------
constexpr size_t OFF_OFFS   = 0;                       // (N+1) ints
constexpr size_t OFF_CNTA   = 524544;                  // NB*GB ints = 256 KB
constexpr size_t OFF_OFSA   = OFF_CNTA   + 262144;     // NB*GB ints = 256 KB
constexpr size_t OFF_BSUM   = OFF_OFSA   + 262144;     // NB ints
constexpr size_t OFF_STARTS = OFF_BSUM   + 1024;       // 257 ints
constexpr size_t OFF_SRCS   = OFF_STARTS + 2048;       // E ints = 8.4 MB
constexpr size_t OFF_WCAT1  = OFF_SRCS   + 8388608;
constexpr size_t OFF_WCAT2  = OFF_WCAT1  + 32768;
constexpr size_t OFF_WIHB   = OFF_WCAT2  + 65536;
constexpr size_t OFF_WHHB   = OFF_WIHB   + 131072;
constexpr size_t OFF_BSUMF  = OFF_WHHB   + 131072;
constexpr size_t OFF_COMB   = OFF_BSUMF  + 2048;
constexpr size_t OFF_ACAT1  = OFF_COMB   + 327680;     // N x 128 bf16 (33.5 MB); node_emb aliases after GEMM1
constexpr size_t OFF_ACAT2  = OFF_ACAT1  + 33554432;   // N x 256 bf16 (67 MB)
// aliases (lifetimes disjoint in stream order):
constexpr size_t OFF_H1F8   = OFF_ACAT1;               // N x 128 B fp8 (16.8 MB): cvt8 -> agg2; clobbered by gemm2's node_emb
constexpr size_t OFF_EBUF   = OFF_ACAT2;               // E unsigned (8.4 MB), dead before gemm1
constexpr size_t OFF_PRE    = OFF_ACAT2  + 2097152;    // 8192 x 512 f32, after gemm2
constexpr size_t OFF_XB8    = OFF_ACAT2  + 50331648;   // N x 64 B fp8 (8.4 MB), dead before gemm1 writes Acat2

extern "C" void kernel_launch(void* const* d_in, const int* in_sizes, int n_in,
                              void* d_out, int out_size, void* d_ws, size_t ws_size,
                              hipStream_t stream){
  const float* x      = (const float*)d_in[0];
  const int* edge     = (const int*)d_in[1];
  const int* batch    = (const int*)d_in[2];
  const int* path_idx = (const int*)d_in[3];
  const int* path_len = (const int*)d_in[4];
  const float* flow   = (const float*)d_in[5];
  const float* Wl1 = (const float*)d_in[6];
  const float* Wr1 = (const float*)d_in[7];
  const float* b1  = (const float*)d_in[8];
  const float* Wl2 = (const float*)d_in[9];
  const float* Wr2 = (const float*)d_in[10];
  const float* b2  = (const float*)d_in[11];
  const float* Wih = (const float*)d_in[12];
  const float* Whh = (const float*)d_in[13];
  const float* bih = (const float*)d_in[14];
  const float* bhh = (const float*)d_in[15];
  const float* Wf  = (const float*)d_in[16];
  const float* bfv = (const float*)d_in[17];
  const float* Ws1 = (const float*)d_in[18];
  const float* bs1 = (const float*)d_in[19];
  const float* Ws2 = (const float*)d_in[20];
  const float* bs2 = (const float*)d_in[21];

  char* ws = (char*)d_ws;
  int* offs    = (int*)(ws + OFF_OFFS);
  int* cntA    = (int*)(ws + OFF_CNTA);
  int* ofsA    = (int*)(ws + OFF_OFSA);
  int* bsum    = (int*)(ws + OFF_BSUM);
  int* starts  = (int*)(ws + OFF_STARTS);
  int* srcS    = (int*)(ws + OFF_SRCS);
  bf16* Wcat1  = (bf16*)(ws + OFF_WCAT1);
  bf16* Wcat2  = (bf16*)(ws + OFF_WCAT2);
  bf16* WihB   = (bf16*)(ws + OFF_WIHB);
  bf16* WhhB   = (bf16*)(ws + OFF_WHHB);
  float* bsumF = (float*)(ws + OFF_BSUMF);
  float* comb  = (float*)(ws + OFF_COMB);
  bf16* Acat1  = (bf16*)(ws + OFF_ACAT1);
  bf16* node_emb = Acat1;                       // alias: Acat1 dead after GEMM1
  bf16* Acat2  = (bf16*)(ws + OFF_ACAT2);
  unsigned* h1f8 = (unsigned*)(ws + OFF_H1F8);  // alias over Acat1 (dead between gemm1 and gemm2)
  unsigned* ebuf = (unsigned*)(ws + OFF_EBUF);
  float* pre   = (float*)(ws + OFF_PRE);
  unsigned* xb8 = (unsigned*)(ws + OFF_XB8);

  mega0_k<<<9156, 256, 0, stream>>>(x, xb8, Acat1, edge + N_EDGES, cntA,
                                    Wl1, Wr1, Wl2, Wr2, Wih, Whh, bih, bhh,
                                    Wcat1, Wcat2, WihB, WhhB, bsumF, batch, starts);
  scan1_k<<<NB, 256, 0, stream>>>(cntA, ofsA, bsum);
  passA2_k<<<GB, 256, 0, stream>>>(edge, edge + N_EDGES, ofsA, bsum, ebuf);
  passB_k<<<NB, 256, 0, stream>>>(ebuf, bsum, offs, srcS);
  agg1_k<<<N_NODES / 4, 256, 0, stream>>>(xb8, offs, srcS, Acat1);
  gemm_k<<<dim3(N_NODES / 64, 1), 256, 0, stream>>>(Acat1, 128, Wcat1, 128, b1, Acat2 + 128, 256, 0, 1, nullptr);
  cvt8_k<<<N_NODES / 8, 256, 0, stream>>>(Acat2, h1f8);
  agg2_k<<<N_NODES / 4, 256, 0, stream>>>(offs, srcS, h1f8, Acat2);
  gemm_k<<<dim3(N_NODES / 64, 1), 256, 0, stream>>>(Acat2, 256, Wcat2, 256, b2, node_emb, 128, 0, 1, nullptr);
  poolflow_k<<<288, 512, 0, stream>>>(node_emb, starts, flow, Wf, bfv, comb);
  gemm_k<<<dim3(BATCHES * LPATH / 64, 4), 256, 0, stream>>>(node_emb, 128, WihB, 128, bsumF, pre, 512, 1, 0, path_idx);
  lstm_k<<<BATCHES / 16, 256, 0, stream>>>(WhhB, pre, path_len, comb);
  head_k<<<BATCHES, 128, 0, stream>>>(comb, Ws1, bs1, Ws2, bs2, (float*)d_out);
}

// Round 10
// 424.714 us; speedup vs baseline: 1.0910x; 1.0329x over previous
//
#include <hip/hip_runtime.h>
#include <hip/hip_bf16.h>

#define N_NODES 131072
#define N_EDGES 2097152
#define BATCHES 256
#define LPATH   32
// two-level counting sort params
#define NB   256          // coarse buckets (512 nodes each)
#define NPB  512          // nodes per bucket
#define GB   256          // cntA/passA2 blocks
#define EPB  8192         // edges per block

typedef __hip_bfloat16 bf16;
using short8  = __attribute__((ext_vector_type(8))) short;
using floatx4 = __attribute__((ext_vector_type(4))) float;
using floatx2 = __attribute__((ext_vector_type(2))) float;

__device__ __forceinline__ float bl(unsigned u){ union {unsigned x; float f;} c; c.x = u << 16; return c.f; }
__device__ __forceinline__ float bh(unsigned u){ union {unsigned x; float f;} c; c.x = u & 0xffff0000u; return c.f; }
__device__ __forceinline__ unsigned packbf(float lo, float hi){
  bf16 l = __float2bfloat16(lo), h = __float2bfloat16(hi);
  unsigned short lu, hu;
  __builtin_memcpy(&lu, &l, 2); __builtin_memcpy(&hu, &h, 2);
  return (unsigned)lu | ((unsigned)hu << 16);
}
__device__ __forceinline__ float frcp(float x){ return __builtin_amdgcn_rcpf(x); }
__device__ __forceinline__ float sigf(float x){ return frcp(1.f + __expf(-x)); }
__device__ __forceinline__ float tanh_fast(float x){ return fmaf(2.f, frcp(1.f + __expf(-2.f * x)), -1.f); }

// ---------------- mega0: xb8 [0,8192) | cntA [8192,8448) | prep [8448,9155) | bounds {9155} ----------------
__global__ void mega0_k(const float* __restrict__ x, unsigned* __restrict__ xb8, bf16* __restrict__ Acat1,
                        const int* __restrict__ dst, int* __restrict__ cntA,
                        const float* __restrict__ Wl1, const float* __restrict__ Wr1,
                        const float* __restrict__ Wl2, const float* __restrict__ Wr2,
                        const float* __restrict__ Wih, const float* __restrict__ Whh,
                        const float* __restrict__ bih, const float* __restrict__ bhh,
                        bf16* __restrict__ Wcat1, bf16* __restrict__ Wcat2,
                        bf16* __restrict__ WihB, bf16* __restrict__ WhhB, float* __restrict__ bsumF,
                        const int* __restrict__ batch, int* __restrict__ starts){
  __shared__ int h[NB];
  int bid = blockIdx.x, tid = threadIdx.x;
  if (bid < 8192){                     // x (f32) -> fp8 rows + bf16 self-half of Acat1
    int g = bid * 256 + tid;           // one thread per 4 features
    int n = g >> 4, p = g & 15;
    float4 v = *(const float4*)(x + (size_t)n * 64 + p * 4);
    uint2 wb; wb.x = packbf(v.x, v.y); wb.y = packbf(v.z, v.w);
    *(uint2*)(Acat1 + (size_t)n * 128 + 64 + p * 4) = wb;
    int w = 0;
    w = __builtin_amdgcn_cvt_pk_fp8_f32(v.x, v.y, w, false);
    w = __builtin_amdgcn_cvt_pk_fp8_f32(v.z, v.w, w, true);
    xb8[(size_t)n * 16 + p] = (unsigned)w;
  } else if (bid < 8448){              // cntA: coarse bucket histogram
    int cb = bid - 8192;
    h[tid] = 0;
    __syncthreads();
    int base = cb * EPB;
    #pragma unroll
    for (int i = 0; i < EPB / 256; ++i){
      int d = dst[base + i * 256 + tid];
      atomicAdd(&h[d >> 9], 1);
    }
    __syncthreads();
    cntA[tid * GB + cb] = h[tid];
  } else if (bid < 9155){              // prep: f32 weights -> bf16
    int g = (bid - 8448) * 256 + tid;
    if (g < 16384) {                   // Wcat1: 128 x 128 (Wl1 | Wr1)
      int hh = g >> 7, k = g & 127;
      float v = (k < 64) ? Wl1[hh * 64 + k] : Wr1[hh * 64 + (k - 64)];
      Wcat1[g] = __float2bfloat16(v);
    } else if (g < 49152) {            // Wcat2: 128 x 256 (Wl2 | Wr2)
      int q = g - 16384;
      int hh = q >> 8, k = q & 255;
      float v = (k < 128) ? Wl2[hh * 128 + k] : Wr2[hh * 128 + (k - 128)];
      Wcat2[q] = __float2bfloat16(v);
    } else if (g < 114688) {           // WihB: 512 x 128
      int q = g - 49152;
      WihB[q] = __float2bfloat16(Wih[q]);
    } else if (g < 180224) {           // WhhB: 512 x 128
      int q = g - 114688;
      WhhB[q] = __float2bfloat16(Whh[q]);
    } else if (g < 180736) {           // bsumF = bih + bhh (f32)
      int k = g - 180224;
      bsumF[k] = bih[k] + bhh[k];
    }
  } else {                             // bounds: segment starts (batch sorted)
    int b = tid;
    int lo = 0, hi = N_NODES;
    while (lo < hi){ int mid = (lo + hi) >> 1; if (batch[mid] < b) lo = mid + 1; else hi = mid; }
    starts[b] = lo;
    if (b == 0) starts[BATCHES] = N_NODES;
  }
}

// ---------------- per-bucket exclusive scan (one block per bucket) + bucket totals ----------------
__global__ void scan1_k(const int* __restrict__ cnt, int* __restrict__ ofsA, int* __restrict__ bsum){
  __shared__ int sh[256];
  int t = threadIdx.x, i = blockIdx.x * 256 + t;
  int v = cnt[i];
  sh[t] = v; __syncthreads();
  int inc = v;
  for (int d = 1; d < 256; d <<= 1){
    int add = (t >= d) ? sh[t - d] : 0;
    __syncthreads();
    inc += add; sh[t] = inc;
    __syncthreads();
  }
  ofsA[i] = inc - v;
  if (t == 255) bsum[blockIdx.x] = inc;
}

// ---------------- passA2: place packed (src | localNode<<17); bucket-total scan computed locally ----------------
__global__ void passA2_k(const int* __restrict__ src, const int* __restrict__ dst,
                         const int* __restrict__ ofsA, const int* __restrict__ bsum,
                         unsigned* __restrict__ ebuf){
  __shared__ int cur[NB];
  __shared__ int sc[NB];
  int tid = threadIdx.x;
  int v = bsum[tid];
  sc[tid] = v; __syncthreads();
  int inc = v;
  for (int d = 1; d < NB; d <<= 1){
    int add = (tid >= d) ? sc[tid - d] : 0;
    __syncthreads();
    inc += add; sc[tid] = inc;
    __syncthreads();
  }
  cur[tid] = ofsA[tid * GB + blockIdx.x] + (inc - v);
  __syncthreads();
  int base = blockIdx.x * EPB;
  #pragma unroll
  for (int i = 0; i < EPB / 256; ++i){
    int e = base + i * 256 + tid;
    int s = src[e], d = dst[e];
    int p = atomicAdd(&cur[d >> 9], 1);
    ebuf[p] = (unsigned)s | ((unsigned)(d & (NPB - 1)) << 17);
  }
}

// ---------------- passB: per-node CSR within bucket; bucket-total scan computed locally ----------------
__global__ void passB_k(const unsigned* __restrict__ ebuf, const int* __restrict__ bsum,
                        int* __restrict__ offs, int* __restrict__ srcS){
  __shared__ int ncnt[NPB];
  __shared__ int pairs[256];
  __shared__ int nofs[NPB];
  __shared__ int sc[NB];
  int k = blockIdx.x, tid = threadIdx.x;
  int v = bsum[tid];
  sc[tid] = v; __syncthreads();
  int inc0 = v;
  for (int d = 1; d < NB; d <<= 1){
    int add = (tid >= d) ? sc[tid - d] : 0;
    __syncthreads();
    inc0 += add; sc[tid] = inc0;
    __syncthreads();
  }
  sc[tid] = inc0 - v;                 // exclusive
  __syncthreads();
  int bs = sc[k];
  int be = (k < NB - 1) ? sc[k + 1] : N_EDGES;
  ncnt[tid] = 0; ncnt[tid + 256] = 0;
  __syncthreads();
  for (int i = bs + tid; i < be; i += 256)
    atomicAdd(&ncnt[ebuf[i] >> 17], 1);
  __syncthreads();
  int p = ncnt[2 * tid] + ncnt[2 * tid + 1];
  pairs[tid] = p;
  __syncthreads();
  int inc = p;
  for (int d = 1; d < 256; d <<= 1){
    int add = (tid >= d) ? pairs[tid - d] : 0;
    __syncthreads();
    inc += add; pairs[tid] = inc;
    __syncthreads();
  }
  int ex = inc - p;
  nofs[2 * tid]     = ex;
  nofs[2 * tid + 1] = ex + ncnt[2 * tid];
  __syncthreads();
  offs[k * NPB + tid]       = bs + nofs[tid];
  offs[k * NPB + tid + 256] = bs + nofs[tid + 256];
  if (k == NB - 1 && tid == 0) offs[N_NODES] = N_EDGES;
  ncnt[tid] = nofs[tid]; ncnt[tid + 256] = nofs[tid + 256];
  __syncthreads();
  for (int i = bs + tid; i < be; i += 256){
    unsigned w = ebuf[i];
    int loc = w >> 17, sv = w & 0x1FFFF;
    int pp = atomicAdd(&ncnt[loc], 1);
    srcS[bs + pp] = sv;
  }
}

// ---------------- SAGE layer-1 aggregation: mean of xb8[src] (fp8), 8 slots x 8 lanes x uint2 ----------------
__global__ void agg1_k(const unsigned* __restrict__ xb8, const int* __restrict__ offs,
                       const int* __restrict__ srcS, bf16* __restrict__ Acat1){
  int wid = threadIdx.x >> 6, lane = threadIdx.x & 63;
  int n = blockIdx.x * 4 + wid;
  int s = offs[n], e = offs[n + 1];
  int slot = lane >> 3, fl = lane & 7;          // fl covers features fl*8 .. fl*8+7
  floatx2 a0={0,0}, a1={0,0}, a2={0,0}, a3={0,0};
  floatx2 c0={0,0}, c1={0,0}, c2={0,0}, c3={0,0};
  int i = s + slot;
  for (; i + 8 < e; i += 16){
    int sv0 = srcS[i], sv1 = srcS[i + 8];
    uint2 u = *(const uint2*)(xb8 + (size_t)sv0 * 16 + fl * 2);
    uint2 v = *(const uint2*)(xb8 + (size_t)sv1 * 16 + fl * 2);
    a0 += __builtin_amdgcn_cvt_pk_f32_fp8(u.x, false);
    a1 += __builtin_amdgcn_cvt_pk_f32_fp8(u.x, true);
    a2 += __builtin_amdgcn_cvt_pk_f32_fp8(u.y, false);
    a3 += __builtin_amdgcn_cvt_pk_f32_fp8(u.y, true);
    c0 += __builtin_amdgcn_cvt_pk_f32_fp8(v.x, false);
    c1 += __builtin_amdgcn_cvt_pk_f32_fp8(v.x, true);
    c2 += __builtin_amdgcn_cvt_pk_f32_fp8(v.y, false);
    c3 += __builtin_amdgcn_cvt_pk_f32_fp8(v.y, true);
  }
  if (i < e){
    int sv0 = srcS[i];
    uint2 u = *(const uint2*)(xb8 + (size_t)sv0 * 16 + fl * 2);
    a0 += __builtin_amdgcn_cvt_pk_f32_fp8(u.x, false);
    a1 += __builtin_amdgcn_cvt_pk_f32_fp8(u.x, true);
    a2 += __builtin_amdgcn_cvt_pk_f32_fp8(u.y, false);
    a3 += __builtin_amdgcn_cvt_pk_f32_fp8(u.y, true);
  }
  a0 += c0; a1 += c1; a2 += c2; a3 += c3;
  float f[8] = {a0.x, a0.y, a1.x, a1.y, a2.x, a2.y, a3.x, a3.y};
  #pragma unroll
  for (int j = 0; j < 8; ++j){
    f[j] += __shfl_xor(f[j], 8);
    f[j] += __shfl_xor(f[j], 16);
    f[j] += __shfl_xor(f[j], 32);
  }
  if (slot == 0){
    int d = e - s; if (d < 1) d = 1;
    float inv = 1.f / (float)d;
    uint4 w;
    w.x = packbf(f[0] * inv, f[1] * inv);
    w.y = packbf(f[2] * inv, f[3] * inv);
    w.z = packbf(f[4] * inv, f[5] * inv);
    w.w = packbf(f[6] * inv, f[7] * inv);
    *(uint4*)(Acat1 + (size_t)n * 128 + fl * 8) = w;
  }
}

// ---------------- gemm1 + fused fp8 conversion: h1B (bf16 N x 128) and h1f8 (fp8 N x 128B) ----------------
// A = Acat1 (N x 128 bf16), W = Wcat1 (128 x 128), relu
__global__ __launch_bounds__(256) void gemmf8_k(const bf16* __restrict__ A, const bf16* __restrict__ W,
                                                const float* __restrict__ bias,
                                                bf16* __restrict__ h1B, unsigned* __restrict__ h1f8){
  __shared__ bf16 Wl[128][136];
  __shared__ unsigned char f8t[64][144];   // +16 pad: spread banks, keep 16B alignment
  int tid = threadIdx.x;
  int wid = tid >> 6, lane = tid & 63;
  int l16 = lane & 15, quad = lane >> 4;
  int rowBase = blockIdx.x * 64 + wid * 16;
  floatx4 acc[8] = {};
  for (int c = tid; c < 2048; c += 256){
    int r = c >> 4, kc = (c & 15) << 3;
    *(uint4*)(&Wl[r][kc]) = *(const uint4*)(W + (size_t)r * 128 + kc);
  }
  __syncthreads();
  for (int kk = 0; kk < 4; ++kk){
    short8 af = *(const short8*)(A + (size_t)(rowBase + l16) * 128 + kk * 32 + quad * 8);
    #pragma unroll
    for (int c = 0; c < 8; ++c){
      short8 bq = *(const short8*)(&Wl[c * 16 + l16][kk * 32 + quad * 8]);
      acc[c] = __builtin_amdgcn_mfma_f32_16x16x32_bf16(af, bq, acc[c], 0, 0, 0);
    }
  }
  #pragma unroll
  for (int c = 0; c < 8; ++c){
    int col = c * 16 + l16;
    float bv = bias[col];
    #pragma unroll
    for (int r = 0; r < 4; ++r){
      int rl = wid * 16 + quad * 4 + r;
      float v = fmaxf(acc[c][r] + bv, 0.f);
      h1B[(size_t)(blockIdx.x * 64 + rl) * 128 + col] = __float2bfloat16(v);
      unsigned pk = (unsigned)__builtin_amdgcn_cvt_pk_fp8_f32(v, v, 0, false);
      f8t[rl][col] = (unsigned char)(pk & 0xFF);
    }
  }
  __syncthreads();
  for (int it = tid; it < 512; it += 256){
    int row = it >> 3, seg = it & 7;
    uint4 val = *(const uint4*)(&f8t[row][seg * 16]);
    *(uint4*)((char*)h1f8 + (size_t)(blockIdx.x * 64 + row) * 128 + seg * 16) = val;
  }
}

// ---------------- SAGE layer-2 aggregation: mean of h1f8[src] (fp8), 4 slots x 16 lanes x uint2 ----------------
__global__ void agg2_k(const int* __restrict__ offs, const int* __restrict__ srcS,
                       const unsigned* __restrict__ h1f8, bf16* __restrict__ meanB){
  int wid = threadIdx.x >> 6, lane = threadIdx.x & 63;
  int n = blockIdx.x * 4 + wid;
  int s = offs[n], e = offs[n + 1];
  int slot = lane >> 4, fl = lane & 15;         // fl covers features fl*8 .. fl*8+7
  floatx2 a0={0,0}, a1={0,0}, a2={0,0}, a3={0,0};
  floatx2 c0={0,0}, c1={0,0}, c2={0,0}, c3={0,0};
  int i = s + slot;
  for (; i + 4 < e; i += 8){
    int sv0 = srcS[i], sv1 = srcS[i + 4];
    uint2 u = *(const uint2*)(h1f8 + (size_t)sv0 * 32 + fl * 2);
    uint2 v = *(const uint2*)(h1f8 + (size_t)sv1 * 32 + fl * 2);
    a0 += __builtin_amdgcn_cvt_pk_f32_fp8(u.x, false);
    a1 += __builtin_amdgcn_cvt_pk_f32_fp8(u.x, true);
    a2 += __builtin_amdgcn_cvt_pk_f32_fp8(u.y, false);
    a3 += __builtin_amdgcn_cvt_pk_f32_fp8(u.y, true);
    c0 += __builtin_amdgcn_cvt_pk_f32_fp8(v.x, false);
    c1 += __builtin_amdgcn_cvt_pk_f32_fp8(v.x, true);
    c2 += __builtin_amdgcn_cvt_pk_f32_fp8(v.y, false);
    c3 += __builtin_amdgcn_cvt_pk_f32_fp8(v.y, true);
  }
  if (i < e){
    int sv0 = srcS[i];
    uint2 u = *(const uint2*)(h1f8 + (size_t)sv0 * 32 + fl * 2);
    a0 += __builtin_amdgcn_cvt_pk_f32_fp8(u.x, false);
    a1 += __builtin_amdgcn_cvt_pk_f32_fp8(u.x, true);
    a2 += __builtin_amdgcn_cvt_pk_f32_fp8(u.y, false);
    a3 += __builtin_amdgcn_cvt_pk_f32_fp8(u.y, true);
  }
  a0 += c0; a1 += c1; a2 += c2; a3 += c3;
  float f[8] = {a0.x, a0.y, a1.x, a1.y, a2.x, a2.y, a3.x, a3.y};
  #pragma unroll
  for (int j = 0; j < 8; ++j){
    f[j] += __shfl_xor(f[j], 16);
    f[j] += __shfl_xor(f[j], 32);
  }
  if (slot == 0){
    int d = e - s; if (d < 1) d = 1;
    float inv = 1.f / (float)d;
    uint4 w;
    w.x = packbf(f[0] * inv, f[1] * inv);
    w.y = packbf(f[2] * inv, f[3] * inv);
    w.z = packbf(f[4] * inv, f[5] * inv);
    w.w = packbf(f[6] * inv, f[7] * inv);
    *(uint4*)(meanB + (size_t)n * 128 + fl * 8) = w;
  }
}

// ---------------- gemm2 split-A: A cols 0:128 from meanB, 128:256 from h1B; out = node_emb ----------------
__global__ __launch_bounds__(256) void gemm2sp_k(const bf16* __restrict__ A0, const bf16* __restrict__ A1,
                                                 const bf16* __restrict__ W, const float* __restrict__ bias,
                                                 bf16* __restrict__ out){
  __shared__ bf16 Wl[128][136];
  int tid = threadIdx.x;
  int wid = tid >> 6, lane = tid & 63;
  int l16 = lane & 15, quad = lane >> 4;
  int rowBase = blockIdx.x * 64 + wid * 16;
  floatx4 acc[8] = {};
  #pragma unroll
  for (int ks = 0; ks < 2; ++ks){
    __syncthreads();
    for (int c = tid; c < 2048; c += 256){
      int r = c >> 4, kc = (c & 15) << 3;
      *(uint4*)(&Wl[r][kc]) = *(const uint4*)(W + (size_t)r * 256 + ks * 128 + kc);
    }
    __syncthreads();
    const bf16* Ab = ks ? A1 : A0;
    for (int kk = 0; kk < 4; ++kk){
      short8 af = *(const short8*)(Ab + (size_t)(rowBase + l16) * 128 + kk * 32 + quad * 8);
      #pragma unroll
      for (int c = 0; c < 8; ++c){
        short8 bq = *(const short8*)(&Wl[c * 16 + l16][kk * 32 + quad * 8]);
        acc[c] = __builtin_amdgcn_mfma_f32_16x16x32_bf16(af, bq, acc[c], 0, 0, 0);
      }
    }
  }
  #pragma unroll
  for (int c = 0; c < 8; ++c){
    int col = c * 16 + l16;
    float bv = bias[col];
    #pragma unroll
    for (int r = 0; r < 4; ++r){
      int row = rowBase + quad * 4 + r;
      out[(size_t)row * 128 + col] = __float2bfloat16(fmaxf(acc[c][r] + bv, 0.f));
    }
  }
}

// ---------------- tail0: blocks [0,512) path pre-GEMM | [512,768) pool | [768,832) flow ----------------
__global__ __launch_bounds__(256) void tail0_k(const bf16* __restrict__ ne, const bf16* __restrict__ W,
                                               const float* __restrict__ bias, float* __restrict__ pre,
                                               const int* __restrict__ ridx,
                                               const int* __restrict__ starts,
                                               const float* __restrict__ flow, const float* __restrict__ Wf,
                                               const float* __restrict__ bfv, float* __restrict__ comb){
  __shared__ bf16 Wl[128][136];
  __shared__ float sh[4][128];
  int bid = blockIdx.x, tid = threadIdx.x;
  if (bid < 512){                       // pre = act-free GEMM: pre[r][c] = ne[ridx[r]] . W[c] + bias[c]
    int bx = bid >> 2, by = bid & 3;
    int wid = tid >> 6, lane = tid & 63;
    int l16 = lane & 15, quad = lane >> 4;
    int rowBase = bx * 64 + wid * 16;
    int colGroup = by * 128;
    int arow = ridx[rowBase + l16];
    floatx4 acc[8] = {};
    for (int c = tid; c < 2048; c += 256){
      int r = c >> 4, kc = (c & 15) << 3;
      *(uint4*)(&Wl[r][kc]) = *(const uint4*)(W + (size_t)(colGroup + r) * 128 + kc);
    }
    __syncthreads();
    for (int kk = 0; kk < 4; ++kk){
      short8 af = *(const short8*)(ne + (size_t)arow * 128 + kk * 32 + quad * 8);
      #pragma unroll
      for (int c = 0; c < 8; ++c){
        short8 bq = *(const short8*)(&Wl[c * 16 + l16][kk * 32 + quad * 8]);
        acc[c] = __builtin_amdgcn_mfma_f32_16x16x32_bf16(af, bq, acc[c], 0, 0, 0);
      }
    }
    #pragma unroll
    for (int c = 0; c < 8; ++c){
      int col = colGroup + c * 16 + l16;
      float bv = bias[col];
      #pragma unroll
      for (int r = 0; r < 4; ++r){
        int row = rowBase + quad * 4 + r;
        pre[(size_t)row * 512 + col] = acc[c][r] + bv;
      }
    }
  } else if (bid < 768){                // graph mean pooling (4 row-slots x 64 lanes)
    int b = bid - 512;
    int q = tid >> 6, lane = tid & 63;
    int s = starts[b], e = starts[b + 1];
    float a0 = 0.f, a1 = 0.f;
    for (int i = s + q; i < e; i += 4){
      unsigned u = *(const unsigned*)(ne + (size_t)i * 128 + lane * 2);
      a0 += bl(u); a1 += bh(u);
    }
    sh[q][lane * 2] = a0; sh[q][lane * 2 + 1] = a1;
    __syncthreads();
    if (tid < 128){
      int f = tid;
      float tot = sh[0][f] + sh[1][f] + sh[2][f] + sh[3][f];
      int d = e - s; if (d < 1) d = 1;
      comb[b * 320 + f] = tot / (float)d;
    }
  } else {                              // flow MLP
    int g = (bid - 768) * 256 + tid;    // 16384 = 256 batches x 64 outputs
    int b = g >> 6, j = g & 63;
    float acc = bfv[j];
    for (int k = 0; k < 16; ++k)
      acc += flow[b * 16 + k] * Wf[j * 16 + k];
    comb[b * 320 + 256 + j] = fmaxf(acc, 0.f);
  }
}

// ---------------- LSTM recurrence via MFMA: 16 batches/block, 16 blocks ----------------
__global__ __launch_bounds__(256, 1) void lstm_k(const bf16* __restrict__ Whh, const float* __restrict__ pre,
                                                 const int* __restrict__ path_len, float* __restrict__ comb){
  __shared__ bf16 hbuf[2][16][136];   // [buf][batch][dim], +8 pad
  int tid = threadIdx.x;
  int w = tid >> 6, lane = tid & 63;
  int l16 = lane & 15, quad = lane >> 4;
  int b0 = blockIdx.x * 16;

  short8 wb[4][2][4];
  #pragma unroll
  for (int q = 0; q < 4; ++q)
    #pragma unroll
    for (int hf = 0; hf < 2; ++hf){
      const bf16* rp = Whh + (size_t)(q * 128 + w * 32 + hf * 16 + l16) * 128 + quad * 8;
      #pragma unroll
      for (int ks = 0; ks < 4; ++ks) wb[q][hf][ks] = *(const short8*)(rp + ks * 32);
    }

  int lenr[4];
  #pragma unroll
  for (int r = 0; r < 4; ++r){
    int L = path_len[b0 + quad * 4 + r];
    if (L < 1) L = 1; if (L > LPATH) L = LPATH;
    lenr[r] = L;
  }
  int maxlen = 1;
  for (int i = 0; i < 16; ++i){
    int L = path_len[b0 + i];
    if (L > LPATH) L = LPATH;
    if (L > maxlen) maxlen = L;
  }

  for (int i = tid; i < 1088; i += 256) ((unsigned*)&hbuf[0][0][0])[i] = 0;

  const float* pb[4];
  #pragma unroll
  for (int r = 0; r < 4; ++r)
    pb[r] = pre + (size_t)(b0 + quad * 4 + r) * LPATH * 512 + w * 32 + l16;

  float pv[4][2][4];
  #pragma unroll
  for (int q = 0; q < 4; ++q)
    #pragma unroll
    for (int hf = 0; hf < 2; ++hf)
      #pragma unroll
      for (int r = 0; r < 4; ++r)
        pv[q][hf][r] = pb[r][q * 128 + hf * 16];

  float cst[2][4] = {}, hst[2][4] = {};

  for (int t = 0; t < maxlen; ++t){
    int cur = t & 1, nxt = cur ^ 1;
    __syncthreads();
    short8 af[4];
    #pragma unroll
    for (int ks = 0; ks < 4; ++ks)
      af[ks] = *(const short8*)(&hbuf[cur][l16][ks * 32 + quad * 8]);
    int tn = (t + 1 < maxlen) ? t + 1 : t;
    float pnext[4][2][4];
    #pragma unroll
    for (int q = 0; q < 4; ++q)
      #pragma unroll
      for (int hf = 0; hf < 2; ++hf)
        #pragma unroll
        for (int r = 0; r < 4; ++r)
          pnext[q][hf][r] = pb[r][tn * 512 + q * 128 + hf * 16];
    floatx4 acc[4][2];
    #pragma unroll
    for (int q = 0; q < 4; ++q)
      #pragma unroll
      for (int hf = 0; hf < 2; ++hf){
        acc[q][hf][0] = pv[q][hf][0]; acc[q][hf][1] = pv[q][hf][1];
        acc[q][hf][2] = pv[q][hf][2]; acc[q][hf][3] = pv[q][hf][3];
      }
    #pragma unroll
    for (int ks = 0; ks < 4; ++ks)
      #pragma unroll
      for (int q = 0; q < 4; ++q)
        #pragma unroll
        for (int hf = 0; hf < 2; ++hf)
          acc[q][hf] = __builtin_amdgcn_mfma_f32_16x16x32_bf16(af[ks], wb[q][hf][ks], acc[q][hf], 0, 0, 0);
    #pragma unroll
    for (int hf = 0; hf < 2; ++hf)
      #pragma unroll
      for (int r = 0; r < 4; ++r){
        float ig = sigf(acc[0][hf][r]);
        float fg = sigf(acc[1][hf][r]);
        float gg = tanh_fast(acc[2][hf][r]);
        float og = sigf(acc[3][hf][r]);
        float cn = fmaf(fg, cst[hf][r], ig * gg);
        float hn = og * tanh_fast(cn);
        bool vld = t < lenr[r];
        cst[hf][r] = vld ? cn : cst[hf][r];
        hst[hf][r] = vld ? hn : hst[hf][r];
        hbuf[nxt][quad * 4 + r][w * 32 + hf * 16 + l16] = __float2bfloat16(hst[hf][r]);
      }
    #pragma unroll
    for (int q = 0; q < 4; ++q)
      #pragma unroll
      for (int hf = 0; hf < 2; ++hf)
        #pragma unroll
        for (int r = 0; r < 4; ++r)
          pv[q][hf][r] = pnext[q][hf][r];
  }

  #pragma unroll
  for (int hf = 0; hf < 2; ++hf)
    #pragma unroll
    for (int r = 0; r < 4; ++r)
      comb[(b0 + quad * 4 + r) * 320 + 128 + w * 32 + hf * 16 + l16] = hst[hf][r];
}

// ---------------- scoring head (f32 weights) ----------------
__global__ void head_k(const float* __restrict__ comb, const float* __restrict__ Ws1, const float* __restrict__ bs1,
                       const float* __restrict__ Ws2, const float* __restrict__ bs2, float* __restrict__ out){
  __shared__ float cl[320];
  __shared__ float red[128];
  int b = blockIdx.x, j = threadIdx.x;   // 128 threads
  for (int k = j; k < 320; k += 128) cl[k] = comb[b * 320 + k];
  __syncthreads();
  float acc = bs1[j];
  const float4* wr = (const float4*)(Ws1 + (size_t)j * 320);
  #pragma unroll 4
  for (int kc = 0; kc < 80; ++kc){
    float4 u = wr[kc];
    int k = kc * 4;
    acc += u.x * cl[k] + u.y * cl[k + 1] + u.z * cl[k + 2] + u.w * cl[k + 3];
  }
  float hv = fmaxf(acc, 0.f);
  red[j] = hv * Ws2[j];
  __syncthreads();
  for (int s = 64; s > 0; s >>= 1){ if (j < s) red[j] += red[j + s]; __syncthreads(); }
  if (j == 0) out[b] = red[0] + bs2[0];
}

// ---------------- workspace layout (16B-aligned) ----------------
constexpr size_t OFF_OFFS   = 0;                       // (N+1) ints
constexpr size_t OFF_CNTA   = 524544;                  // NB*GB ints = 256 KB
constexpr size_t OFF_OFSA   = OFF_CNTA   + 262144;     // NB*GB ints
constexpr size_t OFF_BSUM   = OFF_OFSA   + 262144;     // NB ints
constexpr size_t OFF_STARTS = OFF_BSUM   + 1024;       // 257 ints
constexpr size_t OFF_SRCS   = OFF_STARTS + 2048;       // E ints = 8.4 MB
constexpr size_t OFF_WCAT1  = OFF_SRCS   + 8388608;
constexpr size_t OFF_WCAT2  = OFF_WCAT1  + 32768;
constexpr size_t OFF_WIHB   = OFF_WCAT2  + 65536;
constexpr size_t OFF_WHHB   = OFF_WIHB   + 131072;
constexpr size_t OFF_BSUMF  = OFF_WHHB   + 131072;
constexpr size_t OFF_COMB   = OFF_BSUMF  + 2048;
// Region R1 (33.5 MB): Acat1 [mega0/agg1 -> gemmf8 reads] then meanB [agg2 writes -> gemm2sp reads]
constexpr size_t OFF_R1     = OFF_COMB   + 327680;
// Region R2 (64 MiB), aliased sub-lifetimes:
constexpr size_t OFF_R2     = OFF_R1     + 33554432;
constexpr size_t OFF_EBUF   = OFF_R2;                  // E uint (8.4 MB): sort only
constexpr size_t OFF_H1B    = OFF_R2;                  // N x 128 bf16 (33.5 MB): gemmf8 -> gemm2sp
constexpr size_t OFF_PRE    = OFF_R2;                  // 8192 x 512 f32 (16.8 MB): tail0 -> lstm (h1B dead)
constexpr size_t OFF_XB8    = OFF_R2 + 33554432;       // N x 64 B fp8 (8.4 MB): mega0 -> agg1
constexpr size_t OFF_H1F8   = OFF_R2 + 33554432;       // N x 128 B fp8 (16.8 MB): gemmf8 -> agg2 (xb8 dead)
constexpr size_t OFF_NE     = OFF_R2 + 33554432;       // N x 128 bf16 (33.5 MB): gemm2sp -> tail0 (h1f8 dead)

extern "C" void kernel_launch(void* const* d_in, const int* in_sizes, int n_in,
                              void* d_out, int out_size, void* d_ws, size_t ws_size,
                              hipStream_t stream){
  const float* x      = (const float*)d_in[0];
  const int* edge     = (const int*)d_in[1];
  const int* batch    = (const int*)d_in[2];
  const int* path_idx = (const int*)d_in[3];
  const int* path_len = (const int*)d_in[4];
  const float* flow   = (const float*)d_in[5];
  const float* Wl1 = (const float*)d_in[6];
  const float* Wr1 = (const float*)d_in[7];
  const float* b1  = (const float*)d_in[8];
  const float* Wl2 = (const float*)d_in[9];
  const float* Wr2 = (const float*)d_in[10];
  const float* b2  = (const float*)d_in[11];
  const float* Wih = (const float*)d_in[12];
  const float* Whh = (const float*)d_in[13];
  const float* bih = (const float*)d_in[14];
  const float* bhh = (const float*)d_in[15];
  const float* Wf  = (const float*)d_in[16];
  const float* bfv = (const float*)d_in[17];
  const float* Ws1 = (const float*)d_in[18];
  const float* bs1 = (const float*)d_in[19];
  const float* Ws2 = (const float*)d_in[20];
  const float* bs2 = (const float*)d_in[21];

  char* ws = (char*)d_ws;
  int* offs    = (int*)(ws + OFF_OFFS);
  int* cntA    = (int*)(ws + OFF_CNTA);
  int* ofsA    = (int*)(ws + OFF_OFSA);
  int* bsum    = (int*)(ws + OFF_BSUM);
  int* starts  = (int*)(ws + OFF_STARTS);
  int* srcS    = (int*)(ws + OFF_SRCS);
  bf16* Wcat1  = (bf16*)(ws + OFF_WCAT1);
  bf16* Wcat2  = (bf16*)(ws + OFF_WCAT2);
  bf16* WihB   = (bf16*)(ws + OFF_WIHB);
  bf16* WhhB   = (bf16*)(ws + OFF_WHHB);
  float* bsumF = (float*)(ws + OFF_BSUMF);
  float* comb  = (float*)(ws + OFF_COMB);
  bf16* Acat1  = (bf16*)(ws + OFF_R1);
  bf16* meanB  = (bf16*)(ws + OFF_R1);          // alias: Acat1 dead after gemmf8
  unsigned* ebuf = (unsigned*)(ws + OFF_EBUF);
  bf16* h1B    = (bf16*)(ws + OFF_H1B);         // alias: ebuf dead after passB
  float* pre   = (float*)(ws + OFF_PRE);        // alias: h1B dead after gemm2sp
  unsigned* xb8  = (unsigned*)(ws + OFF_XB8);
  unsigned* h1f8 = (unsigned*)(ws + OFF_H1F8);  // alias: xb8 dead after agg1
  bf16* node_emb = (bf16*)(ws + OFF_NE);        // alias: h1f8 dead after agg2

  mega0_k<<<9156, 256, 0, stream>>>(x, xb8, Acat1, edge + N_EDGES, cntA,
                                    Wl1, Wr1, Wl2, Wr2, Wih, Whh, bih, bhh,
                                    Wcat1, Wcat2, WihB, WhhB, bsumF, batch, starts);
  scan1_k<<<NB, 256, 0, stream>>>(cntA, ofsA, bsum);
  passA2_k<<<GB, 256, 0, stream>>>(edge, edge + N_EDGES, ofsA, bsum, ebuf);
  passB_k<<<NB, 256, 0, stream>>>(ebuf, bsum, offs, srcS);
  agg1_k<<<N_NODES / 4, 256, 0, stream>>>(xb8, offs, srcS, Acat1);
  gemmf8_k<<<N_NODES / 64, 256, 0, stream>>>(Acat1, Wcat1, b1, h1B, h1f8);
  agg2_k<<<N_NODES / 4, 256, 0, stream>>>(offs, srcS, h1f8, meanB);
  gemm2sp_k<<<N_NODES / 64, 256, 0, stream>>>(meanB, h1B, Wcat2, b2, node_emb);
  tail0_k<<<832, 256, 0, stream>>>(node_emb, WihB, bsumF, pre, path_idx, starts, flow, Wf, bfv, comb);
  lstm_k<<<BATCHES / 16, 256, 0, stream>>>(WhhB, pre, path_len, comb);
  head_k<<<BATCHES, 128, 0, stream>>>(comb, Ws1, bs1, Ws2, bs2, (float*)d_out);
}

// Round 11
// 408.550 us; speedup vs baseline: 1.1342x; 1.0396x over previous
//
#include <hip/hip_runtime.h>
#include <hip/hip_bf16.h>

#define N_NODES 131072
#define N_EDGES 2097152
#define BATCHES 256
#define LPATH   32
// two-level counting sort params
#define NB   256          // coarse buckets (512 nodes each)
#define NPB  512          // nodes per bucket
#define GB   256          // cntA/passA2 blocks
#define EPB  8192         // edges per block

typedef __hip_bfloat16 bf16;
using short8  = __attribute__((ext_vector_type(8))) short;
using floatx4 = __attribute__((ext_vector_type(4))) float;
using floatx2 = __attribute__((ext_vector_type(2))) float;

__device__ __forceinline__ float bl(unsigned u){ union {unsigned x; float f;} c; c.x = u << 16; return c.f; }
__device__ __forceinline__ float bh(unsigned u){ union {unsigned x; float f;} c; c.x = u & 0xffff0000u; return c.f; }
__device__ __forceinline__ unsigned packbf(float lo, float hi){
  bf16 l = __float2bfloat16(lo), h = __float2bfloat16(hi);
  unsigned short lu, hu;
  __builtin_memcpy(&lu, &l, 2); __builtin_memcpy(&hu, &h, 2);
  return (unsigned)lu | ((unsigned)hu << 16);
}
__device__ __forceinline__ float frcp(float x){ return __builtin_amdgcn_rcpf(x); }
__device__ __forceinline__ float sigf(float x){ return frcp(1.f + __expf(-x)); }
__device__ __forceinline__ float tanh_fast(float x){ return fmaf(2.f, frcp(1.f + __expf(-2.f * x)), -1.f); }

// ---------------- mega0: xb8 [0,8192) | cntA [8192,8448) | prep [8448,9155) | bounds {9155} ----------------
__global__ void mega0_k(const float* __restrict__ x, unsigned* __restrict__ xb8, bf16* __restrict__ Acat1,
                        const int* __restrict__ dst, int* __restrict__ cntA,
                        const float* __restrict__ Wl1, const float* __restrict__ Wr1,
                        const float* __restrict__ Wl2, const float* __restrict__ Wr2,
                        const float* __restrict__ Wih, const float* __restrict__ Whh,
                        const float* __restrict__ bih, const float* __restrict__ bhh,
                        bf16* __restrict__ Wcat1, bf16* __restrict__ Wcat2,
                        bf16* __restrict__ WihB, bf16* __restrict__ WhhB, float* __restrict__ bsumF,
                        const int* __restrict__ batch, int* __restrict__ starts){
  __shared__ int h[NB];
  int bid = blockIdx.x, tid = threadIdx.x;
  if (bid < 8192){                     // x (f32) -> fp8 rows + bf16 self-half of Acat1
    int g = bid * 256 + tid;           // one thread per 4 features
    int n = g >> 4, p = g & 15;
    float4 v = *(const float4*)(x + (size_t)n * 64 + p * 4);
    uint2 wb; wb.x = packbf(v.x, v.y); wb.y = packbf(v.z, v.w);
    *(uint2*)(Acat1 + (size_t)n * 128 + 64 + p * 4) = wb;
    int w = 0;
    w = __builtin_amdgcn_cvt_pk_fp8_f32(v.x, v.y, w, false);
    w = __builtin_amdgcn_cvt_pk_fp8_f32(v.z, v.w, w, true);
    xb8[(size_t)n * 16 + p] = (unsigned)w;
  } else if (bid < 8448){              // cntA: coarse bucket histogram
    int cb = bid - 8192;
    h[tid] = 0;
    __syncthreads();
    int base = cb * EPB;
    #pragma unroll
    for (int i = 0; i < EPB / 256; ++i){
      int d = dst[base + i * 256 + tid];
      atomicAdd(&h[d >> 9], 1);
    }
    __syncthreads();
    cntA[tid * GB + cb] = h[tid];
  } else if (bid < 9155){              // prep: f32 weights -> bf16
    int g = (bid - 8448) * 256 + tid;
    if (g < 16384) {                   // Wcat1: 128 x 128 (Wl1 | Wr1)
      int hh = g >> 7, k = g & 127;
      float v = (k < 64) ? Wl1[hh * 64 + k] : Wr1[hh * 64 + (k - 64)];
      Wcat1[g] = __float2bfloat16(v);
    } else if (g < 49152) {            // Wcat2: 128 x 256 (Wl2 | Wr2)
      int q = g - 16384;
      int hh = q >> 8, k = q & 255;
      float v = (k < 128) ? Wl2[hh * 128 + k] : Wr2[hh * 128 + (k - 128)];
      Wcat2[q] = __float2bfloat16(v);
    } else if (g < 114688) {           // WihB: 512 x 128
      int q = g - 49152;
      WihB[q] = __float2bfloat16(Wih[q]);
    } else if (g < 180224) {           // WhhB: 512 x 128
      int q = g - 114688;
      WhhB[q] = __float2bfloat16(Whh[q]);
    } else if (g < 180736) {           // bsumF = bih + bhh (f32)
      int k = g - 180224;
      bsumF[k] = bih[k] + bhh[k];
    }
  } else {                             // bounds: segment starts (batch sorted)
    int b = tid;
    int lo = 0, hi = N_NODES;
    while (lo < hi){ int mid = (lo + hi) >> 1; if (batch[mid] < b) lo = mid + 1; else hi = mid; }
    starts[b] = lo;
    if (b == 0) starts[BATCHES] = N_NODES;
  }
}

// ---------------- per-bucket exclusive scan (one block per bucket) + bucket totals ----------------
__global__ void scan1_k(const int* __restrict__ cnt, int* __restrict__ ofsA, int* __restrict__ bsum){
  __shared__ int sh[256];
  int t = threadIdx.x, i = blockIdx.x * 256 + t;
  int v = cnt[i];
  sh[t] = v; __syncthreads();
  int inc = v;
  for (int d = 1; d < 256; d <<= 1){
    int add = (t >= d) ? sh[t - d] : 0;
    __syncthreads();
    inc += add; sh[t] = inc;
    __syncthreads();
  }
  ofsA[i] = inc - v;
  if (t == 255) bsum[blockIdx.x] = inc;
}

// ---------------- passA2: place packed (src | localNode<<17); bucket-total scan computed locally ----------------
__global__ void passA2_k(const int* __restrict__ src, const int* __restrict__ dst,
                         const int* __restrict__ ofsA, const int* __restrict__ bsum,
                         unsigned* __restrict__ ebuf){
  __shared__ int cur[NB];
  __shared__ int sc[NB];
  int tid = threadIdx.x;
  int v = bsum[tid];
  sc[tid] = v; __syncthreads();
  int inc = v;
  for (int d = 1; d < NB; d <<= 1){
    int add = (tid >= d) ? sc[tid - d] : 0;
    __syncthreads();
    inc += add; sc[tid] = inc;
    __syncthreads();
  }
  cur[tid] = ofsA[tid * GB + blockIdx.x] + (inc - v);
  __syncthreads();
  int base = blockIdx.x * EPB;
  #pragma unroll
  for (int i = 0; i < EPB / 256; ++i){
    int e = base + i * 256 + tid;
    int s = src[e], d = dst[e];
    int p = atomicAdd(&cur[d >> 9], 1);
    ebuf[p] = (unsigned)s | ((unsigned)(d & (NPB - 1)) << 17);
  }
}

// ---------------- passB: per-node CSR within bucket; bucket-total scan computed locally ----------------
__global__ void passB_k(const unsigned* __restrict__ ebuf, const int* __restrict__ bsum,
                        int* __restrict__ offs, int* __restrict__ srcS){
  __shared__ int ncnt[NPB];
  __shared__ int pairs[256];
  __shared__ int nofs[NPB];
  __shared__ int sc[NB];
  int k = blockIdx.x, tid = threadIdx.x;
  int v = bsum[tid];
  sc[tid] = v; __syncthreads();
  int inc0 = v;
  for (int d = 1; d < NB; d <<= 1){
    int add = (tid >= d) ? sc[tid - d] : 0;
    __syncthreads();
    inc0 += add; sc[tid] = inc0;
    __syncthreads();
  }
  sc[tid] = inc0 - v;                 // exclusive
  __syncthreads();
  int bs = sc[k];
  int be = (k < NB - 1) ? sc[k + 1] : N_EDGES;
  ncnt[tid] = 0; ncnt[tid + 256] = 0;
  __syncthreads();
  for (int i = bs + tid; i < be; i += 256)
    atomicAdd(&ncnt[ebuf[i] >> 17], 1);
  __syncthreads();
  int p = ncnt[2 * tid] + ncnt[2 * tid + 1];
  pairs[tid] = p;
  __syncthreads();
  int inc = p;
  for (int d = 1; d < 256; d <<= 1){
    int add = (tid >= d) ? pairs[tid - d] : 0;
    __syncthreads();
    inc += add; pairs[tid] = inc;
    __syncthreads();
  }
  int ex = inc - p;
  nofs[2 * tid]     = ex;
  nofs[2 * tid + 1] = ex + ncnt[2 * tid];
  __syncthreads();
  offs[k * NPB + tid]       = bs + nofs[tid];
  offs[k * NPB + tid + 256] = bs + nofs[tid + 256];
  if (k == NB - 1 && tid == 0) offs[N_NODES] = N_EDGES;
  ncnt[tid] = nofs[tid]; ncnt[tid + 256] = nofs[tid + 256];
  __syncthreads();
  for (int i = bs + tid; i < be; i += 256){
    unsigned w = ebuf[i];
    int loc = w >> 17, sv = w & 0x1FFFF;
    int pp = atomicAdd(&ncnt[loc], 1);
    srcS[bs + pp] = sv;
  }
}

// ---------------- SAGE layer-1 aggregation: 4 nodes/wave x 2 slots x 8 lanes x uint2 (fp8) ----------------
__global__ void agg1_k(const unsigned* __restrict__ xb8, const int* __restrict__ offs,
                       const int* __restrict__ srcS, bf16* __restrict__ Acat1){
  int wid = threadIdx.x >> 6, lane = threadIdx.x & 63;
  int q = lane >> 4;                            // node index within wave (0..3)
  int slot = (lane >> 3) & 1, fl = lane & 7;    // fl covers features fl*8 .. fl*8+7
  int n = blockIdx.x * 16 + wid * 4 + q;
  int s = offs[n], e = offs[n + 1];
  floatx2 a0={0,0}, a1={0,0}, a2={0,0}, a3={0,0};
  floatx2 c0={0,0}, c1={0,0}, c2={0,0}, c3={0,0};
  int i = s + slot;
  for (; i + 2 < e; i += 4){
    int sv0 = srcS[i], sv1 = srcS[i + 2];
    uint2 u = *(const uint2*)(xb8 + (size_t)sv0 * 16 + fl * 2);
    uint2 v = *(const uint2*)(xb8 + (size_t)sv1 * 16 + fl * 2);
    a0 += __builtin_amdgcn_cvt_pk_f32_fp8(u.x, false);
    a1 += __builtin_amdgcn_cvt_pk_f32_fp8(u.x, true);
    a2 += __builtin_amdgcn_cvt_pk_f32_fp8(u.y, false);
    a3 += __builtin_amdgcn_cvt_pk_f32_fp8(u.y, true);
    c0 += __builtin_amdgcn_cvt_pk_f32_fp8(v.x, false);
    c1 += __builtin_amdgcn_cvt_pk_f32_fp8(v.x, true);
    c2 += __builtin_amdgcn_cvt_pk_f32_fp8(v.y, false);
    c3 += __builtin_amdgcn_cvt_pk_f32_fp8(v.y, true);
  }
  if (i < e){
    int sv0 = srcS[i];
    uint2 u = *(const uint2*)(xb8 + (size_t)sv0 * 16 + fl * 2);
    a0 += __builtin_amdgcn_cvt_pk_f32_fp8(u.x, false);
    a1 += __builtin_amdgcn_cvt_pk_f32_fp8(u.x, true);
    a2 += __builtin_amdgcn_cvt_pk_f32_fp8(u.y, false);
    a3 += __builtin_amdgcn_cvt_pk_f32_fp8(u.y, true);
  }
  a0 += c0; a1 += c1; a2 += c2; a3 += c3;
  float f[8] = {a0.x, a0.y, a1.x, a1.y, a2.x, a2.y, a3.x, a3.y};
  #pragma unroll
  for (int j = 0; j < 8; ++j)
    f[j] += __shfl_xor(f[j], 8);               // combine the 2 slots of this node
  if (slot == 0){
    int d = e - s; if (d < 1) d = 1;
    float inv = 1.f / (float)d;
    uint4 w;
    w.x = packbf(f[0] * inv, f[1] * inv);
    w.y = packbf(f[2] * inv, f[3] * inv);
    w.z = packbf(f[4] * inv, f[5] * inv);
    w.w = packbf(f[6] * inv, f[7] * inv);
    *(uint4*)(Acat1 + (size_t)n * 128 + fl * 8) = w;
  }
}

// ---------------- gemm1 + fused fp8 conversion: h1B (bf16 N x 128) and h1f8 (fp8 N x 128B) ----------------
__global__ __launch_bounds__(256) void gemmf8_k(const bf16* __restrict__ A, const bf16* __restrict__ W,
                                                const float* __restrict__ bias,
                                                bf16* __restrict__ h1B, unsigned* __restrict__ h1f8){
  __shared__ bf16 Wl[128][136];
  __shared__ unsigned char f8t[64][144];   // +16 pad: spread banks, keep 16B alignment
  int tid = threadIdx.x;
  int wid = tid >> 6, lane = tid & 63;
  int l16 = lane & 15, quad = lane >> 4;
  int rowBase = blockIdx.x * 64 + wid * 16;
  floatx4 acc[8] = {};
  for (int c = tid; c < 2048; c += 256){
    int r = c >> 4, kc = (c & 15) << 3;
    *(uint4*)(&Wl[r][kc]) = *(const uint4*)(W + (size_t)r * 128 + kc);
  }
  __syncthreads();
  for (int kk = 0; kk < 4; ++kk){
    short8 af = *(const short8*)(A + (size_t)(rowBase + l16) * 128 + kk * 32 + quad * 8);
    #pragma unroll
    for (int c = 0; c < 8; ++c){
      short8 bq = *(const short8*)(&Wl[c * 16 + l16][kk * 32 + quad * 8]);
      acc[c] = __builtin_amdgcn_mfma_f32_16x16x32_bf16(af, bq, acc[c], 0, 0, 0);
    }
  }
  #pragma unroll
  for (int c = 0; c < 8; ++c){
    int col = c * 16 + l16;
    float bv = bias[col];
    #pragma unroll
    for (int r = 0; r < 4; ++r){
      int rl = wid * 16 + quad * 4 + r;
      float v = fmaxf(acc[c][r] + bv, 0.f);
      h1B[(size_t)(blockIdx.x * 64 + rl) * 128 + col] = __float2bfloat16(v);
      unsigned pk = (unsigned)__builtin_amdgcn_cvt_pk_fp8_f32(v, v, 0, false);
      f8t[rl][col] = (unsigned char)(pk & 0xFF);
    }
  }
  __syncthreads();
  for (int it = tid; it < 512; it += 256){
    int row = it >> 3, seg = it & 7;
    uint4 val = *(const uint4*)(&f8t[row][seg * 16]);
    *(uint4*)((char*)h1f8 + (size_t)(blockIdx.x * 64 + row) * 128 + seg * 16) = val;
  }
}

// ---------------- SAGE layer-2 aggregation: 2 nodes/wave x 2 slots x 16 lanes x uint2 (fp8) ----------------
__global__ void agg2_k(const int* __restrict__ offs, const int* __restrict__ srcS,
                       const unsigned* __restrict__ h1f8, bf16* __restrict__ meanB){
  int wid = threadIdx.x >> 6, lane = threadIdx.x & 63;
  int half = lane >> 5;                         // node index within wave (0..1)
  int slot = (lane >> 4) & 1, fl = lane & 15;   // fl covers features fl*8 .. fl*8+7
  int n = blockIdx.x * 8 + wid * 2 + half;
  int s = offs[n], e = offs[n + 1];
  floatx2 a0={0,0}, a1={0,0}, a2={0,0}, a3={0,0};
  floatx2 c0={0,0}, c1={0,0}, c2={0,0}, c3={0,0};
  int i = s + slot;
  for (; i + 2 < e; i += 4){
    int sv0 = srcS[i], sv1 = srcS[i + 2];
    uint2 u = *(const uint2*)(h1f8 + (size_t)sv0 * 32 + fl * 2);
    uint2 v = *(const uint2*)(h1f8 + (size_t)sv1 * 32 + fl * 2);
    a0 += __builtin_amdgcn_cvt_pk_f32_fp8(u.x, false);
    a1 += __builtin_amdgcn_cvt_pk_f32_fp8(u.x, true);
    a2 += __builtin_amdgcn_cvt_pk_f32_fp8(u.y, false);
    a3 += __builtin_amdgcn_cvt_pk_f32_fp8(u.y, true);
    c0 += __builtin_amdgcn_cvt_pk_f32_fp8(v.x, false);
    c1 += __builtin_amdgcn_cvt_pk_f32_fp8(v.x, true);
    c2 += __builtin_amdgcn_cvt_pk_f32_fp8(v.y, false);
    c3 += __builtin_amdgcn_cvt_pk_f32_fp8(v.y, true);
  }
  if (i < e){
    int sv0 = srcS[i];
    uint2 u = *(const uint2*)(h1f8 + (size_t)sv0 * 32 + fl * 2);
    a0 += __builtin_amdgcn_cvt_pk_f32_fp8(u.x, false);
    a1 += __builtin_amdgcn_cvt_pk_f32_fp8(u.x, true);
    a2 += __builtin_amdgcn_cvt_pk_f32_fp8(u.y, false);
    a3 += __builtin_amdgcn_cvt_pk_f32_fp8(u.y, true);
  }
  a0 += c0; a1 += c1; a2 += c2; a3 += c3;
  float f[8] = {a0.x, a0.y, a1.x, a1.y, a2.x, a2.y, a3.x, a3.y};
  #pragma unroll
  for (int j = 0; j < 8; ++j)
    f[j] += __shfl_xor(f[j], 16);              // combine the 2 slots of this node
  if (slot == 0){
    int d = e - s; if (d < 1) d = 1;
    float inv = 1.f / (float)d;
    uint4 w;
    w.x = packbf(f[0] * inv, f[1] * inv);
    w.y = packbf(f[2] * inv, f[3] * inv);
    w.z = packbf(f[4] * inv, f[5] * inv);
    w.w = packbf(f[6] * inv, f[7] * inv);
    *(uint4*)(meanB + (size_t)n * 128 + fl * 8) = w;
  }
}

// ---------------- gemm2 split-A: A cols 0:128 from meanB, 128:256 from h1B; out = node_emb ----------------
__global__ __launch_bounds__(256) void gemm2sp_k(const bf16* __restrict__ A0, const bf16* __restrict__ A1,
                                                 const bf16* __restrict__ W, const float* __restrict__ bias,
                                                 bf16* __restrict__ out){
  __shared__ bf16 Wl[128][136];
  int tid = threadIdx.x;
  int wid = tid >> 6, lane = tid & 63;
  int l16 = lane & 15, quad = lane >> 4;
  int rowBase = blockIdx.x * 64 + wid * 16;
  floatx4 acc[8] = {};
  #pragma unroll
  for (int ks = 0; ks < 2; ++ks){
    __syncthreads();
    for (int c = tid; c < 2048; c += 256){
      int r = c >> 4, kc = (c & 15) << 3;
      *(uint4*)(&Wl[r][kc]) = *(const uint4*)(W + (size_t)r * 256 + ks * 128 + kc);
    }
    __syncthreads();
    const bf16* Ab = ks ? A1 : A0;
    for (int kk = 0; kk < 4; ++kk){
      short8 af = *(const short8*)(Ab + (size_t)(rowBase + l16) * 128 + kk * 32 + quad * 8);
      #pragma unroll
      for (int c = 0; c < 8; ++c){
        short8 bq = *(const short8*)(&Wl[c * 16 + l16][kk * 32 + quad * 8]);
        acc[c] = __builtin_amdgcn_mfma_f32_16x16x32_bf16(af, bq, acc[c], 0, 0, 0);
      }
    }
  }
  #pragma unroll
  for (int c = 0; c < 8; ++c){
    int col = c * 16 + l16;
    float bv = bias[col];
    #pragma unroll
    for (int r = 0; r < 4; ++r){
      int row = rowBase + quad * 4 + r;
      out[(size_t)row * 128 + col] = __float2bfloat16(fmaxf(acc[c][r] + bv, 0.f));
    }
  }
}

// ---------------- tail0: blocks [0,512) path pre-GEMM | [512,768) pool | [768,832) flow ----------------
__global__ __launch_bounds__(256) void tail0_k(const bf16* __restrict__ ne, const bf16* __restrict__ W,
                                               const float* __restrict__ bias, float* __restrict__ pre,
                                               const int* __restrict__ ridx,
                                               const int* __restrict__ starts,
                                               const float* __restrict__ flow, const float* __restrict__ Wf,
                                               const float* __restrict__ bfv, float* __restrict__ comb){
  __shared__ bf16 Wl[128][136];
  __shared__ float sh[4][128];
  int bid = blockIdx.x, tid = threadIdx.x;
  if (bid < 512){                       // pre = act-free GEMM: pre[r][c] = ne[ridx[r]] . W[c] + bias[c]
    int bx = bid >> 2, by = bid & 3;
    int wid = tid >> 6, lane = tid & 63;
    int l16 = lane & 15, quad = lane >> 4;
    int rowBase = bx * 64 + wid * 16;
    int colGroup = by * 128;
    int arow = ridx[rowBase + l16];
    floatx4 acc[8] = {};
    for (int c = tid; c < 2048; c += 256){
      int r = c >> 4, kc = (c & 15) << 3;
      *(uint4*)(&Wl[r][kc]) = *(const uint4*)(W + (size_t)(colGroup + r) * 128 + kc);
    }
    __syncthreads();
    for (int kk = 0; kk < 4; ++kk){
      short8 af = *(const short8*)(ne + (size_t)arow * 128 + kk * 32 + quad * 8);
      #pragma unroll
      for (int c = 0; c < 8; ++c){
        short8 bq = *(const short8*)(&Wl[c * 16 + l16][kk * 32 + quad * 8]);
        acc[c] = __builtin_amdgcn_mfma_f32_16x16x32_bf16(af, bq, acc[c], 0, 0, 0);
      }
    }
    #pragma unroll
    for (int c = 0; c < 8; ++c){
      int col = colGroup + c * 16 + l16;
      float bv = bias[col];
      #pragma unroll
      for (int r = 0; r < 4; ++r){
        int row = rowBase + quad * 4 + r;
        pre[(size_t)row * 512 + col] = acc[c][r] + bv;
      }
    }
  } else if (bid < 768){                // graph mean pooling (4 row-slots x 64 lanes)
    int b = bid - 512;
    int q = tid >> 6, lane = tid & 63;
    int s = starts[b], e = starts[b + 1];
    float a0 = 0.f, a1 = 0.f;
    for (int i = s + q; i < e; i += 4){
      unsigned u = *(const unsigned*)(ne + (size_t)i * 128 + lane * 2);
      a0 += bl(u); a1 += bh(u);
    }
    sh[q][lane * 2] = a0; sh[q][lane * 2 + 1] = a1;
    __syncthreads();
    if (tid < 128){
      int f = tid;
      float tot = sh[0][f] + sh[1][f] + sh[2][f] + sh[3][f];
      int d = e - s; if (d < 1) d = 1;
      comb[b * 320 + f] = tot / (float)d;
    }
  } else {                              // flow MLP
    int g = (bid - 768) * 256 + tid;    // 16384 = 256 batches x 64 outputs
    int b = g >> 6, j = g & 63;
    float acc = bfv[j];
    for (int k = 0; k < 16; ++k)
      acc += flow[b * 16 + k] * Wf[j * 16 + k];
    comb[b * 320 + 256 + j] = fmaxf(acc, 0.f);
  }
}

// ---------------- LSTM recurrence via MFMA: 16 batches/block, 16 blocks ----------------
__global__ __launch_bounds__(256, 1) void lstm_k(const bf16* __restrict__ Whh, const float* __restrict__ pre,
                                                 const int* __restrict__ path_len, float* __restrict__ comb){
  __shared__ bf16 hbuf[2][16][136];   // [buf][batch][dim], +8 pad
  int tid = threadIdx.x;
  int w = tid >> 6, lane = tid & 63;
  int l16 = lane & 15, quad = lane >> 4;
  int b0 = blockIdx.x * 16;

  short8 wb[4][2][4];
  #pragma unroll
  for (int q = 0; q < 4; ++q)
    #pragma unroll
    for (int hf = 0; hf < 2; ++hf){
      const bf16* rp = Whh + (size_t)(q * 128 + w * 32 + hf * 16 + l16) * 128 + quad * 8;
      #pragma unroll
      for (int ks = 0; ks < 4; ++ks) wb[q][hf][ks] = *(const short8*)(rp + ks * 32);
    }

  int lenr[4];
  #pragma unroll
  for (int r = 0; r < 4; ++r){
    int L = path_len[b0 + quad * 4 + r];
    if (L < 1) L = 1; if (L > LPATH) L = LPATH;
    lenr[r] = L;
  }
  int maxlen = 1;
  for (int i = 0; i < 16; ++i){
    int L = path_len[b0 + i];
    if (L > LPATH) L = LPATH;
    if (L > maxlen) maxlen = L;
  }

  for (int i = tid; i < 1088; i += 256) ((unsigned*)&hbuf[0][0][0])[i] = 0;

  const float* pb[4];
  #pragma unroll
  for (int r = 0; r < 4; ++r)
    pb[r] = pre + (size_t)(b0 + quad * 4 + r) * LPATH * 512 + w * 32 + l16;

  float pv[4][2][4];
  #pragma unroll
  for (int q = 0; q < 4; ++q)
    #pragma unroll
    for (int hf = 0; hf < 2; ++hf)
      #pragma unroll
      for (int r = 0; r < 4; ++r)
        pv[q][hf][r] = pb[r][q * 128 + hf * 16];

  float cst[2][4] = {}, hst[2][4] = {};

  for (int t = 0; t < maxlen; ++t){
    int cur = t & 1, nxt = cur ^ 1;
    __syncthreads();
    short8 af[4];
    #pragma unroll
    for (int ks = 0; ks < 4; ++ks)
      af[ks] = *(const short8*)(&hbuf[cur][l16][ks * 32 + quad * 8]);
    int tn = (t + 1 < maxlen) ? t + 1 : t;
    float pnext[4][2][4];
    #pragma unroll
    for (int q = 0; q < 4; ++q)
      #pragma unroll
      for (int hf = 0; hf < 2; ++hf)
        #pragma unroll
        for (int r = 0; r < 4; ++r)
          pnext[q][hf][r] = pb[r][tn * 512 + q * 128 + hf * 16];
    floatx4 acc[4][2];
    #pragma unroll
    for (int q = 0; q < 4; ++q)
      #pragma unroll
      for (int hf = 0; hf < 2; ++hf){
        acc[q][hf][0] = pv[q][hf][0]; acc[q][hf][1] = pv[q][hf][1];
        acc[q][hf][2] = pv[q][hf][2]; acc[q][hf][3] = pv[q][hf][3];
      }
    #pragma unroll
    for (int ks = 0; ks < 4; ++ks)
      #pragma unroll
      for (int q = 0; q < 4; ++q)
        #pragma unroll
        for (int hf = 0; hf < 2; ++hf)
          acc[q][hf] = __builtin_amdgcn_mfma_f32_16x16x32_bf16(af[ks], wb[q][hf][ks], acc[q][hf], 0, 0, 0);
    #pragma unroll
    for (int hf = 0; hf < 2; ++hf)
      #pragma unroll
      for (int r = 0; r < 4; ++r){
        float ig = sigf(acc[0][hf][r]);
        float fg = sigf(acc[1][hf][r]);
        float gg = tanh_fast(acc[2][hf][r]);
        float og = sigf(acc[3][hf][r]);
        float cn = fmaf(fg, cst[hf][r], ig * gg);
        float hn = og * tanh_fast(cn);
        bool vld = t < lenr[r];
        cst[hf][r] = vld ? cn : cst[hf][r];
        hst[hf][r] = vld ? hn : hst[hf][r];
        hbuf[nxt][quad * 4 + r][w * 32 + hf * 16 + l16] = __float2bfloat16(hst[hf][r]);
      }
    #pragma unroll
    for (int q = 0; q < 4; ++q)
      #pragma unroll
      for (int hf = 0; hf < 2; ++hf)
        #pragma unroll
        for (int r = 0; r < 4; ++r)
          pv[q][hf][r] = pnext[q][hf][r];
  }

  #pragma unroll
  for (int hf = 0; hf < 2; ++hf)
    #pragma unroll
    for (int r = 0; r < 4; ++r)
      comb[(b0 + quad * 4 + r) * 320 + 128 + w * 32 + hf * 16 + l16] = hst[hf][r];
}

// ---------------- scoring head (f32 weights) ----------------
__global__ void head_k(const float* __restrict__ comb, const float* __restrict__ Ws1, const float* __restrict__ bs1,
                       const float* __restrict__ Ws2, const float* __restrict__ bs2, float* __restrict__ out){
  __shared__ float cl[320];
  __shared__ float red[128];
  int b = blockIdx.x, j = threadIdx.x;   // 128 threads
  for (int k = j; k < 320; k += 128) cl[k] = comb[b * 320 + k];
  __syncthreads();
  float acc = bs1[j];
  const float4* wr = (const float4*)(Ws1 + (size_t)j * 320);
  #pragma unroll 4
  for (int kc = 0; kc < 80; ++kc){
    float4 u = wr[kc];
    int k = kc * 4;
    acc += u.x * cl[k] + u.y * cl[k + 1] + u.z * cl[k + 2] + u.w * cl[k + 3];
  }
  float hv = fmaxf(acc, 0.f);
  red[j] = hv * Ws2[j];
  __syncthreads();
  for (int s = 64; s > 0; s >>= 1){ if (j < s) red[j] += red[j + s]; __syncthreads(); }
  if (j == 0) out[b] = red[0] + bs2[0];
}

// ---------------- workspace layout (16B-aligned) ----------------
constexpr size_t OFF_OFFS   = 0;                       // (N+1) ints
constexpr size_t OFF_CNTA   = 524544;                  // NB*GB ints = 256 KB
constexpr size_t OFF_OFSA   = OFF_CNTA   + 262144;     // NB*GB ints
constexpr size_t OFF_BSUM   = OFF_OFSA   + 262144;     // NB ints
constexpr size_t OFF_STARTS = OFF_BSUM   + 1024;       // 257 ints
constexpr size_t OFF_SRCS   = OFF_STARTS + 2048;       // E ints = 8.4 MB
constexpr size_t OFF_WCAT1  = OFF_SRCS   + 8388608;
constexpr size_t OFF_WCAT2  = OFF_WCAT1  + 32768;
constexpr size_t OFF_WIHB   = OFF_WCAT2  + 65536;
constexpr size_t OFF_WHHB   = OFF_WIHB   + 131072;
constexpr size_t OFF_BSUMF  = OFF_WHHB   + 131072;
constexpr size_t OFF_COMB   = OFF_BSUMF  + 2048;
// Region R1 (33.5 MB): Acat1 [mega0/agg1 -> gemmf8 reads] then meanB [agg2 writes -> gemm2sp reads]
constexpr size_t OFF_R1     = OFF_COMB   + 327680;
// Region R2 (64 MiB), aliased sub-lifetimes:
constexpr size_t OFF_R2     = OFF_R1     + 33554432;
constexpr size_t OFF_EBUF   = OFF_R2;                  // E uint (8.4 MB): sort only
constexpr size_t OFF_H1B    = OFF_R2;                  // N x 128 bf16 (33.5 MB): gemmf8 -> gemm2sp
constexpr size_t OFF_PRE    = OFF_R2;                  // 8192 x 512 f32 (16.8 MB): tail0 -> lstm (h1B dead)
constexpr size_t OFF_XB8    = OFF_R2 + 33554432;       // N x 64 B fp8 (8.4 MB): mega0 -> agg1
constexpr size_t OFF_H1F8   = OFF_R2 + 33554432;       // N x 128 B fp8 (16.8 MB): gemmf8 -> agg2 (xb8 dead)
constexpr size_t OFF_NE     = OFF_R2 + 33554432;       // N x 128 bf16 (33.5 MB): gemm2sp -> tail0 (h1f8 dead)

extern "C" void kernel_launch(void* const* d_in, const int* in_sizes, int n_in,
                              void* d_out, int out_size, void* d_ws, size_t ws_size,
                              hipStream_t stream){
  const float* x      = (const float*)d_in[0];
  const int* edge     = (const int*)d_in[1];
  const int* batch    = (const int*)d_in[2];
  const int* path_idx = (const int*)d_in[3];
  const int* path_len = (const int*)d_in[4];
  const float* flow   = (const float*)d_in[5];
  const float* Wl1 = (const float*)d_in[6];
  const float* Wr1 = (const float*)d_in[7];
  const float* b1  = (const float*)d_in[8];
  const float* Wl2 = (const float*)d_in[9];
  const float* Wr2 = (const float*)d_in[10];
  const float* b2  = (const float*)d_in[11];
  const float* Wih = (const float*)d_in[12];
  const float* Whh = (const float*)d_in[13];
  const float* bih = (const float*)d_in[14];
  const float* bhh = (const float*)d_in[15];
  const float* Wf  = (const float*)d_in[16];
  const float* bfv = (const float*)d_in[17];
  const float* Ws1 = (const float*)d_in[18];
  const float* bs1 = (const float*)d_in[19];
  const float* Ws2 = (const float*)d_in[20];
  const float* bs2 = (const float*)d_in[21];

  char* ws = (char*)d_ws;
  int* offs    = (int*)(ws + OFF_OFFS);
  int* cntA    = (int*)(ws + OFF_CNTA);
  int* ofsA    = (int*)(ws + OFF_OFSA);
  int* bsum    = (int*)(ws + OFF_BSUM);
  int* starts  = (int*)(ws + OFF_STARTS);
  int* srcS    = (int*)(ws + OFF_SRCS);
  bf16* Wcat1  = (bf16*)(ws + OFF_WCAT1);
  bf16* Wcat2  = (bf16*)(ws + OFF_WCAT2);
  bf16* WihB   = (bf16*)(ws + OFF_WIHB);
  bf16* WhhB   = (bf16*)(ws + OFF_WHHB);
  float* bsumF = (float*)(ws + OFF_BSUMF);
  float* comb  = (float*)(ws + OFF_COMB);
  bf16* Acat1  = (bf16*)(ws + OFF_R1);
  bf16* meanB  = (bf16*)(ws + OFF_R1);          // alias: Acat1 dead after gemmf8
  unsigned* ebuf = (unsigned*)(ws + OFF_EBUF);
  bf16* h1B    = (bf16*)(ws + OFF_H1B);         // alias: ebuf dead after passB
  float* pre   = (float*)(ws + OFF_PRE);        // alias: h1B dead after gemm2sp
  unsigned* xb8  = (unsigned*)(ws + OFF_XB8);
  unsigned* h1f8 = (unsigned*)(ws + OFF_H1F8);  // alias: xb8 dead after agg1
  bf16* node_emb = (bf16*)(ws + OFF_NE);        // alias: h1f8 dead after agg2

  mega0_k<<<9156, 256, 0, stream>>>(x, xb8, Acat1, edge + N_EDGES, cntA,
                                    Wl1, Wr1, Wl2, Wr2, Wih, Whh, bih, bhh,
                                    Wcat1, Wcat2, WihB, WhhB, bsumF, batch, starts);
  scan1_k<<<NB, 256, 0, stream>>>(cntA, ofsA, bsum);
  passA2_k<<<GB, 256, 0, stream>>>(edge, edge + N_EDGES, ofsA, bsum, ebuf);
  passB_k<<<NB, 256, 0, stream>>>(ebuf, bsum, offs, srcS);
  agg1_k<<<N_NODES / 16, 256, 0, stream>>>(xb8, offs, srcS, Acat1);
  gemmf8_k<<<N_NODES / 64, 256, 0, stream>>>(Acat1, Wcat1, b1, h1B, h1f8);
  agg2_k<<<N_NODES / 8, 256, 0, stream>>>(offs, srcS, h1f8, meanB);
  gemm2sp_k<<<N_NODES / 64, 256, 0, stream>>>(meanB, h1B, Wcat2, b2, node_emb);
  tail0_k<<<832, 256, 0, stream>>>(node_emb, WihB, bsumF, pre, path_idx, starts, flow, Wf, bfv, comb);
  lstm_k<<<BATCHES / 16, 256, 0, stream>>>(WhhB, pre, path_len, comb);
  head_k<<<BATCHES, 128, 0, stream>>>(comb, Ws1, bs1, Ws2, bs2, (float*)d_out);
}

// Round 12
// 389.115 us; speedup vs baseline: 1.1908x; 1.0499x over previous
//
#include <hip/hip_runtime.h>
#include <hip/hip_bf16.h>

#define N_NODES 131072
#define N_EDGES 2097152
#define BATCHES 256
#define LPATH   32
// two-level counting sort params
#define NB   256          // coarse buckets (512 nodes each)
#define NPB  512          // nodes per bucket
#define GB   256          // cntA/passA2 blocks
#define EPB  8192         // edges per block
#define EBL_CAP 9216      // passB LDS stage capacity (mean 8192, +11 sigma)

typedef __hip_bfloat16 bf16;
using short8  = __attribute__((ext_vector_type(8))) short;
using floatx4 = __attribute__((ext_vector_type(4))) float;
using floatx2 = __attribute__((ext_vector_type(2))) float;

__device__ __forceinline__ float bl(unsigned u){ union {unsigned x; float f;} c; c.x = u << 16; return c.f; }
__device__ __forceinline__ float bh(unsigned u){ union {unsigned x; float f;} c; c.x = u & 0xffff0000u; return c.f; }
__device__ __forceinline__ unsigned packbf(float lo, float hi){
  bf16 l = __float2bfloat16(lo), h = __float2bfloat16(hi);
  unsigned short lu, hu;
  __builtin_memcpy(&lu, &l, 2); __builtin_memcpy(&hu, &h, 2);
  return (unsigned)lu | ((unsigned)hu << 16);
}
__device__ __forceinline__ float frcp(float x){ return __builtin_amdgcn_rcpf(x); }
__device__ __forceinline__ float sigf(float x){ return frcp(1.f + __expf(-x)); }
__device__ __forceinline__ float tanh_fast(float x){ return fmaf(2.f, frcp(1.f + __expf(-2.f * x)), -1.f); }

// ---------------- mega0: xb8 [0,8192) | cntA [8192,8448) | prep [8448,9155) | bounds {9155} ----------------
__global__ void mega0_k(const float* __restrict__ x, unsigned* __restrict__ xb8, bf16* __restrict__ Acat1,
                        const int* __restrict__ dst, int* __restrict__ cntA,
                        const float* __restrict__ Wl1, const float* __restrict__ Wr1,
                        const float* __restrict__ Wl2, const float* __restrict__ Wr2,
                        const float* __restrict__ Wih, const float* __restrict__ Whh,
                        const float* __restrict__ bih, const float* __restrict__ bhh,
                        bf16* __restrict__ Wcat1, bf16* __restrict__ Wcat2,
                        bf16* __restrict__ WihB, bf16* __restrict__ WhhB, float* __restrict__ bsumF,
                        const int* __restrict__ batch, int* __restrict__ starts){
  __shared__ int h[NB];
  int bid = blockIdx.x, tid = threadIdx.x;
  if (bid < 8192){                     // x (f32) -> fp8 rows + bf16 self-half of Acat1
    int g = bid * 256 + tid;           // one thread per 4 features
    int n = g >> 4, p = g & 15;
    float4 v = *(const float4*)(x + (size_t)n * 64 + p * 4);
    uint2 wb; wb.x = packbf(v.x, v.y); wb.y = packbf(v.z, v.w);
    *(uint2*)(Acat1 + (size_t)n * 128 + 64 + p * 4) = wb;
    int w = 0;
    w = __builtin_amdgcn_cvt_pk_fp8_f32(v.x, v.y, w, false);
    w = __builtin_amdgcn_cvt_pk_fp8_f32(v.z, v.w, w, true);
    xb8[(size_t)n * 16 + p] = (unsigned)w;
  } else if (bid < 8448){              // cntA: coarse bucket histogram
    int cb = bid - 8192;
    h[tid] = 0;
    __syncthreads();
    int base = cb * EPB;
    #pragma unroll
    for (int i = 0; i < EPB / 256; ++i){
      int d = dst[base + i * 256 + tid];
      atomicAdd(&h[d >> 9], 1);
    }
    __syncthreads();
    cntA[tid * GB + cb] = h[tid];
  } else if (bid < 9155){              // prep: f32 weights -> bf16
    int g = (bid - 8448) * 256 + tid;
    if (g < 16384) {                   // Wcat1: 128 x 128 (Wl1 | Wr1)
      int hh = g >> 7, k = g & 127;
      float v = (k < 64) ? Wl1[hh * 64 + k] : Wr1[hh * 64 + (k - 64)];
      Wcat1[g] = __float2bfloat16(v);
    } else if (g < 49152) {            // Wcat2: 128 x 256 (Wl2 | Wr2)
      int q = g - 16384;
      int hh = q >> 8, k = q & 255;
      float v = (k < 128) ? Wl2[hh * 128 + k] : Wr2[hh * 128 + (k - 128)];
      Wcat2[q] = __float2bfloat16(v);
    } else if (g < 114688) {           // WihB: 512 x 128
      int q = g - 49152;
      WihB[q] = __float2bfloat16(Wih[q]);
    } else if (g < 180224) {           // WhhB: 512 x 128
      int q = g - 114688;
      WhhB[q] = __float2bfloat16(Whh[q]);
    } else if (g < 180736) {           // bsumF = bih + bhh (f32)
      int k = g - 180224;
      bsumF[k] = bih[k] + bhh[k];
    }
  } else {                             // bounds: segment starts (batch sorted)
    int b = tid;
    int lo = 0, hi = N_NODES;
    while (lo < hi){ int mid = (lo + hi) >> 1; if (batch[mid] < b) lo = mid + 1; else hi = mid; }
    starts[b] = lo;
    if (b == 0) starts[BATCHES] = N_NODES;
  }
}

// ---------------- per-bucket exclusive scan (one block per bucket) + bucket totals ----------------
__global__ void scan1_k(const int* __restrict__ cnt, int* __restrict__ ofsA, int* __restrict__ bsum){
  __shared__ int sh[256];
  int t = threadIdx.x, i = blockIdx.x * 256 + t;
  int v = cnt[i];
  sh[t] = v; __syncthreads();
  int inc = v;
  for (int d = 1; d < 256; d <<= 1){
    int add = (t >= d) ? sh[t - d] : 0;
    __syncthreads();
    inc += add; sh[t] = inc;
    __syncthreads();
  }
  ofsA[i] = inc - v;
  if (t == 255) bsum[blockIdx.x] = inc;
}

// ---------------- passA2: place packed (src | localNode<<17); bucket-total scan computed locally ----------------
__global__ void passA2_k(const int* __restrict__ src, const int* __restrict__ dst,
                         const int* __restrict__ ofsA, const int* __restrict__ bsum,
                         unsigned* __restrict__ ebuf){
  __shared__ int cur[NB];
  __shared__ int sc[NB];
  int tid = threadIdx.x;
  int v = bsum[tid];
  sc[tid] = v; __syncthreads();
  int inc = v;
  for (int d = 1; d < NB; d <<= 1){
    int add = (tid >= d) ? sc[tid - d] : 0;
    __syncthreads();
    inc += add; sc[tid] = inc;
    __syncthreads();
  }
  cur[tid] = ofsA[tid * GB + blockIdx.x] + (inc - v);
  __syncthreads();
  int base = blockIdx.x * EPB;
  #pragma unroll
  for (int i = 0; i < EPB / 256; ++i){
    int e = base + i * 256 + tid;
    int s = src[e], d = dst[e];
    int p = atomicAdd(&cur[d >> 9], 1);
    ebuf[p] = (unsigned)s | ((unsigned)(d & (NPB - 1)) << 17);
  }
}

// ---------------- passB: per-node CSR within bucket; bucket ebuf slice staged in LDS ----------------
__global__ void passB_k(const unsigned* __restrict__ ebuf, const int* __restrict__ bsum,
                        int* __restrict__ offs, int* __restrict__ srcS){
  __shared__ unsigned ebl[EBL_CAP];
  __shared__ int ncnt[NPB];
  __shared__ int pairs[256];
  __shared__ int nofs[NPB];
  __shared__ int sc[NB];
  int k = blockIdx.x, tid = threadIdx.x;
  int v = bsum[tid];
  sc[tid] = v; __syncthreads();
  int inc0 = v;
  for (int d = 1; d < NB; d <<= 1){
    int add = (tid >= d) ? sc[tid - d] : 0;
    __syncthreads();
    inc0 += add; sc[tid] = inc0;
    __syncthreads();
  }
  sc[tid] = inc0 - v;                 // exclusive
  __syncthreads();
  int bs = sc[k];
  int be = (k < NB - 1) ? sc[k + 1] : N_EDGES;
  int cnt = be - bs;
  int stg = cnt < EBL_CAP ? cnt : EBL_CAP;
  for (int i = tid; i < stg; i += 256) ebl[i] = ebuf[bs + i];
  ncnt[tid] = 0; ncnt[tid + 256] = 0;
  __syncthreads();
  for (int i = tid; i < cnt; i += 256){
    unsigned w = (i < stg) ? ebl[i] : ebuf[bs + i];
    atomicAdd(&ncnt[w >> 17], 1);
  }
  __syncthreads();
  int p = ncnt[2 * tid] + ncnt[2 * tid + 1];
  pairs[tid] = p;
  __syncthreads();
  int inc = p;
  for (int d = 1; d < 256; d <<= 1){
    int add = (tid >= d) ? pairs[tid - d] : 0;
    __syncthreads();
    inc += add; pairs[tid] = inc;
    __syncthreads();
  }
  int ex = inc - p;
  nofs[2 * tid]     = ex;
  nofs[2 * tid + 1] = ex + ncnt[2 * tid];
  __syncthreads();
  offs[k * NPB + tid]       = bs + nofs[tid];
  offs[k * NPB + tid + 256] = bs + nofs[tid + 256];
  if (k == NB - 1 && tid == 0) offs[N_NODES] = N_EDGES;
  ncnt[tid] = nofs[tid]; ncnt[tid + 256] = nofs[tid + 256];
  __syncthreads();
  for (int i = tid; i < cnt; i += 256){
    unsigned w = (i < stg) ? ebl[i] : ebuf[bs + i];
    int loc = w >> 17, sv = w & 0x1FFFF;
    int pp = atomicAdd(&ncnt[loc], 1);
    srcS[bs + pp] = sv;
  }
}

// ---------------- SAGE layer-1 aggregation: 4 nodes/wave x 2 slots x 8 lanes, unroll 4 (fp8) ----------------
__global__ void agg1_k(const unsigned* __restrict__ xb8, const int* __restrict__ offs,
                       const int* __restrict__ srcS, bf16* __restrict__ Acat1){
  int wid = threadIdx.x >> 6, lane = threadIdx.x & 63;
  int q = lane >> 4;                            // node index within wave (0..3)
  int slot = (lane >> 3) & 1, fl = lane & 7;    // fl covers features fl*8 .. fl*8+7
  int n = blockIdx.x * 16 + wid * 4 + q;
  int s = offs[n], e = offs[n + 1];
  floatx2 a0={0,0}, a1={0,0}, a2={0,0}, a3={0,0};
  floatx2 c0={0,0}, c1={0,0}, c2={0,0}, c3={0,0};
  int i = s + slot;
  for (; i + 6 < e; i += 8){
    int sv0 = srcS[i], sv1 = srcS[i + 2], sv2 = srcS[i + 4], sv3 = srcS[i + 6];
    uint2 u = *(const uint2*)(xb8 + (size_t)sv0 * 16 + fl * 2);
    uint2 v = *(const uint2*)(xb8 + (size_t)sv1 * 16 + fl * 2);
    uint2 w = *(const uint2*)(xb8 + (size_t)sv2 * 16 + fl * 2);
    uint2 z = *(const uint2*)(xb8 + (size_t)sv3 * 16 + fl * 2);
    a0 += __builtin_amdgcn_cvt_pk_f32_fp8(u.x, false);
    a1 += __builtin_amdgcn_cvt_pk_f32_fp8(u.x, true);
    a2 += __builtin_amdgcn_cvt_pk_f32_fp8(u.y, false);
    a3 += __builtin_amdgcn_cvt_pk_f32_fp8(u.y, true);
    c0 += __builtin_amdgcn_cvt_pk_f32_fp8(v.x, false);
    c1 += __builtin_amdgcn_cvt_pk_f32_fp8(v.x, true);
    c2 += __builtin_amdgcn_cvt_pk_f32_fp8(v.y, false);
    c3 += __builtin_amdgcn_cvt_pk_f32_fp8(v.y, true);
    a0 += __builtin_amdgcn_cvt_pk_f32_fp8(w.x, false);
    a1 += __builtin_amdgcn_cvt_pk_f32_fp8(w.x, true);
    a2 += __builtin_amdgcn_cvt_pk_f32_fp8(w.y, false);
    a3 += __builtin_amdgcn_cvt_pk_f32_fp8(w.y, true);
    c0 += __builtin_amdgcn_cvt_pk_f32_fp8(z.x, false);
    c1 += __builtin_amdgcn_cvt_pk_f32_fp8(z.x, true);
    c2 += __builtin_amdgcn_cvt_pk_f32_fp8(z.y, false);
    c3 += __builtin_amdgcn_cvt_pk_f32_fp8(z.y, true);
  }
  for (; i < e; i += 2){
    int sv0 = srcS[i];
    uint2 u = *(const uint2*)(xb8 + (size_t)sv0 * 16 + fl * 2);
    a0 += __builtin_amdgcn_cvt_pk_f32_fp8(u.x, false);
    a1 += __builtin_amdgcn_cvt_pk_f32_fp8(u.x, true);
    a2 += __builtin_amdgcn_cvt_pk_f32_fp8(u.y, false);
    a3 += __builtin_amdgcn_cvt_pk_f32_fp8(u.y, true);
  }
  a0 += c0; a1 += c1; a2 += c2; a3 += c3;
  float f[8] = {a0.x, a0.y, a1.x, a1.y, a2.x, a2.y, a3.x, a3.y};
  #pragma unroll
  for (int j = 0; j < 8; ++j)
    f[j] += __shfl_xor(f[j], 8);               // combine the 2 slots of this node
  if (slot == 0){
    int d = e - s; if (d < 1) d = 1;
    float inv = 1.f / (float)d;
    uint4 w;
    w.x = packbf(f[0] * inv, f[1] * inv);
    w.y = packbf(f[2] * inv, f[3] * inv);
    w.z = packbf(f[4] * inv, f[5] * inv);
    w.w = packbf(f[6] * inv, f[7] * inv);
    *(uint4*)(Acat1 + (size_t)n * 128 + fl * 8) = w;
  }
}

// ---------------- gemm1 + fused fp8 conversion: h1B (bf16 N x 128) and h1f8 (fp8 N x 128B) ----------------
__global__ __launch_bounds__(256) void gemmf8_k(const bf16* __restrict__ A, const bf16* __restrict__ W,
                                                const float* __restrict__ bias,
                                                bf16* __restrict__ h1B, unsigned* __restrict__ h1f8){
  __shared__ bf16 Wl[128][136];
  __shared__ unsigned char f8t[64][144];   // +16 pad: spread banks, keep 16B alignment
  int tid = threadIdx.x;
  int wid = tid >> 6, lane = tid & 63;
  int l16 = lane & 15, quad = lane >> 4;
  int rowBase = blockIdx.x * 64 + wid * 16;
  floatx4 acc[8] = {};
  for (int c = tid; c < 2048; c += 256){
    int r = c >> 4, kc = (c & 15) << 3;
    *(uint4*)(&Wl[r][kc]) = *(const uint4*)(W + (size_t)r * 128 + kc);
  }
  __syncthreads();
  for (int kk = 0; kk < 4; ++kk){
    short8 af = *(const short8*)(A + (size_t)(rowBase + l16) * 128 + kk * 32 + quad * 8);
    #pragma unroll
    for (int c = 0; c < 8; ++c){
      short8 bq = *(const short8*)(&Wl[c * 16 + l16][kk * 32 + quad * 8]);
      acc[c] = __builtin_amdgcn_mfma_f32_16x16x32_bf16(af, bq, acc[c], 0, 0, 0);
    }
  }
  #pragma unroll
  for (int c = 0; c < 8; ++c){
    int col = c * 16 + l16;
    float bv = bias[col];
    #pragma unroll
    for (int r = 0; r < 4; ++r){
      int rl = wid * 16 + quad * 4 + r;
      float v = fmaxf(acc[c][r] + bv, 0.f);
      h1B[(size_t)(blockIdx.x * 64 + rl) * 128 + col] = __float2bfloat16(v);
      unsigned pk = (unsigned)__builtin_amdgcn_cvt_pk_fp8_f32(v, v, 0, false);
      f8t[rl][col] = (unsigned char)(pk & 0xFF);
    }
  }
  __syncthreads();
  for (int it = tid; it < 512; it += 256){
    int row = it >> 3, seg = it & 7;
    uint4 val = *(const uint4*)(&f8t[row][seg * 16]);
    *(uint4*)((char*)h1f8 + (size_t)(blockIdx.x * 64 + row) * 128 + seg * 16) = val;
  }
}

// ---------------- SAGE layer-2 aggregation: 2 nodes/wave x 2 slots x 16 lanes, unroll 4 (fp8) ----------------
__global__ void agg2_k(const int* __restrict__ offs, const int* __restrict__ srcS,
                       const unsigned* __restrict__ h1f8, bf16* __restrict__ meanB){
  int wid = threadIdx.x >> 6, lane = threadIdx.x & 63;
  int half = lane >> 5;                         // node index within wave (0..1)
  int slot = (lane >> 4) & 1, fl = lane & 15;   // fl covers features fl*8 .. fl*8+7
  int n = blockIdx.x * 8 + wid * 2 + half;
  int s = offs[n], e = offs[n + 1];
  floatx2 a0={0,0}, a1={0,0}, a2={0,0}, a3={0,0};
  floatx2 c0={0,0}, c1={0,0}, c2={0,0}, c3={0,0};
  int i = s + slot;
  for (; i + 6 < e; i += 8){
    int sv0 = srcS[i], sv1 = srcS[i + 2], sv2 = srcS[i + 4], sv3 = srcS[i + 6];
    uint2 u = *(const uint2*)(h1f8 + (size_t)sv0 * 32 + fl * 2);
    uint2 v = *(const uint2*)(h1f8 + (size_t)sv1 * 32 + fl * 2);
    uint2 w = *(const uint2*)(h1f8 + (size_t)sv2 * 32 + fl * 2);
    uint2 z = *(const uint2*)(h1f8 + (size_t)sv3 * 32 + fl * 2);
    a0 += __builtin_amdgcn_cvt_pk_f32_fp8(u.x, false);
    a1 += __builtin_amdgcn_cvt_pk_f32_fp8(u.x, true);
    a2 += __builtin_amdgcn_cvt_pk_f32_fp8(u.y, false);
    a3 += __builtin_amdgcn_cvt_pk_f32_fp8(u.y, true);
    c0 += __builtin_amdgcn_cvt_pk_f32_fp8(v.x, false);
    c1 += __builtin_amdgcn_cvt_pk_f32_fp8(v.x, true);
    c2 += __builtin_amdgcn_cvt_pk_f32_fp8(v.y, false);
    c3 += __builtin_amdgcn_cvt_pk_f32_fp8(v.y, true);
    a0 += __builtin_amdgcn_cvt_pk_f32_fp8(w.x, false);
    a1 += __builtin_amdgcn_cvt_pk_f32_fp8(w.x, true);
    a2 += __builtin_amdgcn_cvt_pk_f32_fp8(w.y, false);
    a3 += __builtin_amdgcn_cvt_pk_f32_fp8(w.y, true);
    c0 += __builtin_amdgcn_cvt_pk_f32_fp8(z.x, false);
    c1 += __builtin_amdgcn_cvt_pk_f32_fp8(z.x, true);
    c2 += __builtin_amdgcn_cvt_pk_f32_fp8(z.y, false);
    c3 += __builtin_amdgcn_cvt_pk_f32_fp8(z.y, true);
  }
  for (; i < e; i += 2){
    int sv0 = srcS[i];
    uint2 u = *(const uint2*)(h1f8 + (size_t)sv0 * 32 + fl * 2);
    a0 += __builtin_amdgcn_cvt_pk_f32_fp8(u.x, false);
    a1 += __builtin_amdgcn_cvt_pk_f32_fp8(u.x, true);
    a2 += __builtin_amdgcn_cvt_pk_f32_fp8(u.y, false);
    a3 += __builtin_amdgcn_cvt_pk_f32_fp8(u.y, true);
  }
  a0 += c0; a1 += c1; a2 += c2; a3 += c3;
  float f[8] = {a0.x, a0.y, a1.x, a1.y, a2.x, a2.y, a3.x, a3.y};
  #pragma unroll
  for (int j = 0; j < 8; ++j)
    f[j] += __shfl_xor(f[j], 16);              // combine the 2 slots of this node
  if (slot == 0){
    int d = e - s; if (d < 1) d = 1;
    float inv = 1.f / (float)d;
    uint4 w;
    w.x = packbf(f[0] * inv, f[1] * inv);
    w.y = packbf(f[2] * inv, f[3] * inv);
    w.z = packbf(f[4] * inv, f[5] * inv);
    w.w = packbf(f[6] * inv, f[7] * inv);
    *(uint4*)(meanB + (size_t)n * 128 + fl * 8) = w;
  }
}

// ---------------- gemm2 split-A: A cols 0:128 from meanB, 128:256 from h1B; out = node_emb ----------------
__global__ __launch_bounds__(256) void gemm2sp_k(const bf16* __restrict__ A0, const bf16* __restrict__ A1,
                                                 const bf16* __restrict__ W, const float* __restrict__ bias,
                                                 bf16* __restrict__ out){
  __shared__ bf16 Wl[128][136];
  int tid = threadIdx.x;
  int wid = tid >> 6, lane = tid & 63;
  int l16 = lane & 15, quad = lane >> 4;
  int rowBase = blockIdx.x * 64 + wid * 16;
  floatx4 acc[8] = {};
  #pragma unroll
  for (int ks = 0; ks < 2; ++ks){
    __syncthreads();
    for (int c = tid; c < 2048; c += 256){
      int r = c >> 4, kc = (c & 15) << 3;
      *(uint4*)(&Wl[r][kc]) = *(const uint4*)(W + (size_t)r * 256 + ks * 128 + kc);
    }
    __syncthreads();
    const bf16* Ab = ks ? A1 : A0;
    for (int kk = 0; kk < 4; ++kk){
      short8 af = *(const short8*)(Ab + (size_t)(rowBase + l16) * 128 + kk * 32 + quad * 8);
      #pragma unroll
      for (int c = 0; c < 8; ++c){
        short8 bq = *(const short8*)(&Wl[c * 16 + l16][kk * 32 + quad * 8]);
        acc[c] = __builtin_amdgcn_mfma_f32_16x16x32_bf16(af, bq, acc[c], 0, 0, 0);
      }
    }
  }
  #pragma unroll
  for (int c = 0; c < 8; ++c){
    int col = c * 16 + l16;
    float bv = bias[col];
    #pragma unroll
    for (int r = 0; r < 4; ++r){
      int row = rowBase + quad * 4 + r;
      out[(size_t)row * 128 + col] = __float2bfloat16(fmaxf(acc[c][r] + bv, 0.f));
    }
  }
}

// ---------------- tail0: blocks [0,512) path pre-GEMM | [512,768) pool | [768,832) flow ----------------
__global__ __launch_bounds__(256) void tail0_k(const bf16* __restrict__ ne, const bf16* __restrict__ W,
                                               const float* __restrict__ bias, float* __restrict__ pre,
                                               const int* __restrict__ ridx,
                                               const int* __restrict__ starts,
                                               const float* __restrict__ flow, const float* __restrict__ Wf,
                                               const float* __restrict__ bfv, float* __restrict__ comb){
  __shared__ bf16 Wl[128][136];
  __shared__ float sh[4][128];
  int bid = blockIdx.x, tid = threadIdx.x;
  if (bid < 512){                       // pre = act-free GEMM: pre[r][c] = ne[ridx[r]] . W[c] + bias[c]
    int bx = bid >> 2, by = bid & 3;
    int wid = tid >> 6, lane = tid & 63;
    int l16 = lane & 15, quad = lane >> 4;
    int rowBase = bx * 64 + wid * 16;
    int colGroup = by * 128;
    int arow = ridx[rowBase + l16];
    floatx4 acc[8] = {};
    for (int c = tid; c < 2048; c += 256){
      int r = c >> 4, kc = (c & 15) << 3;
      *(uint4*)(&Wl[r][kc]) = *(const uint4*)(W + (size_t)(colGroup + r) * 128 + kc);
    }
    __syncthreads();
    for (int kk = 0; kk < 4; ++kk){
      short8 af = *(const short8*)(ne + (size_t)arow * 128 + kk * 32 + quad * 8);
      #pragma unroll
      for (int c = 0; c < 8; ++c){
        short8 bq = *(const short8*)(&Wl[c * 16 + l16][kk * 32 + quad * 8]);
        acc[c] = __builtin_amdgcn_mfma_f32_16x16x32_bf16(af, bq, acc[c], 0, 0, 0);
      }
    }
    #pragma unroll
    for (int c = 0; c < 8; ++c){
      int col = colGroup + c * 16 + l16;
      float bv = bias[col];
      #pragma unroll
      for (int r = 0; r < 4; ++r){
        int row = rowBase + quad * 4 + r;
        pre[(size_t)row * 512 + col] = acc[c][r] + bv;
      }
    }
  } else if (bid < 768){                // graph mean pooling (4 row-slots x 64 lanes)
    int b = bid - 512;
    int q = tid >> 6, lane = tid & 63;
    int s = starts[b], e = starts[b + 1];
    float a0 = 0.f, a1 = 0.f;
    for (int i = s + q; i < e; i += 4){
      unsigned u = *(const unsigned*)(ne + (size_t)i * 128 + lane * 2);
      a0 += bl(u); a1 += bh(u);
    }
    sh[q][lane * 2] = a0; sh[q][lane * 2 + 1] = a1;
    __syncthreads();
    if (tid < 128){
      int f = tid;
      float tot = sh[0][f] + sh[1][f] + sh[2][f] + sh[3][f];
      int d = e - s; if (d < 1) d = 1;
      comb[b * 320 + f] = tot / (float)d;
    }
  } else {                              // flow MLP
    int g = (bid - 768) * 256 + tid;    // 16384 = 256 batches x 64 outputs
    int b = g >> 6, j = g & 63;
    float acc = bfv[j];
    for (int k = 0; k < 16; ++k)
      acc += flow[b * 16 + k] * Wf[j * 16 + k];
    comb[b * 320 + 256 + j] = fmaxf(acc, 0.f);
  }
}

// ---------------- LSTM recurrence via MFMA: 16 batches/block, 16 blocks ----------------
__global__ __launch_bounds__(256, 1) void lstm_k(const bf16* __restrict__ Whh, const float* __restrict__ pre,
                                                 const int* __restrict__ path_len, float* __restrict__ comb){
  __shared__ bf16 hbuf[2][16][136];   // [buf][batch][dim], +8 pad
  int tid = threadIdx.x;
  int w = tid >> 6, lane = tid & 63;
  int l16 = lane & 15, quad = lane >> 4;
  int b0 = blockIdx.x * 16;

  short8 wb[4][2][4];
  #pragma unroll
  for (int q = 0; q < 4; ++q)
    #pragma unroll
    for (int hf = 0; hf < 2; ++hf){
      const bf16* rp = Whh + (size_t)(q * 128 + w * 32 + hf * 16 + l16) * 128 + quad * 8;
      #pragma unroll
      for (int ks = 0; ks < 4; ++ks) wb[q][hf][ks] = *(const short8*)(rp + ks * 32);
    }

  int lenr[4];
  #pragma unroll
  for (int r = 0; r < 4; ++r){
    int L = path_len[b0 + quad * 4 + r];
    if (L < 1) L = 1; if (L > LPATH) L = LPATH;
    lenr[r] = L;
  }
  int maxlen = 1;
  for (int i = 0; i < 16; ++i){
    int L = path_len[b0 + i];
    if (L > LPATH) L = LPATH;
    if (L > maxlen) maxlen = L;
  }

  for (int i = tid; i < 1088; i += 256) ((unsigned*)&hbuf[0][0][0])[i] = 0;

  const float* pb[4];
  #pragma unroll
  for (int r = 0; r < 4; ++r)
    pb[r] = pre + (size_t)(b0 + quad * 4 + r) * LPATH * 512 + w * 32 + l16;

  float pv[4][2][4];
  #pragma unroll
  for (int q = 0; q < 4; ++q)
    #pragma unroll
    for (int hf = 0; hf < 2; ++hf)
      #pragma unroll
      for (int r = 0; r < 4; ++r)
        pv[q][hf][r] = pb[r][q * 128 + hf * 16];

  float cst[2][4] = {}, hst[2][4] = {};

  for (int t = 0; t < maxlen; ++t){
    int cur = t & 1, nxt = cur ^ 1;
    __syncthreads();
    short8 af[4];
    #pragma unroll
    for (int ks = 0; ks < 4; ++ks)
      af[ks] = *(const short8*)(&hbuf[cur][l16][ks * 32 + quad * 8]);
    int tn = (t + 1 < maxlen) ? t + 1 : t;
    float pnext[4][2][4];
    #pragma unroll
    for (int q = 0; q < 4; ++q)
      #pragma unroll
      for (int hf = 0; hf < 2; ++hf)
        #pragma unroll
        for (int r = 0; r < 4; ++r)
          pnext[q][hf][r] = pb[r][tn * 512 + q * 128 + hf * 16];
    floatx4 acc[4][2];
    #pragma unroll
    for (int q = 0; q < 4; ++q)
      #pragma unroll
      for (int hf = 0; hf < 2; ++hf){
        acc[q][hf][0] = pv[q][hf][0]; acc[q][hf][1] = pv[q][hf][1];
        acc[q][hf][2] = pv[q][hf][2]; acc[q][hf][3] = pv[q][hf][3];
      }
    #pragma unroll
    for (int ks = 0; ks < 4; ++ks)
      #pragma unroll
      for (int q = 0; q < 4; ++q)
        #pragma unroll
        for (int hf = 0; hf < 2; ++hf)
          acc[q][hf] = __builtin_amdgcn_mfma_f32_16x16x32_bf16(af[ks], wb[q][hf][ks], acc[q][hf], 0, 0, 0);
    #pragma unroll
    for (int hf = 0; hf < 2; ++hf)
      #pragma unroll
      for (int r = 0; r < 4; ++r){
        float ig = sigf(acc[0][hf][r]);
        float fg = sigf(acc[1][hf][r]);
        float gg = tanh_fast(acc[2][hf][r]);
        float og = sigf(acc[3][hf][r]);
        float cn = fmaf(fg, cst[hf][r], ig * gg);
        float hn = og * tanh_fast(cn);
        bool vld = t < lenr[r];
        cst[hf][r] = vld ? cn : cst[hf][r];
        hst[hf][r] = vld ? hn : hst[hf][r];
        hbuf[nxt][quad * 4 + r][w * 32 + hf * 16 + l16] = __float2bfloat16(hst[hf][r]);
      }
    #pragma unroll
    for (int q = 0; q < 4; ++q)
      #pragma unroll
      for (int hf = 0; hf < 2; ++hf)
        #pragma unroll
        for (int r = 0; r < 4; ++r)
          pv[q][hf][r] = pnext[q][hf][r];
  }

  #pragma unroll
  for (int hf = 0; hf < 2; ++hf)
    #pragma unroll
    for (int r = 0; r < 4; ++r)
      comb[(b0 + quad * 4 + r) * 320 + 128 + w * 32 + hf * 16 + l16] = hst[hf][r];
}

// ---------------- scoring head (f32 weights) ----------------
__global__ void head_k(const float* __restrict__ comb, const float* __restrict__ Ws1, const float* __restrict__ bs1,
                       const float* __restrict__ Ws2, const float* __restrict__ bs2, float* __restrict__ out){
  __shared__ float cl[320];
  __shared__ float red[128];
  int b = blockIdx.x, j = threadIdx.x;   // 128 threads
  for (int k = j; k < 320; k += 128) cl[k] = comb[b * 320 + k];
  __syncthreads();
  float acc = bs1[j];
  const float4* wr = (const float4*)(Ws1 + (size_t)j * 320);
  #pragma unroll 4
  for (int kc = 0; kc < 80; ++kc){
    float4 u = wr[kc];
    int k = kc * 4;
    acc += u.x * cl[k] + u.y * cl[k + 1] + u.z * cl[k + 2] + u.w * cl[k + 3];
  }
  float hv = fmaxf(acc, 0.f);
  red[j] = hv * Ws2[j];
  __syncthreads();
  for (int s = 64; s > 0; s >>= 1){ if (j < s) red[j] += red[j + s]; __syncthreads(); }
  if (j == 0) out[b] = red[0] + bs2[0];
}

// ---------------- workspace layout (16B-aligned) ----------------
constexpr size_t OFF_OFFS   = 0;                       // (N+1) ints
constexpr size_t OFF_CNTA   = 524544;                  // NB*GB ints = 256 KB
constexpr size_t OFF_OFSA   = OFF_CNTA   + 262144;     // NB*GB ints
constexpr size_t OFF_BSUM   = OFF_OFSA   + 262144;     // NB ints
constexpr size_t OFF_STARTS = OFF_BSUM   + 1024;       // 257 ints
constexpr size_t OFF_SRCS   = OFF_STARTS + 2048;       // E ints = 8.4 MB
constexpr size_t OFF_WCAT1  = OFF_SRCS   + 8388608;
constexpr size_t OFF_WCAT2  = OFF_WCAT1  + 32768;
constexpr size_t OFF_WIHB   = OFF_WCAT2  + 65536;
constexpr size_t OFF_WHHB   = OFF_WIHB   + 131072;
constexpr size_t OFF_BSUMF  = OFF_WHHB   + 131072;
constexpr size_t OFF_COMB   = OFF_BSUMF  + 2048;
// Region R1 (33.5 MB): Acat1 [mega0/agg1 -> gemmf8 reads] then meanB [agg2 writes -> gemm2sp reads]
constexpr size_t OFF_R1     = OFF_COMB   + 327680;
// Region R2 (64 MiB), aliased sub-lifetimes:
constexpr size_t OFF_R2     = OFF_R1     + 33554432;
constexpr size_t OFF_EBUF   = OFF_R2;                  // E uint (8.4 MB): sort only
constexpr size_t OFF_H1B    = OFF_R2;                  // N x 128 bf16 (33.5 MB): gemmf8 -> gemm2sp
constexpr size_t OFF_PRE    = OFF_R2;                  // 8192 x 512 f32 (16.8 MB): tail0 -> lstm (h1B dead)
constexpr size_t OFF_XB8    = OFF_R2 + 33554432;       // N x 64 B fp8 (8.4 MB): mega0 -> agg1
constexpr size_t OFF_H1F8   = OFF_R2 + 33554432;       // N x 128 B fp8 (16.8 MB): gemmf8 -> agg2 (xb8 dead)
constexpr size_t OFF_NE     = OFF_R2 + 33554432;       // N x 128 bf16 (33.5 MB): gemm2sp -> tail0 (h1f8 dead)

extern "C" void kernel_launch(void* const* d_in, const int* in_sizes, int n_in,
                              void* d_out, int out_size, void* d_ws, size_t ws_size,
                              hipStream_t stream){
  const float* x      = (const float*)d_in[0];
  const int* edge     = (const int*)d_in[1];
  const int* batch    = (const int*)d_in[2];
  const int* path_idx = (const int*)d_in[3];
  const int* path_len = (const int*)d_in[4];
  const float* flow   = (const float*)d_in[5];
  const float* Wl1 = (const float*)d_in[6];
  const float* Wr1 = (const float*)d_in[7];
  const float* b1  = (const float*)d_in[8];
  const float* Wl2 = (const float*)d_in[9];
  const float* Wr2 = (const float*)d_in[10];
  const float* b2  = (const float*)d_in[11];
  const float* Wih = (const float*)d_in[12];
  const float* Whh = (const float*)d_in[13];
  const float* bih = (const float*)d_in[14];
  const float* bhh = (const float*)d_in[15];
  const float* Wf  = (const float*)d_in[16];
  const float* bfv = (const float*)d_in[17];
  const float* Ws1 = (const float*)d_in[18];
  const float* bs1 = (const float*)d_in[19];
  const float* Ws2 = (const float*)d_in[20];
  const float* bs2 = (const float*)d_in[21];

  char* ws = (char*)d_ws;
  int* offs    = (int*)(ws + OFF_OFFS);
  int* cntA    = (int*)(ws + OFF_CNTA);
  int* ofsA    = (int*)(ws + OFF_OFSA);
  int* bsum    = (int*)(ws + OFF_BSUM);
  int* starts  = (int*)(ws + OFF_STARTS);
  int* srcS    = (int*)(ws + OFF_SRCS);
  bf16* Wcat1  = (bf16*)(ws + OFF_WCAT1);
  bf16* Wcat2  = (bf16*)(ws + OFF_WCAT2);
  bf16* WihB   = (bf16*)(ws + OFF_WIHB);
  bf16* WhhB   = (bf16*)(ws + OFF_WHHB);
  float* bsumF = (float*)(ws + OFF_BSUMF);
  float* comb  = (float*)(ws + OFF_COMB);
  bf16* Acat1  = (bf16*)(ws + OFF_R1);
  bf16* meanB  = (bf16*)(ws + OFF_R1);          // alias: Acat1 dead after gemmf8
  unsigned* ebuf = (unsigned*)(ws + OFF_EBUF);
  bf16* h1B    = (bf16*)(ws + OFF_H1B);         // alias: ebuf dead after passB
  float* pre   = (float*)(ws + OFF_PRE);        // alias: h1B dead after gemm2sp
  unsigned* xb8  = (unsigned*)(ws + OFF_XB8);
  unsigned* h1f8 = (unsigned*)(ws + OFF_H1F8);  // alias: xb8 dead after agg1
  bf16* node_emb = (bf16*)(ws + OFF_NE);        // alias: h1f8 dead after agg2

  mega0_k<<<9156, 256, 0, stream>>>(x, xb8, Acat1, edge + N_EDGES, cntA,
                                    Wl1, Wr1, Wl2, Wr2, Wih, Whh, bih, bhh,
                                    Wcat1, Wcat2, WihB, WhhB, bsumF, batch, starts);
  scan1_k<<<NB, 256, 0, stream>>>(cntA, ofsA, bsum);
  passA2_k<<<GB, 256, 0, stream>>>(edge, edge + N_EDGES, ofsA, bsum, ebuf);
  passB_k<<<NB, 256, 0, stream>>>(ebuf, bsum, offs, srcS);
  agg1_k<<<N_NODES / 16, 256, 0, stream>>>(xb8, offs, srcS, Acat1);
  gemmf8_k<<<N_NODES / 64, 256, 0, stream>>>(Acat1, Wcat1, b1, h1B, h1f8);
  agg2_k<<<N_NODES / 8, 256, 0, stream>>>(offs, srcS, h1f8, meanB);
  gemm2sp_k<<<N_NODES / 64, 256, 0, stream>>>(meanB, h1B, Wcat2, b2, node_emb);
  tail0_k<<<832, 256, 0, stream>>>(node_emb, WihB, bsumF, pre, path_idx, starts, flow, Wf, bfv, comb);
  lstm_k<<<BATCHES / 16, 256, 0, stream>>>(WhhB, pre, path_len, comb);
  head_k<<<BATCHES, 128, 0, stream>>>(comb, Ws1, bs1, Ws2, bs2, (float*)d_out);
}